// Round 1
// baseline (1688.816 us; speedup 1.0000x reference)
//
#include <hip/hip_runtime.h>
#include <math.h>

#define BB 8
#define SS 512
#define FF 64
#define DD 512
#define II 1024
#define NHH 8
#define KK 4
#define DHH 128
#define H1H 32
#define OUTO 24
#define BS (BB*SS)   // 4096

// ---------------- input projection: h = x @ in_w + in_b ----------------
__global__ __launch_bounds__(256) void k_in_proj(const float* __restrict__ x,
                                                 const float* __restrict__ w,
                                                 const float* __restrict__ b,
                                                 float* __restrict__ h) {
  int row = blockIdx.x;  // 0..BS-1
  int tid = threadIdx.x;
  __shared__ float xs[FF];
  if (tid < FF) xs[tid] = x[(size_t)row * FF + tid];
  __syncthreads();
  for (int d = tid; d < DD; d += 256) {
    float acc = b[d];
#pragma unroll 8
    for (int f = 0; f < FF; ++f) acc += xs[f] * w[f * DD + d];
    h[(size_t)row * DD + d] = acc;
  }
}

// ---------------- row layernorm over D=512 ----------------
__global__ __launch_bounds__(256) void k_layernorm(const float* __restrict__ in,
                                                   const float* __restrict__ w,
                                                   const float* __restrict__ b,
                                                   float* __restrict__ out) {
  int row = blockIdx.x;
  int tid = threadIdx.x;
  float v0 = in[(size_t)row * DD + tid];
  float v1 = in[(size_t)row * DD + tid + 256];
  float s = v0 + v1, sq = v0 * v0 + v1 * v1;
  for (int off = 32; off; off >>= 1) {
    s += __shfl_down(s, off);
    sq += __shfl_down(sq, off);
  }
  __shared__ float ss[4], sqs[4];
  int wid = tid >> 6, lane = tid & 63;
  if (lane == 0) { ss[wid] = s; sqs[wid] = sq; }
  __syncthreads();
  if (tid == 0) {
    ss[0] = ss[0] + ss[1] + ss[2] + ss[3];
    sqs[0] = sqs[0] + sqs[1] + sqs[2] + sqs[3];
  }
  __syncthreads();
  float mean = ss[0] * (1.0f / DD);
  float var = sqs[0] * (1.0f / DD) - mean * mean;
  float r = rsqrtf(var + 1e-5f);
  out[(size_t)row * DD + tid] = (v0 - mean) * r * w[tid] + b[tid];
  out[(size_t)row * DD + tid + 256] = (v1 - mean) * r * w[tid + 256] + b[tid + 256];
}

// ---------------- generic fp32 tiled GEMM: C[M,N] (=|+=) A[M,K](lda) @ B[K,N] (+bias) ----------------
// grid: (N/64, M/64), block 256. M=4096 rows.
__global__ __launch_bounds__(256) void k_gemm(const float* __restrict__ A, int lda,
                                              const float* __restrict__ Bm, int N, int Kd,
                                              const float* __restrict__ bias,
                                              float* __restrict__ C, int accumulate) {
  __shared__ float As[16][68];
  __shared__ float Bs[16][68];
  int tid = threadIdx.x;
  int m0 = blockIdx.y * 64, n0 = blockIdx.x * 64;
  int tx = tid & 15, ty = tid >> 4;  // 16x16 threads, 4x4 micro-tile
  float acc[4][4] = {};
  int lm = tid >> 2, lk = (tid & 3) * 4;       // A loader
  int bk = tid >> 4, bn = (tid & 15) * 4;      // B loader
  const float* Aptr = A + (size_t)(m0 + lm) * lda + lk;
  const float* Bptr = Bm + (size_t)bk * N + n0 + bn;
  int nkt = Kd >> 4;
  for (int kt = 0; kt < nkt; ++kt) {
    float4 a4 = *(const float4*)(Aptr + kt * 16);
    As[lk + 0][lm] = a4.x;
    As[lk + 1][lm] = a4.y;
    As[lk + 2][lm] = a4.z;
    As[lk + 3][lm] = a4.w;
    float4 b4 = *(const float4*)(Bptr + (size_t)kt * 16 * N);
    *(float4*)&Bs[bk][bn] = b4;
    __syncthreads();
#pragma unroll
    for (int kk = 0; kk < 16; ++kk) {
      float4 av = *(const float4*)&As[kk][ty * 4];
      float4 bv = *(const float4*)&Bs[kk][tx * 4];
      float am[4] = {av.x, av.y, av.z, av.w};
      float bb2[4] = {bv.x, bv.y, bv.z, bv.w};
#pragma unroll
      for (int i = 0; i < 4; ++i)
#pragma unroll
        for (int j = 0; j < 4; ++j) acc[i][j] += am[i] * bb2[j];
    }
    __syncthreads();
  }
#pragma unroll
  for (int i = 0; i < 4; ++i) {
    int r = m0 + ty * 4 + i;
    float4 o;
    o.x = acc[i][0]; o.y = acc[i][1]; o.z = acc[i][2]; o.w = acc[i][3];
    float* Cp = C + (size_t)r * N + n0 + tx * 4;
    if (bias) {
      const float* bp = bias + n0 + tx * 4;
      o.x += bp[0]; o.y += bp[1]; o.z += bp[2]; o.w += bp[3];
    }
    if (accumulate) {
      float4 c0 = *(const float4*)Cp;
      o.x += c0.x; o.y += c0.y; o.z += c0.z; o.w += c0.w;
    }
    *(float4*)Cp = o;
  }
}

// ---------------- causal conv (K=4) + SiLU ----------------
__global__ __launch_bounds__(256) void k_conv_silu(const float* __restrict__ up,
                                                   const float* __restrict__ cw,
                                                   const float* __restrict__ cb,
                                                   float* __restrict__ out) {
  int idx = blockIdx.x * 256 + threadIdx.x;  // over BS*II
  int i = idx & (II - 1);
  int row = idx >> 10;
  int s = row & (SS - 1);
  float4 w4 = *(const float4*)(cw + (size_t)i * 4);
  float wj[4] = {w4.x, w4.y, w4.z, w4.w};
  float acc = cb[i];
#pragma unroll
  for (int j = 0; j < 4; ++j) {
    int so = s + j - 3;
    if (so >= 0) acc += up[(size_t)(row + j - 3) * (2 * II) + i] * wj[j];
  }
  float sig = 1.0f / (1.0f + __expf(-acc));
  out[(size_t)row * II + i] = acc * sig;
}

// ---------------- input/forget gate projections (NH=8 outs per row) ----------------
__global__ __launch_bounds__(256) void k_gates(const float* __restrict__ q,
                                               const float* __restrict__ k,
                                               const float* __restrict__ v,
                                               const float* __restrict__ igw,
                                               const float* __restrict__ igb,
                                               const float* __restrict__ fgw,
                                               const float* __restrict__ fgb,
                                               float* __restrict__ ig, float* __restrict__ fg) {
  int row = blockIdx.x;  // b*S+s
  int tid = threadIdx.x;
  float pig[NHH] = {}, pfg[NHH] = {};
  for (int c = tid; c < II; c += 256) {
    float qv = q[(size_t)row * II + c];
    float kv = k[(size_t)row * II + c];
    float vv = v[(size_t)row * II + c];
    const float* w0 = igw + (size_t)c * NHH;
    const float* w1 = igw + (size_t)(II + c) * NHH;
    const float* w2 = igw + (size_t)(2 * II + c) * NHH;
    const float* f0 = fgw + (size_t)c * NHH;
    const float* f1 = fgw + (size_t)(II + c) * NHH;
    const float* f2 = fgw + (size_t)(2 * II + c) * NHH;
#pragma unroll
    for (int n = 0; n < NHH; ++n) {
      pig[n] += qv * w0[n] + kv * w1[n] + vv * w2[n];
      pfg[n] += qv * f0[n] + kv * f1[n] + vv * f2[n];
    }
  }
  for (int off = 32; off; off >>= 1) {
#pragma unroll
    for (int n = 0; n < NHH; ++n) {
      pig[n] += __shfl_down(pig[n], off);
      pfg[n] += __shfl_down(pfg[n], off);
    }
  }
  __shared__ float red[2 * NHH][4];
  int wid = tid >> 6, lane = tid & 63;
  if (lane == 0) {
#pragma unroll
    for (int n = 0; n < NHH; ++n) {
      red[n][wid] = pig[n];
      red[NHH + n][wid] = pfg[n];
    }
  }
  __syncthreads();
  int b = row / SS, s = row & (SS - 1);
  if (tid < NHH) {
    float a = red[tid][0] + red[tid][1] + red[tid][2] + red[tid][3];
    ig[((size_t)b * NHH + tid) * SS + s] = a + igb[tid];
  } else if (tid >= 64 && tid < 64 + NHH) {
    int n = tid - 64;
    float a = red[NHH + n][0] + red[NHH + n][1] + red[NHH + n][2] + red[NHH + n][3];
    fg[((size_t)b * NHH + n) * SS + s] = a + fgb[n];
  }
}

// ---------------- per-(b,n) scan: cumsum(logsigmoid(fg)), e=ig-cs, M=cummax(e), maxd=cs+M ----------------
__global__ __launch_bounds__(512) void k_scan(const float* __restrict__ ig,
                                              const float* __restrict__ fg,
                                              float* __restrict__ e_g, float* __restrict__ M_g,
                                              float* __restrict__ maxd_g) {
  int bn = blockIdx.x;
  int t = threadIdx.x;
  __shared__ float buf[SS];
  float f = fg[(size_t)bn * SS + t];
  float lf = (f >= 0.f) ? -log1pf(expf(-f)) : (f - log1pf(expf(f)));
  buf[t] = lf;
  __syncthreads();
  for (int off = 1; off < SS; off <<= 1) {
    float val = buf[t];
    if (t >= off) val += buf[t - off];
    __syncthreads();
    buf[t] = val;
    __syncthreads();
  }
  float cs = buf[t];
  float e = ig[(size_t)bn * SS + t] - cs;
  __syncthreads();
  buf[t] = e;
  __syncthreads();
  for (int off = 1; off < SS; off <<= 1) {
    float val = buf[t];
    if (t >= off) val = fmaxf(val, buf[t - off]);
    __syncthreads();
    buf[t] = val;
    __syncthreads();
  }
  float M = buf[t];
  e_g[(size_t)bn * SS + t] = e;
  M_g[(size_t)bn * SS + t] = M;
  maxd_g[(size_t)bn * SS + t] = cs + M;
}

// ---------------- mLSTM attention (flash-style, analytic decay) ----------------
// grid: (8 s-tiles swizzled, B*NH). block 256. out hc in (B,S,I) layout.
__global__ __launch_bounds__(256) void k_attn(const float* __restrict__ q,
                                              const float* __restrict__ k,
                                              const float* __restrict__ v,
                                              const float* __restrict__ e_g,
                                              const float* __restrict__ M_g,
                                              const float* __restrict__ maxd_g,
                                              float* __restrict__ hc) {
  __shared__ float lds[64 * 132 + 32 * 132 + 32 * 128 + 64 * 33 + 64];
  float* q_s = lds;                 // [64][132]
  float* k_s = q_s + 64 * 132;      // [32][132]
  float* v_s = k_s + 32 * 132;      // [32][128]
  float* w_s = v_s + 32 * 128;      // [64][33]
  float* scale_s = w_s + 64 * 33;   // [64]
  int tid = threadIdx.x;
  int xb = blockIdx.x;
  int stile = (xb & 1) ? (7 - (xb >> 1)) : (xb >> 1);  // pair heavy+light tiles per CU
  int bn = blockIdx.y;
  int b = bn >> 3, n = bn & 7;
  int s0 = stile * 64;
  const size_t rowbase = ((size_t)b * SS) * II + (size_t)n * DHH;

  // load q tile 64x128 (float4)
  for (int idx = tid; idx < 64 * 32; idx += 256) {
    int r = idx >> 5, c4 = (idx & 31) * 4;
    *(float4*)&q_s[r * 132 + c4] = *(const float4*)&q[rowbase + (size_t)(s0 + r) * II + c4];
  }

  int si = tid >> 2;       // phase A: row 0..63
  int tjb = tid & 3;       // phase A: col base
  int sr = tid & 63;       // phase B: row 0..63
  int dcb = tid >> 6;      // phase B: col group 0..3 (wave-uniform)
  float acc[32] = {};
  float rsum = 0.f;
  float Ms = M_g[(size_t)bn * SS + s0 + si];
  int ntt = (s0 + 64) >> 5;
  const float rsq = 0.08838834764831845f;  // 1/sqrt(128)

  for (int tt0 = 0; tt0 < ntt; ++tt0) {
    int t0 = tt0 * 32;
    __syncthreads();  // prev phase B done with k_s/v_s/w_s (and 1st iter: q_s load pending)
    for (int idx = tid; idx < 32 * 32; idx += 256) {
      int r = idx >> 5, c4 = (idx & 31) * 4;
      *(float4*)&k_s[r * 132 + c4] = *(const float4*)&k[rowbase + (size_t)(t0 + r) * II + c4];
      *(float4*)&v_s[r * 128 + c4] = *(const float4*)&v[rowbase + (size_t)(t0 + r) * II + c4];
    }
    __syncthreads();
    // phase A: w[64][32] = (q.k)/sqrt(DH) * exp(e[t]-M[s]), causal mask
    float wacc[8] = {};
    for (int d = 0; d < 128; d += 4) {
      float4 q4 = *(const float4*)&q_s[si * 132 + d];
#pragma unroll
      for (int j = 0; j < 8; ++j) {
        float4 k4 = *(const float4*)&k_s[(tjb + 4 * j) * 132 + d];
        wacc[j] += q4.x * k4.x + q4.y * k4.y + q4.z * k4.z + q4.w * k4.w;
      }
    }
    int sg = s0 + si;
#pragma unroll
    for (int j = 0; j < 8; ++j) {
      int tg = t0 + tjb + 4 * j;
      float wv = 0.f;
      if (tg <= sg) {
        float ee = e_g[(size_t)bn * SS + tg];
        wv = wacc[j] * rsq * __expf(ee - Ms);
      }
      w_s[si * 33 + tjb + 4 * j] = wv;
    }
    __syncthreads();
    // phase B: acc += w * v  (each thread: row sr, cols jj*16+dcb*4+r)
    for (int ttj = 0; ttj < 32; ++ttj) {
      float wv = w_s[sr * 33 + ttj];
      rsum += wv;
      const float* vrow = &v_s[ttj * 128 + dcb * 4];
#pragma unroll
      for (int jj = 0; jj < 8; ++jj) {
        float4 v4 = *(const float4*)(vrow + jj * 16);
        acc[jj * 4 + 0] += wv * v4.x;
        acc[jj * 4 + 1] += wv * v4.y;
        acc[jj * 4 + 2] += wv * v4.z;
        acc[jj * 4 + 3] += wv * v4.w;
      }
    }
  }
  // norm: max(|rowsum|, exp(-maxd)), scale rows
  if (dcb == 0) {
    float md = maxd_g[(size_t)bn * SS + s0 + sr];
    float nrm = fmaxf(fabsf(rsum), __expf(-md));
    scale_s[sr] = 1.0f / (nrm + 1e-6f);
  }
  __syncthreads();
  float scl = scale_s[sr];
  float* ostage = q_s;  // reuse as [128][65]
#pragma unroll
  for (int jj = 0; jj < 8; ++jj)
#pragma unroll
    for (int r2 = 0; r2 < 4; ++r2) {
      int c = jj * 16 + dcb * 4 + r2;
      ostage[c * 65 + sr] = acc[jj * 4 + r2] * scl;
    }
  __syncthreads();
  for (int idx = tid; idx < 64 * 128; idx += 256) {
    int r = idx >> 7, c = idx & 127;
    hc[rowbase + (size_t)(s0 + r) * II + c] = ostage[c * 65 + r];
  }
}

// ---------------- per-head groupnorm + skip + silu(z) gate (in-place hc -> hs) ----------------
__global__ __launch_bounds__(256) void k_gn_skip(const float* __restrict__ hcin,
                                                 const float* __restrict__ convact,
                                                 const float* __restrict__ up,
                                                 const float* __restrict__ gnw,
                                                 const float* __restrict__ skw,
                                                 float* __restrict__ hs) {
  int row = blockIdx.x;
  int tid = threadIdx.x;
  int n = tid >> 5, j = tid & 31;
  float vals[4];
  float s = 0.f, sq = 0.f;
#pragma unroll
  for (int kk2 = 0; kk2 < 4; ++kk2) {
    int i = n * DHH + j + 32 * kk2;
    float vv = hcin[(size_t)row * II + i];
    vals[kk2] = vv;
    s += vv;
    sq += vv * vv;
  }
#pragma unroll
  for (int off2 = 16; off2; off2 >>= 1) {
    s += __shfl_xor(s, off2);
    sq += __shfl_xor(sq, off2);
  }
  float mean = s * (1.0f / DHH);
  float var = sq * (1.0f / DHH) - mean * mean;
  float r = rsqrtf(var + 1e-5f);
#pragma unroll
  for (int kk2 = 0; kk2 < 4; ++kk2) {
    int i = n * DHH + j + 32 * kk2;
    float hn = (vals[kk2] - mean) * r * gnw[i];
    float ca = convact[(size_t)row * II + i];
    float z = up[(size_t)row * 2 * II + II + i];
    float sz = z / (1.0f + __expf(-z));
    hs[(size_t)row * II + i] = (hn + skw[i] * ca) * sz;
  }
}

// ---------------- final LN(last row) + 2-layer head ----------------
__global__ __launch_bounds__(256) void k_head(const float* __restrict__ h,
                                              const float* __restrict__ pw,
                                              const float* __restrict__ pb,
                                              const float* __restrict__ w1,
                                              const float* __restrict__ b1,
                                              const float* __restrict__ w2,
                                              const float* __restrict__ b2,
                                              float* __restrict__ out) {
  int b = blockIdx.x;
  int tid = threadIdx.x;
  __shared__ float last[DD];
  __shared__ float hid[H1H];
  __shared__ float ss[4], sqs[4];
  const float* row = h + ((size_t)b * SS + SS - 1) * DD;
  float v0 = row[tid], v1 = row[tid + 256];
  float s = v0 + v1, sq = v0 * v0 + v1 * v1;
  for (int off = 32; off; off >>= 1) {
    s += __shfl_down(s, off);
    sq += __shfl_down(sq, off);
  }
  int wid = tid >> 6, lane = tid & 63;
  if (lane == 0) { ss[wid] = s; sqs[wid] = sq; }
  __syncthreads();
  if (tid == 0) {
    ss[0] = ss[0] + ss[1] + ss[2] + ss[3];
    sqs[0] = sqs[0] + sqs[1] + sqs[2] + sqs[3];
  }
  __syncthreads();
  float mean = ss[0] * (1.0f / DD);
  float var = sqs[0] * (1.0f / DD) - mean * mean;
  float r = rsqrtf(var + 1e-5f);
  last[tid] = (v0 - mean) * r * pw[tid] + pb[tid];
  last[tid + 256] = (v1 - mean) * r * pw[tid + 256] + pb[tid + 256];
  __syncthreads();
  if (tid < H1H) {
    float a = b1[tid];
    for (int d2 = 0; d2 < DD; ++d2) a += last[d2] * w1[(size_t)d2 * H1H + tid];
    hid[tid] = fmaxf(a, 0.f);
  }
  __syncthreads();
  if (tid < OUTO) {
    float a = b2[tid];
#pragma unroll
    for (int j2 = 0; j2 < H1H; ++j2) a += hid[j2] * w2[(size_t)j2 * OUTO + tid];
    out[(size_t)b * OUTO + tid] = a;
  }
}

extern "C" void kernel_launch(void* const* d_in, const int* in_sizes, int n_in,
                              void* d_out, int out_size, void* d_ws, size_t ws_size,
                              hipStream_t stream) {
  (void)in_sizes; (void)n_in; (void)out_size; (void)ws_size;
  const float* x    = (const float*)d_in[0];
  const float* in_w = (const float*)d_in[1];
  const float* in_b = (const float*)d_in[2];
  const float* ln_w = (const float*)d_in[3];
  const float* ln_b = (const float*)d_in[4];
  const float* up_w = (const float*)d_in[5];
  const float* conv_w = (const float*)d_in[6];
  const float* conv_b = (const float*)d_in[7];
  const float* q_w  = (const float*)d_in[8];
  const float* k_w  = (const float*)d_in[9];
  const float* v_w  = (const float*)d_in[10];
  const float* ig_w = (const float*)d_in[11];
  const float* ig_b = (const float*)d_in[12];
  const float* fg_w = (const float*)d_in[13];
  const float* fg_b = (const float*)d_in[14];
  const float* gn_w = (const float*)d_in[15];
  const float* sk_w = (const float*)d_in[16];
  const float* dn_w = (const float*)d_in[17];
  const float* po_w = (const float*)d_in[18];
  const float* po_b = (const float*)d_in[19];
  const float* h1_w = (const float*)d_in[20];
  const float* h1_b = (const float*)d_in[21];
  const float* h2_w = (const float*)d_in[22];
  const float* h2_b = (const float*)d_in[23];

  float* ws = (float*)d_ws;
  float* h    = ws;                  // 2,097,152
  float* xn   = h + 2097152;         // 2,097,152
  float* up   = xn + 2097152;        // 8,388,608
  float* conv = up + 8388608;        // 4,194,304
  float* qb   = conv + 4194304;      // 4,194,304
  float* kb   = qb + 4194304;        // 4,194,304
  float* vb   = kb + 4194304;        // 4,194,304
  float* hc   = vb + 4194304;        // 4,194,304
  float* igb_ = hc + 4194304;        // 32,768
  float* fgb_ = igb_ + 32768;        // 32,768
  float* e_g  = fgb_ + 32768;        // 32,768
  float* M_g  = e_g + 32768;         // 32,768
  float* md_g = M_g + 32768;         // 32,768  -> total ~128.6 MB

  k_in_proj<<<BS, 256, 0, stream>>>(x, in_w, in_b, h);
  for (int l = 0; l < 2; ++l) {
    k_layernorm<<<BS, 256, 0, stream>>>(h, ln_w + l * DD, ln_b + l * DD, xn);
    k_gemm<<<dim3(32, 64), 256, 0, stream>>>(xn, DD, up_w + (size_t)l * DD * 2 * II,
                                             2 * II, DD, nullptr, up, 0);
    k_conv_silu<<<BS * II / 256, 256, 0, stream>>>(up, conv_w + l * II * KK, conv_b + l * II, conv);
    k_gemm<<<dim3(16, 64), 256, 0, stream>>>(conv, II, q_w + (size_t)l * II * II,
                                             II, II, nullptr, qb, 0);
    k_gemm<<<dim3(16, 64), 256, 0, stream>>>(conv, II, k_w + (size_t)l * II * II,
                                             II, II, nullptr, kb, 0);
    k_gemm<<<dim3(16, 64), 256, 0, stream>>>(up, 2 * II, v_w + (size_t)l * II * II,
                                             II, II, nullptr, vb, 0);
    k_gates<<<BS, 256, 0, stream>>>(qb, kb, vb, ig_w + l * 3 * II * NHH, ig_b + l * NHH,
                                    fg_w + l * 3 * II * NHH, fg_b + l * NHH, igb_, fgb_);
    k_scan<<<BB * NHH, 512, 0, stream>>>(igb_, fgb_, e_g, M_g, md_g);
    k_attn<<<dim3(8, BB * NHH), 256, 0, stream>>>(qb, kb, vb, e_g, M_g, md_g, hc);
    k_gn_skip<<<BS, 256, 0, stream>>>(hc, conv, up, gn_w + l * II, sk_w + l * II, hc);
    k_gemm<<<dim3(8, 64), 256, 0, stream>>>(hc, II, dn_w + (size_t)l * II * DD,
                                            DD, II, nullptr, h, 1);
  }
  k_head<<<BB, 256, 0, stream>>>(h, po_w, po_b, h1_w, h1_b, h2_w, h2_b, (float*)d_out);
}

// Round 2
// 934.648 us; speedup vs baseline: 1.8069x; 1.8069x over previous
//
#include <hip/hip_runtime.h>
#include <math.h>

#define BB 8
#define SS 512
#define FF 64
#define DD 512
#define II 1024
#define NHH 8
#define KK 4
#define DHH 128
#define H1H 32
#define OUTO 24
#define BS (BB*SS)   // 4096

typedef unsigned short ushort;
typedef __attribute__((ext_vector_type(8))) short short8;
typedef __attribute__((ext_vector_type(8))) unsigned short ushort8;
typedef __attribute__((ext_vector_type(4))) float f32x4;

__device__ __forceinline__ float bf2f(ushort u) {
  return __uint_as_float(((unsigned int)u) << 16);
}
__device__ __forceinline__ ushort f2bf(float f) {
  unsigned int u = __float_as_uint(f);
  unsigned int r = u + 0x7fffu + ((u >> 16) & 1u);
  return (ushort)(r >> 16);
}

typedef __attribute__((address_space(1))) const void gvoid;
typedef __attribute__((address_space(3))) void lvoid;
__device__ __forceinline__ void async16(const void* g, void* l) {
  __builtin_amdgcn_global_load_lds((gvoid*)g, (lvoid*)l, 16, 0, 0);
}

// ---------------- input projection: h = x @ in_w + in_b (fp32, tiny K) ----------------
__global__ __launch_bounds__(256) void k_in_proj(const float* __restrict__ x,
                                                 const float* __restrict__ w,
                                                 const float* __restrict__ b,
                                                 float* __restrict__ h) {
  int row = blockIdx.x;
  int tid = threadIdx.x;
  __shared__ float xs[FF];
  if (tid < FF) xs[tid] = x[(size_t)row * FF + tid];
  __syncthreads();
  for (int d = tid; d < DD; d += 256) {
    float acc = b[d];
#pragma unroll 8
    for (int f = 0; f < FF; ++f) acc += xs[f] * w[f * DD + d];
    h[(size_t)row * DD + d] = acc;
  }
}

// ---------------- row layernorm over D=512 -> bf16 out ----------------
__global__ __launch_bounds__(256) void k_layernorm(const float* __restrict__ in,
                                                   const float* __restrict__ w,
                                                   const float* __restrict__ b,
                                                   ushort* __restrict__ out) {
  int row = blockIdx.x;
  int tid = threadIdx.x;
  float v0 = in[(size_t)row * DD + tid];
  float v1 = in[(size_t)row * DD + tid + 256];
  float s = v0 + v1, sq = v0 * v0 + v1 * v1;
  for (int off = 32; off; off >>= 1) {
    s += __shfl_down(s, off);
    sq += __shfl_down(sq, off);
  }
  __shared__ float ss[4], sqs[4];
  int wid = tid >> 6, lane = tid & 63;
  if (lane == 0) { ss[wid] = s; sqs[wid] = sq; }
  __syncthreads();
  if (tid == 0) {
    ss[0] = ss[0] + ss[1] + ss[2] + ss[3];
    sqs[0] = sqs[0] + sqs[1] + sqs[2] + sqs[3];
  }
  __syncthreads();
  float mean = ss[0] * (1.0f / DD);
  float var = sqs[0] * (1.0f / DD) - mean * mean;
  float r = rsqrtf(var + 1e-5f);
  out[(size_t)row * DD + tid] = f2bf((v0 - mean) * r * w[tid] + b[tid]);
  out[(size_t)row * DD + tid + 256] = f2bf((v1 - mean) * r * w[tid + 256] + b[tid + 256]);
}

// ---------------- weight convert+transpose: W[K][N] f32 -> Wt[N][K] bf16 ----------------
__global__ __launch_bounds__(256) void k_wt(const float* __restrict__ W,
                                            ushort* __restrict__ Wt, int Kd, int N) {
  __shared__ float t[32][33];
  int tid = threadIdx.x;
  int n0 = blockIdx.x * 32, k0 = blockIdx.y * 32;
  int c = tid & 31, r8 = tid >> 5;
  for (int rr = r8; rr < 32; rr += 8)
    t[rr][c] = W[(size_t)(k0 + rr) * N + n0 + c];
  __syncthreads();
  for (int rr = r8; rr < 32; rr += 8)
    Wt[(size_t)(n0 + rr) * Kd + k0 + c] = f2bf(t[c][rr]);
}

// ---------------- bf16 MFMA GEMM: C[M,N] = A[M,K](lda) @ Wt[N,K]^T ----------------
// 128x128 tile, BK=32, 4 waves (2x2), each wave 64x64 via 4x4 16x16x32 frags.
__global__ __launch_bounds__(256) void k_gemm_bf16(const ushort* __restrict__ A, int lda,
                                                   const ushort* __restrict__ Bt, int ldb,
                                                   int N, int Kd,
                                                   float* __restrict__ Cf, int accumulate,
                                                   ushort* __restrict__ Cb, int ldc) {
  __shared__ ushort As[128 * 32];
  __shared__ ushort Bs[128 * 32];
  int tid = threadIdx.x;
  int wave = tid >> 6, lane = tid & 63;
  int m0 = blockIdx.y * 128, n0 = blockIdx.x * 128;
  int wm = wave >> 1, wn = wave & 1;
  f32x4 acc[4][4] = {};

  // staging: wave w owns LDS rows [w*32, w*32+32); 2 issues of 16 rows each
  int srow = wave * 32 + (lane >> 2);
  int scol = (lane & 3) * 8;  // element offset within row (16B chunks)
  const ushort* Ag = A + (size_t)(m0 + srow) * lda + scol;
  const ushort* Bg = Bt + (size_t)(n0 + srow) * ldb + scol;
  ushort* AsW = As + wave * 1024;
  ushort* BsW = Bs + wave * 1024;

  int frow = lane & 15, fk = (lane >> 4) * 8;
  const ushort* ap = As + (size_t)(wm * 64 + frow) * 32 + fk;
  const ushort* bp = Bs + (size_t)(wn * 64 + frow) * 32 + fk;

  for (int kt = 0; kt < Kd; kt += 32) {
    async16(Ag + kt, AsW);
    async16(Ag + kt + (size_t)16 * lda, AsW + 512);
    async16(Bg + kt, BsW);
    async16(Bg + kt + (size_t)16 * ldb, BsW + 512);
    asm volatile("s_waitcnt vmcnt(0)" ::: "memory");
    __syncthreads();
    short8 a[4], b[4];
#pragma unroll
    for (int i = 0; i < 4; ++i) {
      a[i] = *(const short8*)(ap + i * 16 * 32);
      b[i] = *(const short8*)(bp + i * 16 * 32);
    }
#pragma unroll
    for (int i = 0; i < 4; ++i)
#pragma unroll
      for (int j = 0; j < 4; ++j)
        acc[i][j] = __builtin_amdgcn_mfma_f32_16x16x32_bf16(a[i], b[j], acc[i][j], 0, 0, 0);
    __syncthreads();
  }

  int ccol = lane & 15, crow = (lane >> 4) * 4;
#pragma unroll
  for (int i = 0; i < 4; ++i) {
#pragma unroll
    for (int j = 0; j < 4; ++j) {
      int grow = m0 + wm * 64 + i * 16 + crow;
      int gcol = n0 + wn * 64 + j * 16 + ccol;
#pragma unroll
      for (int r = 0; r < 4; ++r) {
        float v = acc[i][j][r];
        if (Cf) {
          size_t idx = (size_t)(grow + r) * N + gcol;
          Cf[idx] = accumulate ? (Cf[idx] + v) : v;
        }
        if (Cb) Cb[(size_t)(grow + r) * ldc + gcol] = f2bf(v);
      }
    }
  }
}

// ---------------- causal conv (K=4) + SiLU (bf16 in/out) ----------------
__global__ __launch_bounds__(256) void k_conv_silu(const ushort* __restrict__ up,
                                                   const float* __restrict__ cw,
                                                   const float* __restrict__ cb,
                                                   ushort* __restrict__ out) {
  int idx = blockIdx.x * 256 + threadIdx.x;
  int i = idx & (II - 1);
  int row = idx >> 10;
  int s = row & (SS - 1);
  float4 w4 = *(const float4*)(cw + (size_t)i * 4);
  float wj[4] = {w4.x, w4.y, w4.z, w4.w};
  float acc = cb[i];
#pragma unroll
  for (int j = 0; j < 4; ++j) {
    int so = s + j - 3;
    if (so >= 0) acc += bf2f(up[(size_t)(row + j - 3) * (2 * II) + i]) * wj[j];
  }
  float sig = 1.0f / (1.0f + __expf(-acc));
  out[(size_t)row * II + i] = f2bf(acc * sig);
}

// ---------------- gate projections ----------------
__global__ __launch_bounds__(256) void k_gates(const ushort* __restrict__ q,
                                               const ushort* __restrict__ k,
                                               const ushort* __restrict__ v,
                                               const float* __restrict__ igw,
                                               const float* __restrict__ igb,
                                               const float* __restrict__ fgw,
                                               const float* __restrict__ fgb,
                                               float* __restrict__ ig, float* __restrict__ fg) {
  int row = blockIdx.x;
  int tid = threadIdx.x;
  float pig[NHH] = {}, pfg[NHH] = {};
  for (int c = tid; c < II; c += 256) {
    float qv = bf2f(q[(size_t)row * II + c]);
    float kv = bf2f(k[(size_t)row * II + c]);
    float vv = bf2f(v[(size_t)row * II + c]);
    const float* w0 = igw + (size_t)c * NHH;
    const float* w1 = igw + (size_t)(II + c) * NHH;
    const float* w2 = igw + (size_t)(2 * II + c) * NHH;
    const float* f0 = fgw + (size_t)c * NHH;
    const float* f1 = fgw + (size_t)(II + c) * NHH;
    const float* f2 = fgw + (size_t)(2 * II + c) * NHH;
#pragma unroll
    for (int n = 0; n < NHH; ++n) {
      pig[n] += qv * w0[n] + kv * w1[n] + vv * w2[n];
      pfg[n] += qv * f0[n] + kv * f1[n] + vv * f2[n];
    }
  }
  for (int off = 32; off; off >>= 1) {
#pragma unroll
    for (int n = 0; n < NHH; ++n) {
      pig[n] += __shfl_down(pig[n], off);
      pfg[n] += __shfl_down(pfg[n], off);
    }
  }
  __shared__ float red[2 * NHH][4];
  int wid = tid >> 6, lane = tid & 63;
  if (lane == 0) {
#pragma unroll
    for (int n = 0; n < NHH; ++n) {
      red[n][wid] = pig[n];
      red[NHH + n][wid] = pfg[n];
    }
  }
  __syncthreads();
  int b = row / SS, s = row & (SS - 1);
  if (tid < NHH) {
    float a = red[tid][0] + red[tid][1] + red[tid][2] + red[tid][3];
    ig[((size_t)b * NHH + tid) * SS + s] = a + igb[tid];
  } else if (tid >= 64 && tid < 64 + NHH) {
    int n = tid - 64;
    float a = red[NHH + n][0] + red[NHH + n][1] + red[NHH + n][2] + red[NHH + n][3];
    fg[((size_t)b * NHH + n) * SS + s] = a + fgb[n];
  }
}

// ---------------- per-(b,n) scan ----------------
__global__ __launch_bounds__(512) void k_scan(const float* __restrict__ ig,
                                              const float* __restrict__ fg,
                                              float* __restrict__ e_g, float* __restrict__ M_g,
                                              float* __restrict__ maxd_g) {
  int bn = blockIdx.x;
  int t = threadIdx.x;
  __shared__ float buf[SS];
  float f = fg[(size_t)bn * SS + t];
  float lf = (f >= 0.f) ? -log1pf(expf(-f)) : (f - log1pf(expf(f)));
  buf[t] = lf;
  __syncthreads();
  for (int off = 1; off < SS; off <<= 1) {
    float val = buf[t];
    if (t >= off) val += buf[t - off];
    __syncthreads();
    buf[t] = val;
    __syncthreads();
  }
  float cs = buf[t];
  float e = ig[(size_t)bn * SS + t] - cs;
  __syncthreads();
  buf[t] = e;
  __syncthreads();
  for (int off = 1; off < SS; off <<= 1) {
    float val = buf[t];
    if (t >= off) val = fmaxf(val, buf[t - off]);
    __syncthreads();
    buf[t] = val;
    __syncthreads();
  }
  float M = buf[t];
  e_g[(size_t)bn * SS + t] = e;
  M_g[(size_t)bn * SS + t] = M;
  maxd_g[(size_t)bn * SS + t] = cs + M;
}

// ---------------- mLSTM attention (fp32 compute, bf16 q/k/v in) ----------------
__global__ __launch_bounds__(256) void k_attn(const ushort* __restrict__ q,
                                              const ushort* __restrict__ k,
                                              const ushort* __restrict__ v,
                                              const float* __restrict__ e_g,
                                              const float* __restrict__ M_g,
                                              const float* __restrict__ maxd_g,
                                              float* __restrict__ hc) {
  __shared__ float lds[64 * 132 + 32 * 132 + 32 * 128 + 64 * 33 + 64];
  float* q_s = lds;
  float* k_s = q_s + 64 * 132;
  float* v_s = k_s + 32 * 132;
  float* w_s = v_s + 32 * 128;
  float* scale_s = w_s + 64 * 33;
  int tid = threadIdx.x;
  int xb = blockIdx.x;
  int stile = (xb & 1) ? (7 - (xb >> 1)) : (xb >> 1);
  int bn = blockIdx.y;
  int b = bn >> 3, n = bn & 7;
  int s0 = stile * 64;
  const size_t rowbase = ((size_t)b * SS) * II + (size_t)n * DHH;

  for (int idx = tid; idx < 64 * 16; idx += 256) {
    int r = idx >> 4, c8 = (idx & 15) * 8;
    ushort8 u = *(const ushort8*)&q[rowbase + (size_t)(s0 + r) * II + c8];
#pragma unroll
    for (int t2 = 0; t2 < 8; ++t2) q_s[r * 132 + c8 + t2] = bf2f(u[t2]);
  }

  int si = tid >> 2;
  int tjb = tid & 3;
  int sr = tid & 63;
  int dcb = tid >> 6;
  float acc[32] = {};
  float rsum = 0.f;
  float Ms = M_g[(size_t)bn * SS + s0 + si];
  int ntt = (s0 + 64) >> 5;
  const float rsq = 0.08838834764831845f;

  for (int tt0 = 0; tt0 < ntt; ++tt0) {
    int t0 = tt0 * 32;
    __syncthreads();
    for (int idx = tid; idx < 32 * 16; idx += 256) {
      int r = idx >> 4, c8 = (idx & 15) * 8;
      ushort8 uk = *(const ushort8*)&k[rowbase + (size_t)(t0 + r) * II + c8];
      ushort8 uv = *(const ushort8*)&v[rowbase + (size_t)(t0 + r) * II + c8];
#pragma unroll
      for (int t2 = 0; t2 < 8; ++t2) {
        k_s[r * 132 + c8 + t2] = bf2f(uk[t2]);
        v_s[r * 128 + c8 + t2] = bf2f(uv[t2]);
      }
    }
    __syncthreads();
    float wacc[8] = {};
    for (int d = 0; d < 128; d += 4) {
      float4 q4 = *(const float4*)&q_s[si * 132 + d];
#pragma unroll
      for (int j = 0; j < 8; ++j) {
        float4 k4 = *(const float4*)&k_s[(tjb + 4 * j) * 132 + d];
        wacc[j] += q4.x * k4.x + q4.y * k4.y + q4.z * k4.z + q4.w * k4.w;
      }
    }
    int sg = s0 + si;
#pragma unroll
    for (int j = 0; j < 8; ++j) {
      int tg = t0 + tjb + 4 * j;
      float wv = 0.f;
      if (tg <= sg) {
        float ee = e_g[(size_t)bn * SS + tg];
        wv = wacc[j] * rsq * __expf(ee - Ms);
      }
      w_s[si * 33 + tjb + 4 * j] = wv;
    }
    __syncthreads();
    for (int ttj = 0; ttj < 32; ++ttj) {
      float wv = w_s[sr * 33 + ttj];
      rsum += wv;
      const float* vrow = &v_s[ttj * 128 + dcb * 4];
#pragma unroll
      for (int jj = 0; jj < 8; ++jj) {
        float4 v4 = *(const float4*)(vrow + jj * 16);
        acc[jj * 4 + 0] += wv * v4.x;
        acc[jj * 4 + 1] += wv * v4.y;
        acc[jj * 4 + 2] += wv * v4.z;
        acc[jj * 4 + 3] += wv * v4.w;
      }
    }
  }
  if (dcb == 0) {
    float md = maxd_g[(size_t)bn * SS + s0 + sr];
    float nrm = fmaxf(fabsf(rsum), __expf(-md));
    scale_s[sr] = 1.0f / (nrm + 1e-6f);
  }
  __syncthreads();
  float scl = scale_s[sr];
  float* ostage = q_s;
#pragma unroll
  for (int jj = 0; jj < 8; ++jj)
#pragma unroll
    for (int r2 = 0; r2 < 4; ++r2) {
      int c = jj * 16 + dcb * 4 + r2;
      ostage[c * 65 + sr] = acc[jj * 4 + r2] * scl;
    }
  __syncthreads();
  for (int idx = tid; idx < 64 * 128; idx += 256) {
    int r = idx >> 7, c = idx & 127;
    hc[rowbase + (size_t)(s0 + r) * II + c] = ostage[c * 65 + r];
  }
}

// ---------------- groupnorm + skip + silu gate -> bf16 ----------------
__global__ __launch_bounds__(256) void k_gn_skip(const float* __restrict__ hcin,
                                                 const ushort* __restrict__ convact,
                                                 const ushort* __restrict__ up,
                                                 const float* __restrict__ gnw,
                                                 const float* __restrict__ skw,
                                                 ushort* __restrict__ hs) {
  int row = blockIdx.x;
  int tid = threadIdx.x;
  int n = tid >> 5, j = tid & 31;
  float vals[4];
  float s = 0.f, sq = 0.f;
#pragma unroll
  for (int kk2 = 0; kk2 < 4; ++kk2) {
    int i = n * DHH + j + 32 * kk2;
    float vv = hcin[(size_t)row * II + i];
    vals[kk2] = vv;
    s += vv;
    sq += vv * vv;
  }
#pragma unroll
  for (int off2 = 16; off2; off2 >>= 1) {
    s += __shfl_xor(s, off2);
    sq += __shfl_xor(sq, off2);
  }
  float mean = s * (1.0f / DHH);
  float var = sq * (1.0f / DHH) - mean * mean;
  float r = rsqrtf(var + 1e-5f);
#pragma unroll
  for (int kk2 = 0; kk2 < 4; ++kk2) {
    int i = n * DHH + j + 32 * kk2;
    float hn = (vals[kk2] - mean) * r * gnw[i];
    float ca = bf2f(convact[(size_t)row * II + i]);
    float z = bf2f(up[(size_t)row * 2 * II + II + i]);
    float sz = z / (1.0f + __expf(-z));
    hs[(size_t)row * II + i] = f2bf((hn + skw[i] * ca) * sz);
  }
}

// ---------------- final LN(last row) + 2-layer head ----------------
__global__ __launch_bounds__(256) void k_head(const float* __restrict__ h,
                                              const float* __restrict__ pw,
                                              const float* __restrict__ pb,
                                              const float* __restrict__ w1,
                                              const float* __restrict__ b1,
                                              const float* __restrict__ w2,
                                              const float* __restrict__ b2,
                                              float* __restrict__ out) {
  int b = blockIdx.x;
  int tid = threadIdx.x;
  __shared__ float last[DD];
  __shared__ float hid[H1H];
  __shared__ float ss[4], sqs[4];
  const float* row = h + ((size_t)b * SS + SS - 1) * DD;
  float v0 = row[tid], v1 = row[tid + 256];
  float s = v0 + v1, sq = v0 * v0 + v1 * v1;
  for (int off = 32; off; off >>= 1) {
    s += __shfl_down(s, off);
    sq += __shfl_down(sq, off);
  }
  int wid = tid >> 6, lane = tid & 63;
  if (lane == 0) { ss[wid] = s; sqs[wid] = sq; }
  __syncthreads();
  if (tid == 0) {
    ss[0] = ss[0] + ss[1] + ss[2] + ss[3];
    sqs[0] = sqs[0] + sqs[1] + sqs[2] + sqs[3];
  }
  __syncthreads();
  float mean = ss[0] * (1.0f / DD);
  float var = sqs[0] * (1.0f / DD) - mean * mean;
  float r = rsqrtf(var + 1e-5f);
  last[tid] = (v0 - mean) * r * pw[tid] + pb[tid];
  last[tid + 256] = (v1 - mean) * r * pw[tid + 256] + pb[tid + 256];
  __syncthreads();
  if (tid < H1H) {
    float a = b1[tid];
    for (int d2 = 0; d2 < DD; ++d2) a += last[d2] * w1[(size_t)d2 * H1H + tid];
    hid[tid] = fmaxf(a, 0.f);
  }
  __syncthreads();
  if (tid < OUTO) {
    float a = b2[tid];
#pragma unroll
    for (int j2 = 0; j2 < H1H; ++j2) a += hid[j2] * w2[(size_t)j2 * OUTO + tid];
    out[(size_t)b * OUTO + tid] = a;
  }
}

extern "C" void kernel_launch(void* const* d_in, const int* in_sizes, int n_in,
                              void* d_out, int out_size, void* d_ws, size_t ws_size,
                              hipStream_t stream) {
  (void)in_sizes; (void)n_in; (void)out_size; (void)ws_size;
  const float* x    = (const float*)d_in[0];
  const float* in_w = (const float*)d_in[1];
  const float* in_b = (const float*)d_in[2];
  const float* ln_w = (const float*)d_in[3];
  const float* ln_b = (const float*)d_in[4];
  const float* up_w = (const float*)d_in[5];
  const float* conv_w = (const float*)d_in[6];
  const float* conv_b = (const float*)d_in[7];
  const float* q_w  = (const float*)d_in[8];
  const float* k_w  = (const float*)d_in[9];
  const float* v_w  = (const float*)d_in[10];
  const float* ig_w = (const float*)d_in[11];
  const float* ig_b = (const float*)d_in[12];
  const float* fg_w = (const float*)d_in[13];
  const float* fg_b = (const float*)d_in[14];
  const float* gn_w = (const float*)d_in[15];
  const float* sk_w = (const float*)d_in[16];
  const float* dn_w = (const float*)d_in[17];
  const float* po_w = (const float*)d_in[18];
  const float* po_b = (const float*)d_in[19];
  const float* h1_w = (const float*)d_in[20];
  const float* h1_b = (const float*)d_in[21];
  const float* h2_w = (const float*)d_in[22];
  const float* h2_b = (const float*)d_in[23];

  float* h = (float*)d_ws;                              // 2,097,152 f32
  ushort* xn_bf = (ushort*)(h + 2097152);               // 2,097,152 bf16
  ushort* up_bf = xn_bf + 2097152;                      // 8,388,608 bf16
  ushort* conv_bf = up_bf + 8388608;                    // 4,194,304 bf16
  ushort* qb = conv_bf + 4194304;                       // 4,194,304 bf16
  ushort* kb = qb + 4194304;                            // 4,194,304 bf16
  ushort* vb = kb + 4194304;                            // 4,194,304 bf16
  float* hc = (float*)(vb + 4194304);                   // 4,194,304 f32
  ushort* hs_bf = (ushort*)(hc + 4194304);              // 4,194,304 bf16
  ushort* wT = hs_bf + 4194304;                         // 1,048,576 bf16 scratch
  float* igb_ = (float*)(wT + 1048576);                 // 32768 f32 each below
  float* fgb_ = igb_ + 32768;
  float* e_g  = fgb_ + 32768;
  float* M_g  = e_g + 32768;
  float* md_g = M_g + 32768;

  k_in_proj<<<BS, 256, 0, stream>>>(x, in_w, in_b, h);
  for (int l = 0; l < 2; ++l) {
    k_layernorm<<<BS, 256, 0, stream>>>(h, ln_w + l * DD, ln_b + l * DD, xn_bf);
    // up: [4096,512] @ [512,2048]
    k_wt<<<dim3(2 * II / 32, DD / 32), 256, 0, stream>>>(up_w + (size_t)l * DD * 2 * II, wT, DD, 2 * II);
    k_gemm_bf16<<<dim3(2 * II / 128, BS / 128), 256, 0, stream>>>(xn_bf, DD, wT, DD, 2 * II, DD,
                                                                  nullptr, 0, up_bf, 2 * II);
    k_conv_silu<<<BS * II / 256, 256, 0, stream>>>(up_bf, conv_w + l * II * KK, conv_b + l * II, conv_bf);
    // q: conv_act @ q_w
    k_wt<<<dim3(II / 32, II / 32), 256, 0, stream>>>(q_w + (size_t)l * II * II, wT, II, II);
    k_gemm_bf16<<<dim3(II / 128, BS / 128), 256, 0, stream>>>(conv_bf, II, wT, II, II, II,
                                                              nullptr, 0, qb, II);
    // k: conv_act @ k_w
    k_wt<<<dim3(II / 32, II / 32), 256, 0, stream>>>(k_w + (size_t)l * II * II, wT, II, II);
    k_gemm_bf16<<<dim3(II / 128, BS / 128), 256, 0, stream>>>(conv_bf, II, wT, II, II, II,
                                                              nullptr, 0, kb, II);
    // v: x_m @ v_w  (x_m = up_bf[..., :I], lda = 2I)
    k_wt<<<dim3(II / 32, II / 32), 256, 0, stream>>>(v_w + (size_t)l * II * II, wT, II, II);
    k_gemm_bf16<<<dim3(II / 128, BS / 128), 256, 0, stream>>>(up_bf, 2 * II, wT, II, II, II,
                                                              nullptr, 0, vb, II);
    k_gates<<<BS, 256, 0, stream>>>(qb, kb, vb, ig_w + l * 3 * II * NHH, ig_b + l * NHH,
                                    fg_w + l * 3 * II * NHH, fg_b + l * NHH, igb_, fgb_);
    k_scan<<<BB * NHH, 512, 0, stream>>>(igb_, fgb_, e_g, M_g, md_g);
    k_attn<<<dim3(8, BB * NHH), 256, 0, stream>>>(qb, kb, vb, e_g, M_g, md_g, hc);
    k_gn_skip<<<BS, 256, 0, stream>>>(hc, conv_bf, up_bf, gn_w + l * II, sk_w + l * II, hs_bf);
    // down: hs @ down_w, accumulate into h
    k_wt<<<dim3(DD / 32, II / 32), 256, 0, stream>>>(dn_w + (size_t)l * II * DD, wT, II, DD);
    k_gemm_bf16<<<dim3(DD / 128, BS / 128), 256, 0, stream>>>(hs_bf, II, wT, II, DD, II,
                                                              h, 1, nullptr, 0);
  }
  k_head<<<BB, 256, 0, stream>>>(h, po_w, po_b, h1_w, h1_b, h2_w, h2_b, (float*)d_out);
}

// Round 3
// 552.673 us; speedup vs baseline: 3.0557x; 1.6911x over previous
//
#include <hip/hip_runtime.h>
#include <math.h>

#define BB 8
#define SS 512
#define FF 64
#define DD 512
#define II 1024
#define NHH 8
#define KK 4
#define DHH 128
#define H1H 32
#define OUTO 24
#define BS (BB*SS)   // 4096

typedef unsigned short ushort;
typedef __attribute__((ext_vector_type(8))) short short8;
typedef __attribute__((ext_vector_type(8))) unsigned short ushort8;
typedef __attribute__((ext_vector_type(4))) unsigned short ushort4v;
typedef __attribute__((ext_vector_type(4))) float f32x4;

__device__ __forceinline__ float bf2f(ushort u) {
  return __uint_as_float(((unsigned int)u) << 16);
}
__device__ __forceinline__ ushort f2bf(float f) {
  unsigned int u = __float_as_uint(f);
  unsigned int r = u + 0x7fffu + ((u >> 16) & 1u);
  return (ushort)(r >> 16);
}

typedef __attribute__((address_space(1))) const void gvoid;
typedef __attribute__((address_space(3))) void lvoid;
__device__ __forceinline__ void async16(const void* g, void* l) {
  __builtin_amdgcn_global_load_lds((gvoid*)g, (lvoid*)l, 16, 0, 0);
}

// ---------------- input projection: h = x @ in_w + in_b (fp32, tiny K) ----------------
__global__ __launch_bounds__(256) void k_in_proj(const float* __restrict__ x,
                                                 const float* __restrict__ w,
                                                 const float* __restrict__ b,
                                                 float* __restrict__ h) {
  int row = blockIdx.x;
  int tid = threadIdx.x;
  __shared__ float xs[FF];
  if (tid < FF) xs[tid] = x[(size_t)row * FF + tid];
  __syncthreads();
  for (int d = tid; d < DD; d += 256) {
    float acc = b[d];
#pragma unroll 8
    for (int f = 0; f < FF; ++f) acc += xs[f] * w[f * DD + d];
    h[(size_t)row * DD + d] = acc;
  }
}

// ---------------- row layernorm over D=512 -> bf16 out ----------------
__global__ __launch_bounds__(256) void k_layernorm(const float* __restrict__ in,
                                                   const float* __restrict__ w,
                                                   const float* __restrict__ b,
                                                   ushort* __restrict__ out) {
  int row = blockIdx.x;
  int tid = threadIdx.x;
  float v0 = in[(size_t)row * DD + tid];
  float v1 = in[(size_t)row * DD + tid + 256];
  float s = v0 + v1, sq = v0 * v0 + v1 * v1;
  for (int off = 32; off; off >>= 1) {
    s += __shfl_down(s, off);
    sq += __shfl_down(sq, off);
  }
  __shared__ float ss[4], sqs[4];
  int wid = tid >> 6, lane = tid & 63;
  if (lane == 0) { ss[wid] = s; sqs[wid] = sq; }
  __syncthreads();
  if (tid == 0) {
    ss[0] = ss[0] + ss[1] + ss[2] + ss[3];
    sqs[0] = sqs[0] + sqs[1] + sqs[2] + sqs[3];
  }
  __syncthreads();
  float mean = ss[0] * (1.0f / DD);
  float var = sqs[0] * (1.0f / DD) - mean * mean;
  float r = rsqrtf(var + 1e-5f);
  out[(size_t)row * DD + tid] = f2bf((v0 - mean) * r * w[tid] + b[tid]);
  out[(size_t)row * DD + tid + 256] = f2bf((v1 - mean) * r * w[tid + 256] + b[tid + 256]);
}

// ---------------- weight convert+transpose: W[K][N] f32 -> Wt[N][K] bf16 ----------------
__global__ __launch_bounds__(256) void k_wt(const float* __restrict__ W,
                                            ushort* __restrict__ Wt, int Kd, int N) {
  __shared__ float t[32][33];
  int tid = threadIdx.x;
  int n0 = blockIdx.x * 32, k0 = blockIdx.y * 32;
  int c = tid & 31, r8 = tid >> 5;
  for (int rr = r8; rr < 32; rr += 8)
    t[rr][c] = W[(size_t)(k0 + rr) * N + n0 + c];
  __syncthreads();
  for (int rr = r8; rr < 32; rr += 8)
    Wt[(size_t)(n0 + rr) * Kd + k0 + c] = f2bf(t[c][rr]);
}

// ---------------- bf16 MFMA GEMM: C[M,N] = A[M,K](lda) @ Wt[N,K]^T ----------------
// 128x128 tile, BK=32, 4 waves (2x2), each wave 64x64 via 4x4 16x16x32 frags.
// Outputs: Cf (f32, optional accumulate), Cb (bf16 row-major), Ct (bf16 per-head
// transposed [b][n][d][s], only valid for N=II, M=BS).
__global__ __launch_bounds__(256) void k_gemm_bf16(const ushort* __restrict__ A, int lda,
                                                   const ushort* __restrict__ Bt, int ldb,
                                                   int N, int Kd,
                                                   float* __restrict__ Cf, int accumulate,
                                                   ushort* __restrict__ Cb, int ldc,
                                                   ushort* __restrict__ Ct) {
  __shared__ ushort As[128 * 32];
  __shared__ ushort Bs[128 * 32];
  int tid = threadIdx.x;
  int wave = tid >> 6, lane = tid & 63;
  int m0 = blockIdx.y * 128, n0 = blockIdx.x * 128;
  int wm = wave >> 1, wn = wave & 1;
  f32x4 acc[4][4] = {};

  int srow = wave * 32 + (lane >> 2);
  int scol = (lane & 3) * 8;
  const ushort* Ag = A + (size_t)(m0 + srow) * lda + scol;
  const ushort* Bg = Bt + (size_t)(n0 + srow) * ldb + scol;
  ushort* AsW = As + wave * 1024;
  ushort* BsW = Bs + wave * 1024;

  int frow = lane & 15, fk = (lane >> 4) * 8;
  const ushort* ap = As + (size_t)(wm * 64 + frow) * 32 + fk;
  const ushort* bp = Bs + (size_t)(wn * 64 + frow) * 32 + fk;

  for (int kt = 0; kt < Kd; kt += 32) {
    async16(Ag + kt, AsW);
    async16(Ag + kt + (size_t)16 * lda, AsW + 512);
    async16(Bg + kt, BsW);
    async16(Bg + kt + (size_t)16 * ldb, BsW + 512);
    asm volatile("s_waitcnt vmcnt(0)" ::: "memory");
    __syncthreads();
    short8 a[4], b[4];
#pragma unroll
    for (int i = 0; i < 4; ++i) {
      a[i] = *(const short8*)(ap + i * 16 * 32);
      b[i] = *(const short8*)(bp + i * 16 * 32);
    }
#pragma unroll
    for (int i = 0; i < 4; ++i)
#pragma unroll
      for (int j = 0; j < 4; ++j)
        acc[i][j] = __builtin_amdgcn_mfma_f32_16x16x32_bf16(a[i], b[j], acc[i][j], 0, 0, 0);
    __syncthreads();
  }

  int ccol = lane & 15, crow = (lane >> 4) * 4;
#pragma unroll
  for (int i = 0; i < 4; ++i) {
#pragma unroll
    for (int j = 0; j < 4; ++j) {
      int grow = m0 + wm * 64 + i * 16 + crow;
      int gcol = n0 + wn * 64 + j * 16 + ccol;
#pragma unroll
      for (int r = 0; r < 4; ++r) {
        float v = acc[i][j][r];
        if (Cf) {
          size_t idx = (size_t)(grow + r) * N + gcol;
          Cf[idx] = accumulate ? (Cf[idx] + v) : v;
        }
        if (Cb) Cb[(size_t)(grow + r) * ldc + gcol] = f2bf(v);
      }
      if (Ct) {
        int b8 = grow >> 9, sloc = grow & 511;
        int nh = gcol >> 7, d = gcol & 127;
        ushort4v o;
#pragma unroll
        for (int r = 0; r < 4; ++r) o[r] = f2bf(acc[i][j][r]);
        *(ushort4v*)&Ct[((size_t)(b8 * NHH + nh) * DHH + d) * SS + sloc] = o;
      }
    }
  }
}

// ---------------- causal conv (K=4) + SiLU (bf16 in/out) ----------------
__global__ __launch_bounds__(256) void k_conv_silu(const ushort* __restrict__ up,
                                                   const float* __restrict__ cw,
                                                   const float* __restrict__ cb,
                                                   ushort* __restrict__ out) {
  int idx = blockIdx.x * 256 + threadIdx.x;
  int i = idx & (II - 1);
  int row = idx >> 10;
  int s = row & (SS - 1);
  float4 w4 = *(const float4*)(cw + (size_t)i * 4);
  float wj[4] = {w4.x, w4.y, w4.z, w4.w};
  float acc = cb[i];
#pragma unroll
  for (int j = 0; j < 4; ++j) {
    int so = s + j - 3;
    if (so >= 0) acc += bf2f(up[(size_t)(row + j - 3) * (2 * II) + i]) * wj[j];
  }
  float sig = 1.0f / (1.0f + __expf(-acc));
  out[(size_t)row * II + i] = f2bf(acc * sig);
}

// ---------------- gate projections (q,k from fused qkb; v row-major) ----------------
__global__ __launch_bounds__(256) void k_gates(const ushort* __restrict__ qkb,
                                               const ushort* __restrict__ v,
                                               const float* __restrict__ igw,
                                               const float* __restrict__ igb,
                                               const float* __restrict__ fgw,
                                               const float* __restrict__ fgb,
                                               float* __restrict__ ig, float* __restrict__ fg) {
  int row = blockIdx.x;
  int tid = threadIdx.x;
  float pig[NHH] = {}, pfg[NHH] = {};
  for (int c = tid; c < II; c += 256) {
    float qv = bf2f(qkb[(size_t)row * 2048 + c]);
    float kv = bf2f(qkb[(size_t)row * 2048 + II + c]);
    float vv = bf2f(v[(size_t)row * II + c]);
    const float* w0 = igw + (size_t)c * NHH;
    const float* w1 = igw + (size_t)(II + c) * NHH;
    const float* w2 = igw + (size_t)(2 * II + c) * NHH;
    const float* f0 = fgw + (size_t)c * NHH;
    const float* f1 = fgw + (size_t)(II + c) * NHH;
    const float* f2 = fgw + (size_t)(2 * II + c) * NHH;
#pragma unroll
    for (int n = 0; n < NHH; ++n) {
      pig[n] += qv * w0[n] + kv * w1[n] + vv * w2[n];
      pfg[n] += qv * f0[n] + kv * f1[n] + vv * f2[n];
    }
  }
  for (int off = 32; off; off >>= 1) {
#pragma unroll
    for (int n = 0; n < NHH; ++n) {
      pig[n] += __shfl_down(pig[n], off);
      pfg[n] += __shfl_down(pfg[n], off);
    }
  }
  __shared__ float red[2 * NHH][4];
  int wid = tid >> 6, lane = tid & 63;
  if (lane == 0) {
#pragma unroll
    for (int n = 0; n < NHH; ++n) {
      red[n][wid] = pig[n];
      red[NHH + n][wid] = pfg[n];
    }
  }
  __syncthreads();
  int b = row / SS, s = row & (SS - 1);
  if (tid < NHH) {
    float a = red[tid][0] + red[tid][1] + red[tid][2] + red[tid][3];
    ig[((size_t)b * NHH + tid) * SS + s] = a + igb[tid];
  } else if (tid >= 64 && tid < 64 + NHH) {
    int n = tid - 64;
    float a = red[NHH + n][0] + red[NHH + n][1] + red[NHH + n][2] + red[NHH + n][3];
    fg[((size_t)b * NHH + n) * SS + s] = a + fgb[n];
  }
}

// ---------------- per-(b,n) scan ----------------
__global__ __launch_bounds__(512) void k_scan(const float* __restrict__ ig,
                                              const float* __restrict__ fg,
                                              float* __restrict__ e_g, float* __restrict__ M_g,
                                              float* __restrict__ maxd_g) {
  int bn = blockIdx.x;
  int t = threadIdx.x;
  __shared__ float buf[SS];
  float f = fg[(size_t)bn * SS + t];
  float lf = (f >= 0.f) ? -log1pf(expf(-f)) : (f - log1pf(expf(f)));
  buf[t] = lf;
  __syncthreads();
  for (int off = 1; off < SS; off <<= 1) {
    float val = buf[t];
    if (t >= off) val += buf[t - off];
    __syncthreads();
    buf[t] = val;
    __syncthreads();
  }
  float cs = buf[t];
  float e = ig[(size_t)bn * SS + t] - cs;
  __syncthreads();
  buf[t] = e;
  __syncthreads();
  for (int off = 1; off < SS; off <<= 1) {
    float val = buf[t];
    if (t >= off) val = fmaxf(val, buf[t - off]);
    __syncthreads();
    buf[t] = val;
    __syncthreads();
  }
  float M = buf[t];
  e_g[(size_t)bn * SS + t] = e;
  M_g[(size_t)bn * SS + t] = M;
  maxd_g[(size_t)bn * SS + t] = cs + M;
}

// ---------------- mLSTM attention, MFMA bf16 ----------------
// grid (8 stiles, 64 bn), block 256 (4 waves x 16 Q-rows). KV tile 64.
__global__ __launch_bounds__(256) void k_attn_mfma(const ushort* __restrict__ qkb,
                                                   const ushort* __restrict__ vbt,
                                                   const float* __restrict__ e_g,
                                                   const float* __restrict__ M_g,
                                                   const float* __restrict__ maxd_g,
                                                   float* __restrict__ hc) {
  __shared__ ushort K_s[64 * 136];      // [t][d], pad->136 (272B rows, 16B aligned)
  __shared__ ushort Vt_s[128 * 72];     // [d][t], pad->72 (144B rows)
  __shared__ ushort w_s[4 * 16 * 72];   // per-wave [16 s][t], pad->72
  __shared__ float e_s[64];

  int tid = threadIdx.x;
  int wave = tid >> 6, lane = tid & 63;
  int xb = blockIdx.x;
  int stile = (xb & 1) ? (7 - (xb >> 1)) : (xb >> 1);
  int bn = blockIdx.y;
  int b = bn >> 3, n = bn & 7;
  int s0 = stile * 64;

  const size_t qbase = (size_t)(b * SS) * 2048 + (size_t)n * DHH;
  const size_t kbase = qbase + II;
  const size_t vtbase = (size_t)bn * DHH * SS;
  const size_t hcbase = (size_t)(b * SS) * II + (size_t)n * DHH;

  int l15 = lane & 15, lg = lane >> 4;
  int kg8 = lg * 8;
  int crow = lg * 4;
  int srow_base = s0 + wave * 16 + crow;  // + r

  // Q fragments straight from global (row = lane&15 within wave's 16 rows)
  short8 qf[4];
  {
    int qrow = s0 + wave * 16 + l15;
#pragma unroll
    for (int ks = 0; ks < 4; ++ks)
      qf[ks] = *(const short8*)&qkb[qbase + (size_t)qrow * 2048 + ks * 32 + kg8];
  }
  float Ms[4], md[4];
#pragma unroll
  for (int r = 0; r < 4; ++r) {
    Ms[r] = M_g[(size_t)bn * SS + srow_base + r];
    md[r] = maxd_g[(size_t)bn * SS + srow_base + r];
  }

  f32x4 acc[8] = {};
  float rsum[4] = {};
  const float rsq = 0.08838834764831845f;  // 1/sqrt(128)
  ushort* w_w = w_s + wave * 16 * 72;

  int ntt = stile + 1;
  for (int tt = 0; tt < ntt; ++tt) {
    int t0 = tt * 64;
    __syncthreads();  // all waves done reading K_s/Vt_s of prev tile
    for (int task = tid; task < 1024; task += 256) {
      int r = task >> 4, c8 = (task & 15) * 8;
      *(ushort8*)&K_s[r * 136 + c8] =
          *(const ushort8*)&qkb[kbase + (size_t)(t0 + r) * 2048 + c8];
    }
    for (int task = tid; task < 1024; task += 256) {
      int d = task >> 3, c8 = (task & 7) * 8;
      *(ushort8*)&Vt_s[d * 72 + c8] =
          *(const ushort8*)&vbt[vtbase + (size_t)d * SS + t0 + c8];
    }
    if (tid < 64) e_s[tid] = e_g[(size_t)bn * SS + t0 + tid];
    __syncthreads();

    // QK^T: S-tile 16x64 per wave (4 col-tiles x 4 k-slices)
    f32x4 s4[4];
#pragma unroll
    for (int ct = 0; ct < 4; ++ct) {
      f32x4 c = {};
#pragma unroll
      for (int ks = 0; ks < 4; ++ks) {
        short8 kf = *(const short8*)&K_s[(l15 + 16 * ct) * 136 + ks * 32 + kg8];
        c = __builtin_amdgcn_mfma_f32_16x16x32_bf16(qf[ks], kf, c, 0, 0, 0);
      }
      s4[ct] = c;
    }
    // decay + mask + row-sum + spill w to LDS (bf16)
#pragma unroll
    for (int ct = 0; ct < 4; ++ct) {
      float e = e_s[l15 + 16 * ct];
      int t = t0 + l15 + 16 * ct;
      float part[4];
#pragma unroll
      for (int r = 0; r < 4; ++r) {
        int s = srow_base + r;
        float val = (t <= s) ? s4[ct][r] * rsq * __expf(e - Ms[r]) : 0.f;
        part[r] = val;
        w_w[(crow + r) * 72 + l15 + 16 * ct] = f2bf(val);
      }
      s4[ct][0] = part[0]; s4[ct][1] = part[1]; s4[ct][2] = part[2]; s4[ct][3] = part[3];
    }
#pragma unroll
    for (int r = 0; r < 4; ++r) {
      float tmp = s4[0][r] + s4[1][r] + s4[2][r] + s4[3][r];
      tmp += __shfl_xor(tmp, 1);
      tmp += __shfl_xor(tmp, 2);
      tmp += __shfl_xor(tmp, 4);
      tmp += __shfl_xor(tmp, 8);
      rsum[r] += tmp;
    }
    // PV: acc[s][d] += w @ V   (w a-frags from own wave's LDS region)
    short8 wf0 = *(const short8*)&w_w[l15 * 72 + kg8];
    short8 wf1 = *(const short8*)&w_w[l15 * 72 + 32 + kg8];
#pragma unroll
    for (int dt = 0; dt < 8; ++dt) {
      short8 vf0 = *(const short8*)&Vt_s[(dt * 16 + l15) * 72 + kg8];
      short8 vf1 = *(const short8*)&Vt_s[(dt * 16 + l15) * 72 + 32 + kg8];
      acc[dt] = __builtin_amdgcn_mfma_f32_16x16x32_bf16(wf0, vf0, acc[dt], 0, 0, 0);
      acc[dt] = __builtin_amdgcn_mfma_f32_16x16x32_bf16(wf1, vf1, acc[dt], 0, 0, 0);
    }
  }

  float scl[4];
#pragma unroll
  for (int r = 0; r < 4; ++r) {
    float nrm = fmaxf(fabsf(rsum[r]), __expf(-md[r]));
    scl[r] = 1.0f / (nrm + 1e-6f);
  }
#pragma unroll
  for (int dt = 0; dt < 8; ++dt)
#pragma unroll
    for (int r = 0; r < 4; ++r)
      hc[hcbase + (size_t)(srow_base + r) * II + dt * 16 + l15] = acc[dt][r] * scl[r];
}

// ---------------- groupnorm + skip + silu gate -> bf16 ----------------
__global__ __launch_bounds__(256) void k_gn_skip(const float* __restrict__ hcin,
                                                 const ushort* __restrict__ convact,
                                                 const ushort* __restrict__ up,
                                                 const float* __restrict__ gnw,
                                                 const float* __restrict__ skw,
                                                 ushort* __restrict__ hs) {
  int row = blockIdx.x;
  int tid = threadIdx.x;
  int n = tid >> 5, j = tid & 31;
  float vals[4];
  float s = 0.f, sq = 0.f;
#pragma unroll
  for (int kk2 = 0; kk2 < 4; ++kk2) {
    int i = n * DHH + j + 32 * kk2;
    float vv = hcin[(size_t)row * II + i];
    vals[kk2] = vv;
    s += vv;
    sq += vv * vv;
  }
#pragma unroll
  for (int off2 = 16; off2; off2 >>= 1) {
    s += __shfl_xor(s, off2);
    sq += __shfl_xor(sq, off2);
  }
  float mean = s * (1.0f / DHH);
  float var = sq * (1.0f / DHH) - mean * mean;
  float r = rsqrtf(var + 1e-5f);
#pragma unroll
  for (int kk2 = 0; kk2 < 4; ++kk2) {
    int i = n * DHH + j + 32 * kk2;
    float hn = (vals[kk2] - mean) * r * gnw[i];
    float ca = bf2f(convact[(size_t)row * II + i]);
    float z = bf2f(up[(size_t)row * 2 * II + II + i]);
    float sz = z / (1.0f + __expf(-z));
    hs[(size_t)row * II + i] = f2bf((hn + skw[i] * ca) * sz);
  }
}

// ---------------- final LN(last row) + 2-layer head ----------------
__global__ __launch_bounds__(256) void k_head(const float* __restrict__ h,
                                              const float* __restrict__ pw,
                                              const float* __restrict__ pb,
                                              const float* __restrict__ w1,
                                              const float* __restrict__ b1,
                                              const float* __restrict__ w2,
                                              const float* __restrict__ b2,
                                              float* __restrict__ out) {
  int b = blockIdx.x;
  int tid = threadIdx.x;
  __shared__ float last[DD];
  __shared__ float hid[H1H];
  __shared__ float ss[4], sqs[4];
  const float* row = h + ((size_t)b * SS + SS - 1) * DD;
  float v0 = row[tid], v1 = row[tid + 256];
  float s = v0 + v1, sq = v0 * v0 + v1 * v1;
  for (int off = 32; off; off >>= 1) {
    s += __shfl_down(s, off);
    sq += __shfl_down(sq, off);
  }
  int wid = tid >> 6, lane = tid & 63;
  if (lane == 0) { ss[wid] = s; sqs[wid] = sq; }
  __syncthreads();
  if (tid == 0) {
    ss[0] = ss[0] + ss[1] + ss[2] + ss[3];
    sqs[0] = sqs[0] + sqs[1] + sqs[2] + sqs[3];
  }
  __syncthreads();
  float mean = ss[0] * (1.0f / DD);
  float var = sqs[0] * (1.0f / DD) - mean * mean;
  float r = rsqrtf(var + 1e-5f);
  last[tid] = (v0 - mean) * r * pw[tid] + pb[tid];
  last[tid + 256] = (v1 - mean) * r * pw[tid + 256] + pb[tid + 256];
  __syncthreads();
  if (tid < H1H) {
    float a = b1[tid];
    for (int d2 = 0; d2 < DD; ++d2) a += last[d2] * w1[(size_t)d2 * H1H + tid];
    hid[tid] = fmaxf(a, 0.f);
  }
  __syncthreads();
  if (tid < OUTO) {
    float a = b2[tid];
#pragma unroll
    for (int j2 = 0; j2 < H1H; ++j2) a += hid[j2] * w2[(size_t)j2 * OUTO + tid];
    out[(size_t)b * OUTO + tid] = a;
  }
}

extern "C" void kernel_launch(void* const* d_in, const int* in_sizes, int n_in,
                              void* d_out, int out_size, void* d_ws, size_t ws_size,
                              hipStream_t stream) {
  (void)in_sizes; (void)n_in; (void)out_size; (void)ws_size;
  const float* x    = (const float*)d_in[0];
  const float* in_w = (const float*)d_in[1];
  const float* in_b = (const float*)d_in[2];
  const float* ln_w = (const float*)d_in[3];
  const float* ln_b = (const float*)d_in[4];
  const float* up_w = (const float*)d_in[5];
  const float* conv_w = (const float*)d_in[6];
  const float* conv_b = (const float*)d_in[7];
  const float* q_w  = (const float*)d_in[8];
  const float* k_w  = (const float*)d_in[9];
  const float* v_w  = (const float*)d_in[10];
  const float* ig_w = (const float*)d_in[11];
  const float* ig_b = (const float*)d_in[12];
  const float* fg_w = (const float*)d_in[13];
  const float* fg_b = (const float*)d_in[14];
  const float* gn_w = (const float*)d_in[15];
  const float* sk_w = (const float*)d_in[16];
  const float* dn_w = (const float*)d_in[17];
  const float* po_w = (const float*)d_in[18];
  const float* po_b = (const float*)d_in[19];
  const float* h1_w = (const float*)d_in[20];
  const float* h1_b = (const float*)d_in[21];
  const float* h2_w = (const float*)d_in[22];
  const float* h2_b = (const float*)d_in[23];

  float* h = (float*)d_ws;                              // 2,097,152 f32
  ushort* xn_bf = (ushort*)(h + 2097152);               // 2,097,152 bf16
  ushort* up_bf = xn_bf + 2097152;                      // 8,388,608 bf16
  ushort* conv_bf = up_bf + 8388608;                    // 4,194,304 bf16
  ushort* qkb = conv_bf + 4194304;                      // 8,388,608 bf16 (q | k fused)
  ushort* vb = qkb + 8388608;                           // 4,194,304 bf16
  ushort* vbt = vb + 4194304;                           // 4,194,304 bf16 (per-head V^T)
  float* hc = (float*)(vbt + 4194304);                  // 4,194,304 f32
  ushort* hs_bf = (ushort*)(hc + 4194304);              // 4,194,304 bf16
  ushort* wT = hs_bf + 4194304;                         // 2,097,152 bf16 scratch
  float* igb_ = (float*)(wT + 2097152);
  float* fgb_ = igb_ + 32768;
  float* e_g  = fgb_ + 32768;
  float* M_g  = e_g + 32768;
  float* md_g = M_g + 32768;

  k_in_proj<<<BS, 256, 0, stream>>>(x, in_w, in_b, h);
  for (int l = 0; l < 2; ++l) {
    k_layernorm<<<BS, 256, 0, stream>>>(h, ln_w + l * DD, ln_b + l * DD, xn_bf);
    // up: [4096,512] @ [512,2048]
    k_wt<<<dim3(2 * II / 32, DD / 32), 256, 0, stream>>>(up_w + (size_t)l * DD * 2 * II, wT, DD, 2 * II);
    k_gemm_bf16<<<dim3(2 * II / 128, BS / 128), 256, 0, stream>>>(xn_bf, DD, wT, DD, 2 * II, DD,
                                                                  nullptr, 0, up_bf, 2 * II, nullptr);
    k_conv_silu<<<BS * II / 256, 256, 0, stream>>>(up_bf, conv_w + l * II * KK, conv_b + l * II, conv_bf);
    // q|k fused: conv_act @ [q_w k_w]  -> qkb [4096][2048]
    k_wt<<<dim3(II / 32, II / 32), 256, 0, stream>>>(q_w + (size_t)l * II * II, wT, II, II);
    k_wt<<<dim3(II / 32, II / 32), 256, 0, stream>>>(k_w + (size_t)l * II * II, wT + (size_t)II * II, II, II);
    k_gemm_bf16<<<dim3(2 * II / 128, BS / 128), 256, 0, stream>>>(conv_bf, II, wT, II, 2 * II, II,
                                                                  nullptr, 0, qkb, 2 * II, nullptr);
    // v: x_m @ v_w (x_m = up_bf[..., :I], lda = 2I); row-major vb + per-head V^T vbt
    k_wt<<<dim3(II / 32, II / 32), 256, 0, stream>>>(v_w + (size_t)l * II * II, wT, II, II);
    k_gemm_bf16<<<dim3(II / 128, BS / 128), 256, 0, stream>>>(up_bf, 2 * II, wT, II, II, II,
                                                              nullptr, 0, vb, II, vbt);
    k_gates<<<BS, 256, 0, stream>>>(qkb, vb, ig_w + l * 3 * II * NHH, ig_b + l * NHH,
                                    fg_w + l * 3 * II * NHH, fg_b + l * NHH, igb_, fgb_);
    k_scan<<<BB * NHH, 512, 0, stream>>>(igb_, fgb_, e_g, M_g, md_g);
    k_attn_mfma<<<dim3(8, BB * NHH), 256, 0, stream>>>(qkb, vbt, e_g, M_g, md_g, hc);
    k_gn_skip<<<BS, 256, 0, stream>>>(hc, conv_bf, up_bf, gn_w + l * II, sk_w + l * II, hs_bf);
    // down: hs @ down_w, accumulate into h
    k_wt<<<dim3(DD / 32, II / 32), 256, 0, stream>>>(dn_w + (size_t)l * II * DD, wT, II, DD);
    k_gemm_bf16<<<dim3(DD / 128, BS / 128), 256, 0, stream>>>(hs_bf, II, wT, II, DD, II,
                                                              h, 1, nullptr, 0, nullptr);
  }
  k_head<<<BB, 256, 0, stream>>>(h, po_w, po_b, h1_w, h1_b, h2_w, h2_b, (float*)d_out);
}

// Round 4
// 502.740 us; speedup vs baseline: 3.3592x; 1.0993x over previous
//
#include <hip/hip_runtime.h>
#include <math.h>

#define BB 8
#define SS 512
#define FF 64
#define DD 512
#define II 1024
#define NHH 8
#define KK 4
#define DHH 128
#define H1H 32
#define OUTO 24
#define BS (BB*SS)   // 4096

typedef unsigned short ushort;
typedef __attribute__((ext_vector_type(8))) short short8;
typedef __attribute__((ext_vector_type(8))) unsigned short ushort8;
typedef __attribute__((ext_vector_type(4))) unsigned short ushort4v;
typedef __attribute__((ext_vector_type(4))) float f32x4;

__device__ __forceinline__ float bf2f(ushort u) {
  return __uint_as_float(((unsigned int)u) << 16);
}
__device__ __forceinline__ ushort f2bf(float f) {
  unsigned int u = __float_as_uint(f);
  unsigned int r = u + 0x7fffu + ((u >> 16) & 1u);
  return (ushort)(r >> 16);
}

typedef __attribute__((address_space(1))) const void gvoid;
typedef __attribute__((address_space(3))) void lvoid;
__device__ __forceinline__ void async16(const void* g, void* l) {
  __builtin_amdgcn_global_load_lds((gvoid*)g, (lvoid*)l, 16, 0, 0);
}

// ---------------- input projection: h = x @ in_w + in_b (fp32, tiny K) ----------------
__global__ __launch_bounds__(256) void k_in_proj(const float* __restrict__ x,
                                                 const float* __restrict__ w,
                                                 const float* __restrict__ b,
                                                 float* __restrict__ h) {
  int row = blockIdx.x;
  int tid = threadIdx.x;
  __shared__ float xs[FF];
  if (tid < FF) xs[tid] = x[(size_t)row * FF + tid];
  __syncthreads();
  for (int d = tid; d < DD; d += 256) {
    float acc = b[d];
#pragma unroll 8
    for (int f = 0; f < FF; ++f) acc += xs[f] * w[f * DD + d];
    h[(size_t)row * DD + d] = acc;
  }
}

// ---------------- row layernorm over D=512 -> bf16 out ----------------
__global__ __launch_bounds__(256) void k_layernorm(const float* __restrict__ in,
                                                   const float* __restrict__ w,
                                                   const float* __restrict__ b,
                                                   ushort* __restrict__ out) {
  int row = blockIdx.x;
  int tid = threadIdx.x;
  float v0 = in[(size_t)row * DD + tid];
  float v1 = in[(size_t)row * DD + tid + 256];
  float s = v0 + v1, sq = v0 * v0 + v1 * v1;
  for (int off = 32; off; off >>= 1) {
    s += __shfl_down(s, off);
    sq += __shfl_down(sq, off);
  }
  __shared__ float ss[4], sqs[4];
  int wid = tid >> 6, lane = tid & 63;
  if (lane == 0) { ss[wid] = s; sqs[wid] = sq; }
  __syncthreads();
  if (tid == 0) {
    ss[0] = ss[0] + ss[1] + ss[2] + ss[3];
    sqs[0] = sqs[0] + sqs[1] + sqs[2] + sqs[3];
  }
  __syncthreads();
  float mean = ss[0] * (1.0f / DD);
  float var = sqs[0] * (1.0f / DD) - mean * mean;
  float r = rsqrtf(var + 1e-5f);
  out[(size_t)row * DD + tid] = f2bf((v0 - mean) * r * w[tid] + b[tid]);
  out[(size_t)row * DD + tid + 256] = f2bf((v1 - mean) * r * w[tid + 256] + b[tid + 256]);
}

// ---------------- weight convert+transpose: W[K][N] f32 -> Wt[N][K] bf16 ----------------
__global__ __launch_bounds__(256) void k_wt(const float* __restrict__ W,
                                            ushort* __restrict__ Wt, int Kd, int N) {
  __shared__ float t[32][33];
  int tid = threadIdx.x;
  int n0 = blockIdx.x * 32, k0 = blockIdx.y * 32;
  int c = tid & 31, r8 = tid >> 5;
  for (int rr = r8; rr < 32; rr += 8)
    t[rr][c] = W[(size_t)(k0 + rr) * N + n0 + c];
  __syncthreads();
  for (int rr = r8; rr < 32; rr += 8)
    Wt[(size_t)(n0 + rr) * Kd + k0 + c] = f2bf(t[c][rr]);
}

// ---------------- bf16 MFMA GEMM: C[M,N] = A[M,K](lda) @ Wt[N,K]^T ----------------
__global__ __launch_bounds__(256) void k_gemm_bf16(const ushort* __restrict__ A, int lda,
                                                   const ushort* __restrict__ Bt, int ldb,
                                                   int N, int Kd,
                                                   float* __restrict__ Cf, int accumulate,
                                                   ushort* __restrict__ Cb, int ldc,
                                                   ushort* __restrict__ Ct) {
  __shared__ ushort As[128 * 32];
  __shared__ ushort Bs[128 * 32];
  int tid = threadIdx.x;
  int wave = tid >> 6, lane = tid & 63;
  int m0 = blockIdx.y * 128, n0 = blockIdx.x * 128;
  int wm = wave >> 1, wn = wave & 1;
  f32x4 acc[4][4] = {};

  int srow = wave * 32 + (lane >> 2);
  int scol = (lane & 3) * 8;
  const ushort* Ag = A + (size_t)(m0 + srow) * lda + scol;
  const ushort* Bg = Bt + (size_t)(n0 + srow) * ldb + scol;
  ushort* AsW = As + wave * 1024;
  ushort* BsW = Bs + wave * 1024;

  int frow = lane & 15, fk = (lane >> 4) * 8;
  const ushort* ap = As + (size_t)(wm * 64 + frow) * 32 + fk;
  const ushort* bp = Bs + (size_t)(wn * 64 + frow) * 32 + fk;

  for (int kt = 0; kt < Kd; kt += 32) {
    async16(Ag + kt, AsW);
    async16(Ag + kt + (size_t)16 * lda, AsW + 512);
    async16(Bg + kt, BsW);
    async16(Bg + kt + (size_t)16 * ldb, BsW + 512);
    asm volatile("s_waitcnt vmcnt(0)" ::: "memory");
    __syncthreads();
    short8 a[4], b[4];
#pragma unroll
    for (int i = 0; i < 4; ++i) {
      a[i] = *(const short8*)(ap + i * 16 * 32);
      b[i] = *(const short8*)(bp + i * 16 * 32);
    }
#pragma unroll
    for (int i = 0; i < 4; ++i)
#pragma unroll
      for (int j = 0; j < 4; ++j)
        acc[i][j] = __builtin_amdgcn_mfma_f32_16x16x32_bf16(a[i], b[j], acc[i][j], 0, 0, 0);
    __syncthreads();
  }

  int ccol = lane & 15, crow = (lane >> 4) * 4;
#pragma unroll
  for (int i = 0; i < 4; ++i) {
#pragma unroll
    for (int j = 0; j < 4; ++j) {
      int grow = m0 + wm * 64 + i * 16 + crow;
      int gcol = n0 + wn * 64 + j * 16 + ccol;
#pragma unroll
      for (int r = 0; r < 4; ++r) {
        float v = acc[i][j][r];
        if (Cf) {
          size_t idx = (size_t)(grow + r) * N + gcol;
          Cf[idx] = accumulate ? (Cf[idx] + v) : v;
        }
        if (Cb) Cb[(size_t)(grow + r) * ldc + gcol] = f2bf(v);
      }
      if (Ct) {
        int b8 = grow >> 9, sloc = grow & 511;
        int nh = gcol >> 7, d = gcol & 127;
        ushort4v o;
#pragma unroll
        for (int r = 0; r < 4; ++r) o[r] = f2bf(acc[i][j][r]);
        *(ushort4v*)&Ct[((size_t)(b8 * NHH + nh) * DHH + d) * SS + sloc] = o;
      }
    }
  }
}

// ---------------- causal conv (K=4) + SiLU (bf16 in/out) ----------------
__global__ __launch_bounds__(256) void k_conv_silu(const ushort* __restrict__ up,
                                                   const float* __restrict__ cw,
                                                   const float* __restrict__ cb,
                                                   ushort* __restrict__ out) {
  int idx = blockIdx.x * 256 + threadIdx.x;
  int i = idx & (II - 1);
  int row = idx >> 10;
  int s = row & (SS - 1);
  float4 w4 = *(const float4*)(cw + (size_t)i * 4);
  float wj[4] = {w4.x, w4.y, w4.z, w4.w};
  float acc = cb[i];
#pragma unroll
  for (int j = 0; j < 4; ++j) {
    int so = s + j - 3;
    if (so >= 0) acc += bf2f(up[(size_t)(row + j - 3) * (2 * II) + i]) * wj[j];
  }
  float sig = 1.0f / (1.0f + __expf(-acc));
  out[(size_t)row * II + i] = f2bf(acc * sig);
}

// ---------------- gate weight pack: ig_w/fg_w [3072][8] f32 -> Wg[16][3072] bf16 ----------------
__global__ __launch_bounds__(256) void k_wtg(const float* __restrict__ igw,
                                             const float* __restrict__ fgw,
                                             ushort* __restrict__ Wg) {
  int k = blockIdx.x * 256 + threadIdx.x;  // 0..3071
  if (k >= 3 * II) return;
#pragma unroll
  for (int o = 0; o < NHH; ++o) {
    Wg[(size_t)o * (3 * II) + k] = f2bf(igw[(size_t)k * NHH + o]);
    Wg[(size_t)(NHH + o) * (3 * II) + k] = f2bf(fgw[(size_t)k * NHH + o]);
  }
}

// ---------------- gate projections via MFMA: C[4096,16] = [q|k|v] @ Wg^T ----------------
// 1 wave per block, 16 rows per block, grid 256.
__global__ __launch_bounds__(64) void k_gates_mfma(const ushort* __restrict__ qkb,
                                                   const ushort* __restrict__ vb,
                                                   const ushort* __restrict__ Wg,
                                                   const float* __restrict__ igb,
                                                   const float* __restrict__ fgb,
                                                   float* __restrict__ ig,
                                                   float* __restrict__ fg) {
  int lane = threadIdx.x;
  int row0 = blockIdx.x * 16;
  int l15 = lane & 15, lg = lane >> 4;
  int arow = row0 + l15;
  const ushort* qrow = qkb + (size_t)arow * 2048 + lg * 8;
  const ushort* vrow = vb + (size_t)arow * II + lg * 8;
  const ushort* wrow = Wg + (size_t)l15 * (3 * II) + lg * 8;
  f32x4 acc0 = {}, acc1 = {};
#pragma unroll 4
  for (int k = 0; k < 2048; k += 64) {
    short8 a0 = *(const short8*)(qrow + k);
    short8 b0 = *(const short8*)(wrow + k);
    short8 a1 = *(const short8*)(qrow + k + 32);
    short8 b1 = *(const short8*)(wrow + k + 32);
    acc0 = __builtin_amdgcn_mfma_f32_16x16x32_bf16(a0, b0, acc0, 0, 0, 0);
    acc1 = __builtin_amdgcn_mfma_f32_16x16x32_bf16(a1, b1, acc1, 0, 0, 0);
  }
#pragma unroll 4
  for (int k = 0; k < 1024; k += 64) {
    short8 a0 = *(const short8*)(vrow + k);
    short8 b0 = *(const short8*)(wrow + 2048 + k);
    short8 a1 = *(const short8*)(vrow + k + 32);
    short8 b1 = *(const short8*)(wrow + 2048 + k + 32);
    acc0 = __builtin_amdgcn_mfma_f32_16x16x32_bf16(a0, b0, acc0, 0, 0, 0);
    acc1 = __builtin_amdgcn_mfma_f32_16x16x32_bf16(a1, b1, acc1, 0, 0, 0);
  }
  int o = l15;
#pragma unroll
  for (int r = 0; r < 4; ++r) {
    int row = row0 + lg * 4 + r;
    int bb = row >> 9, s = row & (SS - 1);
    float val = acc0[r] + acc1[r];
    if (o < NHH)
      ig[((size_t)bb * NHH + o) * SS + s] = val + igb[o];
    else
      fg[((size_t)bb * NHH + (o - NHH)) * SS + s] = val + fgb[o - NHH];
  }
}

// ---------------- per-(b,n) scan ----------------
__global__ __launch_bounds__(512) void k_scan(const float* __restrict__ ig,
                                              const float* __restrict__ fg,
                                              float* __restrict__ e_g, float* __restrict__ M_g,
                                              float* __restrict__ maxd_g) {
  int bn = blockIdx.x;
  int t = threadIdx.x;
  __shared__ float buf[SS];
  float f = fg[(size_t)bn * SS + t];
  float lf = (f >= 0.f) ? -log1pf(expf(-f)) : (f - log1pf(expf(f)));
  buf[t] = lf;
  __syncthreads();
  for (int off = 1; off < SS; off <<= 1) {
    float val = buf[t];
    if (t >= off) val += buf[t - off];
    __syncthreads();
    buf[t] = val;
    __syncthreads();
  }
  float cs = buf[t];
  float e = ig[(size_t)bn * SS + t] - cs;
  __syncthreads();
  buf[t] = e;
  __syncthreads();
  for (int off = 1; off < SS; off <<= 1) {
    float val = buf[t];
    if (t >= off) val = fmaxf(val, buf[t - off]);
    __syncthreads();
    buf[t] = val;
    __syncthreads();
  }
  float M = buf[t];
  e_g[(size_t)bn * SS + t] = e;
  M_g[(size_t)bn * SS + t] = M;
  maxd_g[(size_t)bn * SS + t] = cs + M;
}

// ---------------- mLSTM attention, MFMA bf16 ----------------
__global__ __launch_bounds__(256) void k_attn_mfma(const ushort* __restrict__ qkb,
                                                   const ushort* __restrict__ vbt,
                                                   const float* __restrict__ e_g,
                                                   const float* __restrict__ M_g,
                                                   const float* __restrict__ maxd_g,
                                                   float* __restrict__ hc) {
  __shared__ ushort K_s[64 * 136];
  __shared__ ushort Vt_s[128 * 72];
  __shared__ ushort w_s[4 * 16 * 72];
  __shared__ float e_s[64];

  int tid = threadIdx.x;
  int wave = tid >> 6, lane = tid & 63;
  int xb = blockIdx.x;
  int stile = (xb & 1) ? (7 - (xb >> 1)) : (xb >> 1);
  int bn = blockIdx.y;
  int b = bn >> 3, n = bn & 7;
  int s0 = stile * 64;

  const size_t qbase = (size_t)(b * SS) * 2048 + (size_t)n * DHH;
  const size_t kbase = qbase + II;
  const size_t vtbase = (size_t)bn * DHH * SS;
  const size_t hcbase = (size_t)(b * SS) * II + (size_t)n * DHH;

  int l15 = lane & 15, lg = lane >> 4;
  int kg8 = lg * 8;
  int crow = lg * 4;
  int srow_base = s0 + wave * 16 + crow;

  short8 qf[4];
  {
    int qrow = s0 + wave * 16 + l15;
#pragma unroll
    for (int ks = 0; ks < 4; ++ks)
      qf[ks] = *(const short8*)&qkb[qbase + (size_t)qrow * 2048 + ks * 32 + kg8];
  }
  float Ms[4], md[4];
#pragma unroll
  for (int r = 0; r < 4; ++r) {
    Ms[r] = M_g[(size_t)bn * SS + srow_base + r];
    md[r] = maxd_g[(size_t)bn * SS + srow_base + r];
  }

  f32x4 acc[8] = {};
  float rsum[4] = {};
  const float rsq = 0.08838834764831845f;
  ushort* w_w = w_s + wave * 16 * 72;

  int ntt = stile + 1;
  for (int tt = 0; tt < ntt; ++tt) {
    int t0 = tt * 64;
    __syncthreads();
    for (int task = tid; task < 1024; task += 256) {
      int r = task >> 4, c8 = (task & 15) * 8;
      *(ushort8*)&K_s[r * 136 + c8] =
          *(const ushort8*)&qkb[kbase + (size_t)(t0 + r) * 2048 + c8];
    }
    for (int task = tid; task < 1024; task += 256) {
      int d = task >> 3, c8 = (task & 7) * 8;
      *(ushort8*)&Vt_s[d * 72 + c8] =
          *(const ushort8*)&vbt[vtbase + (size_t)d * SS + t0 + c8];
    }
    if (tid < 64) e_s[tid] = e_g[(size_t)bn * SS + t0 + tid];
    __syncthreads();

    f32x4 s4[4];
#pragma unroll
    for (int ct = 0; ct < 4; ++ct) {
      f32x4 c = {};
#pragma unroll
      for (int ks = 0; ks < 4; ++ks) {
        short8 kf = *(const short8*)&K_s[(l15 + 16 * ct) * 136 + ks * 32 + kg8];
        c = __builtin_amdgcn_mfma_f32_16x16x32_bf16(qf[ks], kf, c, 0, 0, 0);
      }
      s4[ct] = c;
    }
#pragma unroll
    for (int ct = 0; ct < 4; ++ct) {
      float e = e_s[l15 + 16 * ct];
      int t = t0 + l15 + 16 * ct;
      float part[4];
#pragma unroll
      for (int r = 0; r < 4; ++r) {
        int s = srow_base + r;
        float val = (t <= s) ? s4[ct][r] * rsq * __expf(e - Ms[r]) : 0.f;
        part[r] = val;
        w_w[(crow + r) * 72 + l15 + 16 * ct] = f2bf(val);
      }
      s4[ct][0] = part[0]; s4[ct][1] = part[1]; s4[ct][2] = part[2]; s4[ct][3] = part[3];
    }
#pragma unroll
    for (int r = 0; r < 4; ++r) {
      float tmp = s4[0][r] + s4[1][r] + s4[2][r] + s4[3][r];
      tmp += __shfl_xor(tmp, 1);
      tmp += __shfl_xor(tmp, 2);
      tmp += __shfl_xor(tmp, 4);
      tmp += __shfl_xor(tmp, 8);
      rsum[r] += tmp;
    }
    short8 wf0 = *(const short8*)&w_w[l15 * 72 + kg8];
    short8 wf1 = *(const short8*)&w_w[l15 * 72 + 32 + kg8];
#pragma unroll
    for (int dt = 0; dt < 8; ++dt) {
      short8 vf0 = *(const short8*)&Vt_s[(dt * 16 + l15) * 72 + kg8];
      short8 vf1 = *(const short8*)&Vt_s[(dt * 16 + l15) * 72 + 32 + kg8];
      acc[dt] = __builtin_amdgcn_mfma_f32_16x16x32_bf16(wf0, vf0, acc[dt], 0, 0, 0);
      acc[dt] = __builtin_amdgcn_mfma_f32_16x16x32_bf16(wf1, vf1, acc[dt], 0, 0, 0);
    }
  }

  float scl[4];
#pragma unroll
  for (int r = 0; r < 4; ++r) {
    float nrm = fmaxf(fabsf(rsum[r]), __expf(-md[r]));
    scl[r] = 1.0f / (nrm + 1e-6f);
  }
#pragma unroll
  for (int dt = 0; dt < 8; ++dt)
#pragma unroll
    for (int r = 0; r < 4; ++r)
      hc[hcbase + (size_t)(srow_base + r) * II + dt * 16 + l15] = acc[dt][r] * scl[r];
}

// ---------------- groupnorm + skip + silu gate -> bf16 ----------------
__global__ __launch_bounds__(256) void k_gn_skip(const float* __restrict__ hcin,
                                                 const ushort* __restrict__ convact,
                                                 const ushort* __restrict__ up,
                                                 const float* __restrict__ gnw,
                                                 const float* __restrict__ skw,
                                                 ushort* __restrict__ hs) {
  int row = blockIdx.x;
  int tid = threadIdx.x;
  int n = tid >> 5, j = tid & 31;
  float vals[4];
  float s = 0.f, sq = 0.f;
#pragma unroll
  for (int kk2 = 0; kk2 < 4; ++kk2) {
    int i = n * DHH + j + 32 * kk2;
    float vv = hcin[(size_t)row * II + i];
    vals[kk2] = vv;
    s += vv;
    sq += vv * vv;
  }
#pragma unroll
  for (int off2 = 16; off2; off2 >>= 1) {
    s += __shfl_xor(s, off2);
    sq += __shfl_xor(sq, off2);
  }
  float mean = s * (1.0f / DHH);
  float var = sq * (1.0f / DHH) - mean * mean;
  float r = rsqrtf(var + 1e-5f);
#pragma unroll
  for (int kk2 = 0; kk2 < 4; ++kk2) {
    int i = n * DHH + j + 32 * kk2;
    float hn = (vals[kk2] - mean) * r * gnw[i];
    float ca = bf2f(convact[(size_t)row * II + i]);
    float z = bf2f(up[(size_t)row * 2 * II + II + i]);
    float sz = z / (1.0f + __expf(-z));
    hs[(size_t)row * II + i] = f2bf((hn + skw[i] * ca) * sz);
  }
}

// ---------------- final LN(last row) + 2-layer head ----------------
__global__ __launch_bounds__(256) void k_head(const float* __restrict__ h,
                                              const float* __restrict__ pw,
                                              const float* __restrict__ pb,
                                              const float* __restrict__ w1,
                                              const float* __restrict__ b1,
                                              const float* __restrict__ w2,
                                              const float* __restrict__ b2,
                                              float* __restrict__ out) {
  int b = blockIdx.x;
  int tid = threadIdx.x;
  __shared__ float last[DD];
  __shared__ float hid[H1H];
  __shared__ float ss[4], sqs[4];
  const float* row = h + ((size_t)b * SS + SS - 1) * DD;
  float v0 = row[tid], v1 = row[tid + 256];
  float s = v0 + v1, sq = v0 * v0 + v1 * v1;
  for (int off = 32; off; off >>= 1) {
    s += __shfl_down(s, off);
    sq += __shfl_down(sq, off);
  }
  int wid = tid >> 6, lane = tid & 63;
  if (lane == 0) { ss[wid] = s; sqs[wid] = sq; }
  __syncthreads();
  if (tid == 0) {
    ss[0] = ss[0] + ss[1] + ss[2] + ss[3];
    sqs[0] = sqs[0] + sqs[1] + sqs[2] + sqs[3];
  }
  __syncthreads();
  float mean = ss[0] * (1.0f / DD);
  float var = sqs[0] * (1.0f / DD) - mean * mean;
  float r = rsqrtf(var + 1e-5f);
  last[tid] = (v0 - mean) * r * pw[tid] + pb[tid];
  last[tid + 256] = (v1 - mean) * r * pw[tid + 256] + pb[tid + 256];
  __syncthreads();
  if (tid < H1H) {
    float a = b1[tid];
    for (int d2 = 0; d2 < DD; ++d2) a += last[d2] * w1[(size_t)d2 * H1H + tid];
    hid[tid] = fmaxf(a, 0.f);
  }
  __syncthreads();
  if (tid < OUTO) {
    float a = b2[tid];
#pragma unroll
    for (int j2 = 0; j2 < H1H; ++j2) a += hid[j2] * w2[(size_t)j2 * OUTO + tid];
    out[(size_t)b * OUTO + tid] = a;
  }
}

extern "C" void kernel_launch(void* const* d_in, const int* in_sizes, int n_in,
                              void* d_out, int out_size, void* d_ws, size_t ws_size,
                              hipStream_t stream) {
  (void)in_sizes; (void)n_in; (void)out_size; (void)ws_size;
  const float* x    = (const float*)d_in[0];
  const float* in_w = (const float*)d_in[1];
  const float* in_b = (const float*)d_in[2];
  const float* ln_w = (const float*)d_in[3];
  const float* ln_b = (const float*)d_in[4];
  const float* up_w = (const float*)d_in[5];
  const float* conv_w = (const float*)d_in[6];
  const float* conv_b = (const float*)d_in[7];
  const float* q_w  = (const float*)d_in[8];
  const float* k_w  = (const float*)d_in[9];
  const float* v_w  = (const float*)d_in[10];
  const float* ig_w = (const float*)d_in[11];
  const float* ig_b = (const float*)d_in[12];
  const float* fg_w = (const float*)d_in[13];
  const float* fg_b = (const float*)d_in[14];
  const float* gn_w = (const float*)d_in[15];
  const float* sk_w = (const float*)d_in[16];
  const float* dn_w = (const float*)d_in[17];
  const float* po_w = (const float*)d_in[18];
  const float* po_b = (const float*)d_in[19];
  const float* h1_w = (const float*)d_in[20];
  const float* h1_b = (const float*)d_in[21];
  const float* h2_w = (const float*)d_in[22];
  const float* h2_b = (const float*)d_in[23];

  float* h = (float*)d_ws;                              // 2,097,152 f32
  ushort* xn_bf = (ushort*)(h + 2097152);               // 2,097,152 bf16
  ushort* up_bf = xn_bf + 2097152;                      // 8,388,608 bf16
  ushort* conv_bf = up_bf + 8388608;                    // 4,194,304 bf16
  ushort* qkb = conv_bf + 4194304;                      // 8,388,608 bf16 (q | k fused)
  ushort* vb = qkb + 8388608;                           // 4,194,304 bf16
  ushort* vbt = vb + 4194304;                           // 4,194,304 bf16 (per-head V^T)
  float* hc = (float*)(vbt + 4194304);                  // 4,194,304 f32
  ushort* hs_bf = (ushort*)(hc + 4194304);              // 4,194,304 bf16
  ushort* wT = hs_bf + 4194304;                         // 2,097,152 bf16 scratch
  ushort* Wg = wT + 2097152;                            // 49,152 bf16 gate weights
  float* igb_ = (float*)(Wg + 49152);
  float* fgb_ = igb_ + 32768;
  float* e_g  = fgb_ + 32768;
  float* M_g  = e_g + 32768;
  float* md_g = M_g + 32768;

  k_in_proj<<<BS, 256, 0, stream>>>(x, in_w, in_b, h);
  for (int l = 0; l < 2; ++l) {
    k_layernorm<<<BS, 256, 0, stream>>>(h, ln_w + l * DD, ln_b + l * DD, xn_bf);
    // up: [4096,512] @ [512,2048]
    k_wt<<<dim3(2 * II / 32, DD / 32), 256, 0, stream>>>(up_w + (size_t)l * DD * 2 * II, wT, DD, 2 * II);
    k_gemm_bf16<<<dim3(2 * II / 128, BS / 128), 256, 0, stream>>>(xn_bf, DD, wT, DD, 2 * II, DD,
                                                                  nullptr, 0, up_bf, 2 * II, nullptr);
    k_conv_silu<<<BS * II / 256, 256, 0, stream>>>(up_bf, conv_w + l * II * KK, conv_b + l * II, conv_bf);
    // q|k fused: conv_act @ [q_w k_w]  -> qkb [4096][2048]
    k_wt<<<dim3(II / 32, II / 32), 256, 0, stream>>>(q_w + (size_t)l * II * II, wT, II, II);
    k_wt<<<dim3(II / 32, II / 32), 256, 0, stream>>>(k_w + (size_t)l * II * II, wT + (size_t)II * II, II, II);
    k_gemm_bf16<<<dim3(2 * II / 128, BS / 128), 256, 0, stream>>>(conv_bf, II, wT, II, 2 * II, II,
                                                                  nullptr, 0, qkb, 2 * II, nullptr);
    // v: x_m @ v_w (x_m = up_bf[..., :I], lda = 2I); row-major vb + per-head V^T vbt
    k_wt<<<dim3(II / 32, II / 32), 256, 0, stream>>>(v_w + (size_t)l * II * II, wT, II, II);
    k_gemm_bf16<<<dim3(II / 128, BS / 128), 256, 0, stream>>>(up_bf, 2 * II, wT, II, II, II,
                                                              nullptr, 0, vb, II, vbt);
    // gates via MFMA
    k_wtg<<<12, 256, 0, stream>>>(ig_w + (size_t)l * 3 * II * NHH, fg_w + (size_t)l * 3 * II * NHH, Wg);
    k_gates_mfma<<<256, 64, 0, stream>>>(qkb, vb, Wg, ig_b + l * NHH, fg_b + l * NHH, igb_, fgb_);
    k_scan<<<BB * NHH, 512, 0, stream>>>(igb_, fgb_, e_g, M_g, md_g);
    k_attn_mfma<<<dim3(8, BB * NHH), 256, 0, stream>>>(qkb, vbt, e_g, M_g, md_g, hc);
    k_gn_skip<<<BS, 256, 0, stream>>>(hc, conv_bf, up_bf, gn_w + l * II, sk_w + l * II, hs_bf);
    // down: hs @ down_w, accumulate into h
    k_wt<<<dim3(DD / 32, II / 32), 256, 0, stream>>>(dn_w + (size_t)l * II * DD, wT, II, DD);
    k_gemm_bf16<<<dim3(DD / 128, BS / 128), 256, 0, stream>>>(hs_bf, II, wT, II, DD, II,
                                                              h, 1, nullptr, 0, nullptr);
  }
  k_head<<<BB, 256, 0, stream>>>(h, po_w, po_b, h1_w, h1_b, h2_w, h2_b, (float*)d_out);
}

// Round 5
// 452.635 us; speedup vs baseline: 3.7311x; 1.1107x over previous
//
#include <hip/hip_runtime.h>
#include <math.h>

#define BB 8
#define SS 512
#define FF 64
#define DD 512
#define II 1024
#define NHH 8
#define KK 4
#define DHH 128
#define H1H 32
#define OUTO 24
#define BS (BB*SS)   // 4096

typedef unsigned short ushort;
typedef __attribute__((ext_vector_type(8))) short short8;
typedef __attribute__((ext_vector_type(8))) unsigned short ushort8;
typedef __attribute__((ext_vector_type(4))) unsigned short ushort4v;
typedef __attribute__((ext_vector_type(4))) float f32x4;

__device__ __forceinline__ float bf2f(ushort u) {
  return __uint_as_float(((unsigned int)u) << 16);
}
__device__ __forceinline__ ushort f2bf(float f) {
  unsigned int u = __float_as_uint(f);
  unsigned int r = u + 0x7fffu + ((u >> 16) & 1u);
  return (ushort)(r >> 16);
}

typedef __attribute__((address_space(1))) const void gvoid;
typedef __attribute__((address_space(3))) void lvoid;
__device__ __forceinline__ void async16(const void* g, void* l) {
  __builtin_amdgcn_global_load_lds((gvoid*)g, (lvoid*)l, 16, 0, 0);
}

// ---------------- input projection: h = x @ in_w + in_b ----------------
// 16 rows per block, 2 cols per thread; in_w streamed once per block.
__global__ __launch_bounds__(256) void k_in_proj(const float* __restrict__ x,
                                                 const float* __restrict__ w,
                                                 const float* __restrict__ b,
                                                 float* __restrict__ h) {
  int r0 = blockIdx.x * 16;
  int tid = threadIdx.x;
  __shared__ float xs[16][FF];
  for (int i = tid; i < 16 * FF; i += 256)
    xs[i >> 6][i & 63] = x[(size_t)(r0 + (i >> 6)) * FF + (i & 63)];
  __syncthreads();
  float acc0[16], acc1[16];
  float b0 = b[tid], b1 = b[tid + 256];
#pragma unroll
  for (int r = 0; r < 16; ++r) { acc0[r] = b0; acc1[r] = b1; }
  for (int f = 0; f < FF; ++f) {
    float w0 = w[(size_t)f * DD + tid];
    float w1 = w[(size_t)f * DD + tid + 256];
#pragma unroll
    for (int r = 0; r < 16; ++r) {
      float xv = xs[r][f];
      acc0[r] += xv * w0;
      acc1[r] += xv * w1;
    }
  }
#pragma unroll
  for (int r = 0; r < 16; ++r) {
    h[(size_t)(r0 + r) * DD + tid] = acc0[r];
    h[(size_t)(r0 + r) * DD + tid + 256] = acc1[r];
  }
}

// ---------------- row layernorm over D=512 -> bf16 out ----------------
__global__ __launch_bounds__(256) void k_layernorm(const float* __restrict__ in,
                                                   const float* __restrict__ w,
                                                   const float* __restrict__ b,
                                                   ushort* __restrict__ out) {
  int row = blockIdx.x;
  int tid = threadIdx.x;
  float v0 = in[(size_t)row * DD + tid];
  float v1 = in[(size_t)row * DD + tid + 256];
  float s = v0 + v1, sq = v0 * v0 + v1 * v1;
  for (int off = 32; off; off >>= 1) {
    s += __shfl_down(s, off);
    sq += __shfl_down(sq, off);
  }
  __shared__ float ss[4], sqs[4];
  int wid = tid >> 6, lane = tid & 63;
  if (lane == 0) { ss[wid] = s; sqs[wid] = sq; }
  __syncthreads();
  if (tid == 0) {
    ss[0] = ss[0] + ss[1] + ss[2] + ss[3];
    sqs[0] = sqs[0] + sqs[1] + sqs[2] + sqs[3];
  }
  __syncthreads();
  float mean = ss[0] * (1.0f / DD);
  float var = sqs[0] * (1.0f / DD) - mean * mean;
  float r = rsqrtf(var + 1e-5f);
  out[(size_t)row * DD + tid] = f2bf((v0 - mean) * r * w[tid] + b[tid]);
  out[(size_t)row * DD + tid + 256] = f2bf((v1 - mean) * r * w[tid + 256] + b[tid + 256]);
}

// ---------------- fused weight convert+transpose for one layer ----------------
// blocks 0..1023: up_w -> wt_up; 1024..2047: q_w -> wt_qk[0:1024];
// 2048..3071: k_w -> wt_qk[1024:2048]; 3072..4095: v_w -> wt_v;
// 4096..4607: dn_w -> wt_dn; 4608..4619: gate pack.
__global__ __launch_bounds__(256) void k_wt_all(const float* __restrict__ up_w,
                                                const float* __restrict__ q_w,
                                                const float* __restrict__ k_w,
                                                const float* __restrict__ v_w,
                                                const float* __restrict__ dn_w,
                                                const float* __restrict__ igw,
                                                const float* __restrict__ fgw,
                                                ushort* __restrict__ wt_up,
                                                ushort* __restrict__ wt_qk,
                                                ushort* __restrict__ wt_v,
                                                ushort* __restrict__ wt_dn,
                                                ushort* __restrict__ Wg) {
  int blk = blockIdx.x;
  int tid = threadIdx.x;
  if (blk >= 4608) {
    int k = (blk - 4608) * 256 + tid;
    if (k < 3 * II) {
#pragma unroll
      for (int o = 0; o < NHH; ++o) {
        Wg[(size_t)o * (3 * II) + k] = f2bf(igw[(size_t)k * NHH + o]);
        Wg[(size_t)(NHH + o) * (3 * II) + k] = f2bf(fgw[(size_t)k * NHH + o]);
      }
    }
    return;
  }
  const float* src; ushort* dst; int N, Kd, t;
  if (blk < 1024)      { src = up_w; dst = wt_up; N = 2048; Kd = 512;  t = blk; }
  else if (blk < 2048) { src = q_w;  dst = wt_qk; N = 1024; Kd = 1024; t = blk - 1024; }
  else if (blk < 3072) { src = k_w;  dst = wt_qk + 1024 * 1024; N = 1024; Kd = 1024; t = blk - 2048; }
  else if (blk < 4096) { src = v_w;  dst = wt_v;  N = 1024; Kd = 1024; t = blk - 3072; }
  else                 { src = dn_w; dst = wt_dn; N = 512;  Kd = 1024; t = blk - 4096; }
  int ntn = N >> 5;
  int n0 = (t % ntn) * 32, k0 = (t / ntn) * 32;
  __shared__ float tb[32][33];
  int c = tid & 31, r8 = tid >> 5;
  for (int rr = r8; rr < 32; rr += 8)
    tb[rr][c] = src[(size_t)(k0 + rr) * N + n0 + c];
  __syncthreads();
  for (int rr = r8; rr < 32; rr += 8)
    dst[(size_t)(n0 + rr) * Kd + k0 + c] = f2bf(tb[c][rr]);
}

// ---------------- bf16 MFMA GEMM: C[M,N] = A[M,K](lda) @ Wt[N,K]^T ----------------
__global__ __launch_bounds__(256) void k_gemm_bf16(const ushort* __restrict__ A, int lda,
                                                   const ushort* __restrict__ Bt, int ldb,
                                                   int N, int Kd,
                                                   float* __restrict__ Cf, int accumulate,
                                                   ushort* __restrict__ Cb, int ldc,
                                                   ushort* __restrict__ Ct) {
  __shared__ ushort As[128 * 32];
  __shared__ ushort Bs[128 * 32];
  int tid = threadIdx.x;
  int wave = tid >> 6, lane = tid & 63;
  int m0 = blockIdx.y * 128, n0 = blockIdx.x * 128;
  int wm = wave >> 1, wn = wave & 1;
  f32x4 acc[4][4] = {};

  int srow = wave * 32 + (lane >> 2);
  int scol = (lane & 3) * 8;
  const ushort* Ag = A + (size_t)(m0 + srow) * lda + scol;
  const ushort* Bg = Bt + (size_t)(n0 + srow) * ldb + scol;
  ushort* AsW = As + wave * 1024;
  ushort* BsW = Bs + wave * 1024;

  int frow = lane & 15, fk = (lane >> 4) * 8;
  const ushort* ap = As + (size_t)(wm * 64 + frow) * 32 + fk;
  const ushort* bp = Bs + (size_t)(wn * 64 + frow) * 32 + fk;

  for (int kt = 0; kt < Kd; kt += 32) {
    async16(Ag + kt, AsW);
    async16(Ag + kt + (size_t)16 * lda, AsW + 512);
    async16(Bg + kt, BsW);
    async16(Bg + kt + (size_t)16 * ldb, BsW + 512);
    asm volatile("s_waitcnt vmcnt(0)" ::: "memory");
    __syncthreads();
    short8 a[4], b[4];
#pragma unroll
    for (int i = 0; i < 4; ++i) {
      a[i] = *(const short8*)(ap + i * 16 * 32);
      b[i] = *(const short8*)(bp + i * 16 * 32);
    }
#pragma unroll
    for (int i = 0; i < 4; ++i)
#pragma unroll
      for (int j = 0; j < 4; ++j)
        acc[i][j] = __builtin_amdgcn_mfma_f32_16x16x32_bf16(a[i], b[j], acc[i][j], 0, 0, 0);
    __syncthreads();
  }

  int ccol = lane & 15, crow = (lane >> 4) * 4;
#pragma unroll
  for (int i = 0; i < 4; ++i) {
#pragma unroll
    for (int j = 0; j < 4; ++j) {
      int grow = m0 + wm * 64 + i * 16 + crow;
      int gcol = n0 + wn * 64 + j * 16 + ccol;
#pragma unroll
      for (int r = 0; r < 4; ++r) {
        float v = acc[i][j][r];
        if (Cf) {
          size_t idx = (size_t)(grow + r) * N + gcol;
          Cf[idx] = accumulate ? (Cf[idx] + v) : v;
        }
        if (Cb) Cb[(size_t)(grow + r) * ldc + gcol] = f2bf(v);
      }
      if (Ct) {
        int b8 = grow >> 9, sloc = grow & 511;
        int nh = gcol >> 7, d = gcol & 127;
        ushort4v o;
#pragma unroll
        for (int r = 0; r < 4; ++r) o[r] = f2bf(acc[i][j][r]);
        *(ushort4v*)&Ct[((size_t)(b8 * NHH + nh) * DHH + d) * SS + sloc] = o;
      }
    }
  }
}

// ---------------- causal conv (K=4) + SiLU, 8 channels/thread ----------------
__global__ __launch_bounds__(256) void k_conv_silu(const ushort* __restrict__ up,
                                                   const float* __restrict__ cw,
                                                   const float* __restrict__ cb,
                                                   ushort* __restrict__ out) {
  int g = blockIdx.x * 256 + threadIdx.x;  // over BS*II/8
  int c8 = (g & 127) * 8;
  int row = g >> 7;
  int s = row & (SS - 1);
  float acc[8];
  float4 wv[8];
#pragma unroll
  for (int t = 0; t < 8; ++t) {
    acc[t] = cb[c8 + t];
    wv[t] = *(const float4*)(cw + (size_t)(c8 + t) * 4);
  }
#pragma unroll
  for (int j = 0; j < 4; ++j) {
    int so = s + j - 3;
    if (so >= 0) {
      ushort8 u = *(const ushort8*)&up[(size_t)(row + j - 3) * 2048 + c8];
#pragma unroll
      for (int t = 0; t < 8; ++t) {
        float wc = (j == 0) ? wv[t].x : (j == 1) ? wv[t].y : (j == 2) ? wv[t].z : wv[t].w;
        acc[t] += bf2f(u[t]) * wc;
      }
    }
  }
  ushort8 o;
#pragma unroll
  for (int t = 0; t < 8; ++t) {
    float sig = 1.0f / (1.0f + __expf(-acc[t]));
    o[t] = f2bf(acc[t] * sig);
  }
  *(ushort8*)&out[(size_t)row * II + c8] = o;
}

// ---------------- gate projections via MFMA: C[4096,16] = [q|k|v] @ Wg^T ----------------
__global__ __launch_bounds__(64) void k_gates_mfma(const ushort* __restrict__ qkb,
                                                   const ushort* __restrict__ vb,
                                                   const ushort* __restrict__ Wg,
                                                   const float* __restrict__ igb,
                                                   const float* __restrict__ fgb,
                                                   float* __restrict__ ig,
                                                   float* __restrict__ fg) {
  int lane = threadIdx.x;
  int row0 = blockIdx.x * 16;
  int l15 = lane & 15, lg = lane >> 4;
  int arow = row0 + l15;
  const ushort* qrow = qkb + (size_t)arow * 2048 + lg * 8;
  const ushort* vrow = vb + (size_t)arow * II + lg * 8;
  const ushort* wrow = Wg + (size_t)l15 * (3 * II) + lg * 8;
  f32x4 acc0 = {}, acc1 = {};
#pragma unroll 4
  for (int k = 0; k < 2048; k += 64) {
    short8 a0 = *(const short8*)(qrow + k);
    short8 b0 = *(const short8*)(wrow + k);
    short8 a1 = *(const short8*)(qrow + k + 32);
    short8 b1 = *(const short8*)(wrow + k + 32);
    acc0 = __builtin_amdgcn_mfma_f32_16x16x32_bf16(a0, b0, acc0, 0, 0, 0);
    acc1 = __builtin_amdgcn_mfma_f32_16x16x32_bf16(a1, b1, acc1, 0, 0, 0);
  }
#pragma unroll 4
  for (int k = 0; k < 1024; k += 64) {
    short8 a0 = *(const short8*)(vrow + k);
    short8 b0 = *(const short8*)(wrow + 2048 + k);
    short8 a1 = *(const short8*)(vrow + k + 32);
    short8 b1 = *(const short8*)(wrow + 2048 + k + 32);
    acc0 = __builtin_amdgcn_mfma_f32_16x16x32_bf16(a0, b0, acc0, 0, 0, 0);
    acc1 = __builtin_amdgcn_mfma_f32_16x16x32_bf16(a1, b1, acc1, 0, 0, 0);
  }
  int o = l15;
#pragma unroll
  for (int r = 0; r < 4; ++r) {
    int row = row0 + lg * 4 + r;
    int bb = row >> 9, s = row & (SS - 1);
    float val = acc0[r] + acc1[r];
    if (o < NHH)
      ig[((size_t)bb * NHH + o) * SS + s] = val + igb[o];
    else
      fg[((size_t)bb * NHH + (o - NHH)) * SS + s] = val + fgb[o - NHH];
  }
}

// ---------------- per-(b,n) scan: one wave per bn, shfl prefix ----------------
__global__ __launch_bounds__(64) void k_scan(const float* __restrict__ ig,
                                             const float* __restrict__ fg,
                                             float* __restrict__ e_g, float* __restrict__ M_g,
                                             float* __restrict__ maxd_g) {
  int bn = blockIdx.x;
  int lane = threadIdx.x;
  size_t base = (size_t)bn * SS + lane * 8;
  float4 f0 = *(const float4*)&fg[base];
  float4 f1 = *(const float4*)&fg[base + 4];
  float fv[8] = {f0.x, f0.y, f0.z, f0.w, f1.x, f1.y, f1.z, f1.w};
  float lf[8];
#pragma unroll
  for (int j = 0; j < 8; ++j) {
    float f = fv[j];
    lf[j] = (f >= 0.f) ? -log1pf(expf(-f)) : (f - log1pf(expf(f)));
  }
  float cum[8];
  float run = 0.f;
#pragma unroll
  for (int j = 0; j < 8; ++j) { run += lf[j]; cum[j] = run; }
  float inc = run;
#pragma unroll
  for (int off = 1; off < 64; off <<= 1) {
    float t = __shfl_up(inc, off);
    if (lane >= off) inc += t;
  }
  float exs = inc - run;
  float4 i0 = *(const float4*)&ig[base];
  float4 i1 = *(const float4*)&ig[base + 4];
  float igv[8] = {i0.x, i0.y, i0.z, i0.w, i1.x, i1.y, i1.z, i1.w};
  float cs[8], e[8];
#pragma unroll
  for (int j = 0; j < 8; ++j) {
    cs[j] = exs + cum[j];
    e[j] = igv[j] - cs[j];
  }
  float mcum[8];
  float mrun = -3.0e38f;
#pragma unroll
  for (int j = 0; j < 8; ++j) { mrun = fmaxf(mrun, e[j]); mcum[j] = mrun; }
  float minc = mrun;
#pragma unroll
  for (int off = 1; off < 64; off <<= 1) {
    float t = __shfl_up(minc, off);
    if (lane >= off) minc = fmaxf(minc, t);
  }
  float mex = __shfl_up(minc, 1);
  if (lane == 0) mex = -3.0e38f;
  float M[8], mdv[8];
#pragma unroll
  for (int j = 0; j < 8; ++j) {
    M[j] = fmaxf(mex, mcum[j]);
    mdv[j] = cs[j] + M[j];
  }
  *(float4*)&e_g[base] = make_float4(e[0], e[1], e[2], e[3]);
  *(float4*)&e_g[base + 4] = make_float4(e[4], e[5], e[6], e[7]);
  *(float4*)&M_g[base] = make_float4(M[0], M[1], M[2], M[3]);
  *(float4*)&M_g[base + 4] = make_float4(M[4], M[5], M[6], M[7]);
  *(float4*)&maxd_g[base] = make_float4(mdv[0], mdv[1], mdv[2], mdv[3]);
  *(float4*)&maxd_g[base + 4] = make_float4(mdv[4], mdv[5], mdv[6], mdv[7]);
}

// ---------------- mLSTM attention, MFMA bf16, async dbuf staging, fused GN epilogue --------
// grid (8 stiles swizzled, 64 bn), block 256 (4 waves x 16 Q-rows). KV tile 64.
// LDS: linear layouts + XOR swizzle (source-side for global_load_lds, read-side XOR).
__global__ __launch_bounds__(256) void k_attn_mfma(const ushort* __restrict__ qkb,
                                                   const ushort* __restrict__ vbt,
                                                   const float* __restrict__ e_g,
                                                   const float* __restrict__ M_g,
                                                   const float* __restrict__ maxd_g,
                                                   const ushort* __restrict__ convact,
                                                   const ushort* __restrict__ up,
                                                   const float* __restrict__ gnw,
                                                   const float* __restrict__ skw,
                                                   ushort* __restrict__ hs) {
  __shared__ __align__(16) ushort K2[2][64 * 128];
  __shared__ __align__(16) ushort V2[2][128 * 64];
  __shared__ __align__(16) ushort w_s[4][16 * 72];
  __shared__ float e_s[SS];

  int tid = threadIdx.x;
  int wave = tid >> 6, lane = tid & 63;
  int xb = blockIdx.x;
  int stile = (xb & 1) ? (7 - (xb >> 1)) : (xb >> 1);
  int bn = blockIdx.y;
  int b = bn >> 3, n = bn & 7;
  int s0 = stile * 64;

  const size_t qbase = (size_t)(b * SS) * 2048 + (size_t)n * DHH;
  const size_t kbase = qbase + II;
  const size_t vtbase = (size_t)bn * DHH * SS;
  const size_t obase = (size_t)(b * SS) * II + (size_t)n * DHH;

  int l15 = lane & 15, lg = lane >> 4;
  int kg8 = lg * 8;
  int crow = lg * 4;
  int srow_base = s0 + wave * 16 + crow;

  e_s[tid] = e_g[(size_t)bn * SS + tid];
  e_s[tid + 256] = e_g[(size_t)bn * SS + tid + 256];

  short8 qf[4];
  {
    int qrow = s0 + wave * 16 + l15;
#pragma unroll
    for (int ks = 0; ks < 4; ++ks)
      qf[ks] = *(const short8*)&qkb[qbase + (size_t)qrow * 2048 + ks * 32 + kg8];
  }
  float Ms[4], md[4];
#pragma unroll
  for (int r = 0; r < 4; ++r) {
    Ms[r] = M_g[(size_t)bn * SS + srow_base + r];
    md[r] = maxd_g[(size_t)bn * SS + srow_base + r];
  }

  f32x4 acc[8] = {};
  float rsum[4] = {};
  const float rsq = 0.08838834764831845f;
  ushort* w_w = &w_s[wave][0];
  int ntt = stile + 1;

  // prologue: stage tile 0 into buffer 0 (8 async16 per wave)
#pragma unroll
  for (int i = 0; i < 4; ++i) {
    int r = wave * 16 + i * 4 + (lane >> 4);
    int sp = (lane & 15) ^ (r & 7);
    async16(&qkb[kbase + (size_t)r * 2048 + sp * 8], &K2[0][(wave * 16 + i * 4) * 128]);
  }
#pragma unroll
  for (int i = 0; i < 4; ++i) {
    int d = wave * 32 + i * 8 + (lane >> 3);
    int sp = (lane & 7) ^ (d & 7);
    async16(&vbt[vtbase + (size_t)d * SS + sp * 8], &V2[0][(wave * 32 + i * 8) * 64]);
  }

  for (int tt = 0; tt < ntt; ++tt) {
    int cur = tt & 1;
    if (tt + 1 < ntt) {
      int t1 = (tt + 1) * 64;
      int nxt = cur ^ 1;
#pragma unroll
      for (int i = 0; i < 4; ++i) {
        int r = wave * 16 + i * 4 + (lane >> 4);
        int sp = (lane & 15) ^ (r & 7);
        async16(&qkb[kbase + (size_t)(t1 + r) * 2048 + sp * 8], &K2[nxt][(wave * 16 + i * 4) * 128]);
      }
#pragma unroll
      for (int i = 0; i < 4; ++i) {
        int d = wave * 32 + i * 8 + (lane >> 3);
        int sp = (lane & 7) ^ (d & 7);
        async16(&vbt[vtbase + (size_t)d * SS + t1 + sp * 8], &V2[nxt][(wave * 32 + i * 8) * 64]);
      }
      asm volatile("s_waitcnt vmcnt(8) lgkmcnt(0)" ::: "memory");
    } else {
      asm volatile("s_waitcnt vmcnt(0) lgkmcnt(0)" ::: "memory");
    }
    __builtin_amdgcn_s_barrier();

    int t0 = tt * 64;
    const ushort* Kc = &K2[cur][0];
    const ushort* Vc = &V2[cur][0];

    // QK^T: per wave 16 rows x 64 cols
    f32x4 s4[4];
#pragma unroll
    for (int ct = 0; ct < 4; ++ct) {
      f32x4 c = {};
      int ro = l15 + 16 * ct;
#pragma unroll
      for (int ks = 0; ks < 4; ++ks) {
        int sp = (ks * 4 + lg) ^ (ro & 7);
        short8 kf = *(const short8*)&Kc[ro * 128 + sp * 8];
        c = __builtin_amdgcn_mfma_f32_16x16x32_bf16(qf[ks], kf, c, 0, 0, 0);
      }
      s4[ct] = c;
    }
    // decay + mask + spill w (bf16) to per-wave LDS
#pragma unroll
    for (int ct = 0; ct < 4; ++ct) {
      int t = t0 + l15 + 16 * ct;
      float e = e_s[t];
#pragma unroll
      for (int r = 0; r < 4; ++r) {
        int s = srow_base + r;
        float val = (t <= s) ? s4[ct][r] * rsq * __expf(e - Ms[r]) : 0.f;
        s4[ct][r] = val;
        w_w[(crow + r) * 72 + l15 + 16 * ct] = f2bf(val);
      }
    }
#pragma unroll
    for (int r = 0; r < 4; ++r) {
      float tmp = s4[0][r] + s4[1][r] + s4[2][r] + s4[3][r];
      tmp += __shfl_xor(tmp, 1);
      tmp += __shfl_xor(tmp, 2);
      tmp += __shfl_xor(tmp, 4);
      tmp += __shfl_xor(tmp, 8);
      rsum[r] += tmp;
    }
    // PV
    short8 wf0 = *(const short8*)&w_w[l15 * 72 + kg8];
    short8 wf1 = *(const short8*)&w_w[l15 * 72 + 32 + kg8];
#pragma unroll
    for (int dt = 0; dt < 8; ++dt) {
      int d = dt * 16 + l15;
      int sp0 = lg ^ (d & 7);
      int sp1 = (lg + 4) ^ (d & 7);
      short8 vf0 = *(const short8*)&Vc[d * 64 + sp0 * 8];
      short8 vf1 = *(const short8*)&Vc[d * 64 + sp1 * 8];
      acc[dt] = __builtin_amdgcn_mfma_f32_16x16x32_bf16(wf0, vf0, acc[dt], 0, 0, 0);
      acc[dt] = __builtin_amdgcn_mfma_f32_16x16x32_bf16(wf1, vf1, acc[dt], 0, 0, 0);
    }
    __builtin_amdgcn_s_barrier();
  }

  // epilogue: mLSTM norm + groupnorm + skip + silu(z) gate, write bf16
  float scl[4], sum[4] = {}, sq[4] = {};
#pragma unroll
  for (int r = 0; r < 4; ++r) {
    float nrm = fmaxf(fabsf(rsum[r]), __expf(-md[r]));
    scl[r] = 1.0f / (nrm + 1e-6f);
  }
#pragma unroll
  for (int dt = 0; dt < 8; ++dt)
#pragma unroll
    for (int r = 0; r < 4; ++r) {
      float v = acc[dt][r] * scl[r];
      sum[r] += v;
      sq[r] += v * v;
    }
#pragma unroll
  for (int r = 0; r < 4; ++r) {
#pragma unroll
    for (int off = 1; off <= 8; off <<= 1) {
      sum[r] += __shfl_xor(sum[r], off);
      sq[r] += __shfl_xor(sq[r], off);
    }
  }
  float mu[4], rstd[4];
#pragma unroll
  for (int r = 0; r < 4; ++r) {
    mu[r] = sum[r] * (1.0f / DHH);
    float var = sq[r] * (1.0f / DHH) - mu[r] * mu[r];
    rstd[r] = rsqrtf(var + 1e-5f);
  }
#pragma unroll
  for (int dt = 0; dt < 8; ++dt) {
    int c = dt * 16 + l15;
    float gw = gnw[n * DHH + c];
    float sw = skw[n * DHH + c];
#pragma unroll
    for (int r = 0; r < 4; ++r) {
      size_t ridx = (size_t)(b * SS + srow_base + r);
      float v = acc[dt][r] * scl[r];
      float hn = (v - mu[r]) * rstd[r] * gw;
      float ca = bf2f(convact[ridx * II + n * DHH + c]);
      float z = bf2f(up[ridx * 2048 + II + n * DHH + c]);
      float sz = z / (1.0f + __expf(-z));
      hs[ridx * II + n * DHH + c] = f2bf((hn + sw * ca) * sz);
    }
  }
}

// ---------------- final LN(last row) + 2-layer head ----------------
__global__ __launch_bounds__(256) void k_head(const float* __restrict__ h,
                                              const float* __restrict__ pw,
                                              const float* __restrict__ pb,
                                              const float* __restrict__ w1,
                                              const float* __restrict__ b1,
                                              const float* __restrict__ w2,
                                              const float* __restrict__ b2,
                                              float* __restrict__ out) {
  int b = blockIdx.x;
  int tid = threadIdx.x;
  __shared__ float last[DD];
  __shared__ float hid[H1H];
  __shared__ float ss[4], sqs[4];
  const float* row = h + ((size_t)b * SS + SS - 1) * DD;
  float v0 = row[tid], v1 = row[tid + 256];
  float s = v0 + v1, sq = v0 * v0 + v1 * v1;
  for (int off = 32; off; off >>= 1) {
    s += __shfl_down(s, off);
    sq += __shfl_down(sq, off);
  }
  int wid = tid >> 6, lane = tid & 63;
  if (lane == 0) { ss[wid] = s; sqs[wid] = sq; }
  __syncthreads();
  if (tid == 0) {
    ss[0] = ss[0] + ss[1] + ss[2] + ss[3];
    sqs[0] = sqs[0] + sqs[1] + sqs[2] + sqs[3];
  }
  __syncthreads();
  float mean = ss[0] * (1.0f / DD);
  float var = sqs[0] * (1.0f / DD) - mean * mean;
  float r = rsqrtf(var + 1e-5f);
  last[tid] = (v0 - mean) * r * pw[tid] + pb[tid];
  last[tid + 256] = (v1 - mean) * r * pw[tid + 256] + pb[tid + 256];
  __syncthreads();
  if (tid < H1H) {
    float a = b1[tid];
    for (int d2 = 0; d2 < DD; ++d2) a += last[d2] * w1[(size_t)d2 * H1H + tid];
    hid[tid] = fmaxf(a, 0.f);
  }
  __syncthreads();
  if (tid < OUTO) {
    float a = b2[tid];
#pragma unroll
    for (int j2 = 0; j2 < H1H; ++j2) a += hid[j2] * w2[(size_t)j2 * OUTO + tid];
    out[(size_t)b * OUTO + tid] = a;
  }
}

extern "C" void kernel_launch(void* const* d_in, const int* in_sizes, int n_in,
                              void* d_out, int out_size, void* d_ws, size_t ws_size,
                              hipStream_t stream) {
  (void)in_sizes; (void)n_in; (void)out_size; (void)ws_size;
  const float* x    = (const float*)d_in[0];
  const float* in_w = (const float*)d_in[1];
  const float* in_b = (const float*)d_in[2];
  const float* ln_w = (const float*)d_in[3];
  const float* ln_b = (const float*)d_in[4];
  const float* up_w = (const float*)d_in[5];
  const float* conv_w = (const float*)d_in[6];
  const float* conv_b = (const float*)d_in[7];
  const float* q_w  = (const float*)d_in[8];
  const float* k_w  = (const float*)d_in[9];
  const float* v_w  = (const float*)d_in[10];
  const float* ig_w = (const float*)d_in[11];
  const float* ig_b = (const float*)d_in[12];
  const float* fg_w = (const float*)d_in[13];
  const float* fg_b = (const float*)d_in[14];
  const float* gn_w = (const float*)d_in[15];
  const float* sk_w = (const float*)d_in[16];
  const float* dn_w = (const float*)d_in[17];
  const float* po_w = (const float*)d_in[18];
  const float* po_b = (const float*)d_in[19];
  const float* h1_w = (const float*)d_in[20];
  const float* h1_b = (const float*)d_in[21];
  const float* h2_w = (const float*)d_in[22];
  const float* h2_b = (const float*)d_in[23];

  float* h = (float*)d_ws;                              // 2M f32
  ushort* xn_bf = (ushort*)(h + 2097152);               // 2M bf16
  ushort* up_bf = xn_bf + 2097152;                      // 8M bf16
  ushort* conv_bf = up_bf + 8388608;                    // 4M bf16
  ushort* qkb = conv_bf + 4194304;                      // 8M bf16 (q | k fused)
  ushort* vb = qkb + 8388608;                           // 4M bf16
  ushort* vbt = vb + 4194304;                           // 4M bf16 (per-head V^T)
  ushort* hs_bf = vbt + 4194304;                        // 4M bf16
  ushort* wt_up = hs_bf + 4194304;                      // 1M bf16
  ushort* wt_qk = wt_up + 1048576;                      // 2M bf16
  ushort* wt_v  = wt_qk + 2097152;                      // 1M bf16
  ushort* wt_dn = wt_v + 1048576;                       // 0.5M bf16
  ushort* Wg = wt_dn + 524288;                          // 49152 bf16
  float* igb_ = (float*)(Wg + 49152);
  float* fgb_ = igb_ + 32768;
  float* e_g  = fgb_ + 32768;
  float* M_g  = e_g + 32768;
  float* md_g = M_g + 32768;

  k_in_proj<<<BS / 16, 256, 0, stream>>>(x, in_w, in_b, h);
  for (int l = 0; l < 2; ++l) {
    k_layernorm<<<BS, 256, 0, stream>>>(h, ln_w + l * DD, ln_b + l * DD, xn_bf);
    k_wt_all<<<4620, 256, 0, stream>>>(up_w + (size_t)l * DD * 2 * II,
                                       q_w + (size_t)l * II * II,
                                       k_w + (size_t)l * II * II,
                                       v_w + (size_t)l * II * II,
                                       dn_w + (size_t)l * II * DD,
                                       ig_w + (size_t)l * 3 * II * NHH,
                                       fg_w + (size_t)l * 3 * II * NHH,
                                       wt_up, wt_qk, wt_v, wt_dn, Wg);
    // up: [4096,512] @ [512,2048]
    k_gemm_bf16<<<dim3(2 * II / 128, BS / 128), 256, 0, stream>>>(xn_bf, DD, wt_up, DD, 2 * II, DD,
                                                                  nullptr, 0, up_bf, 2 * II, nullptr);
    k_conv_silu<<<BS * II / 8 / 256, 256, 0, stream>>>(up_bf, conv_w + l * II * KK, conv_b + l * II, conv_bf);
    // q|k fused: conv_act @ [q_w k_w] -> qkb [4096][2048]
    k_gemm_bf16<<<dim3(2 * II / 128, BS / 128), 256, 0, stream>>>(conv_bf, II, wt_qk, II, 2 * II, II,
                                                                  nullptr, 0, qkb, 2 * II, nullptr);
    // v: x_m @ v_w (x_m = up_bf[..., :I], lda = 2I); row-major vb + per-head V^T vbt
    k_gemm_bf16<<<dim3(II / 128, BS / 128), 256, 0, stream>>>(up_bf, 2 * II, wt_v, II, II, II,
                                                              nullptr, 0, vb, II, vbt);
    k_gates_mfma<<<256, 64, 0, stream>>>(qkb, vb, Wg, ig_b + l * NHH, fg_b + l * NHH, igb_, fgb_);
    k_scan<<<BB * NHH, 64, 0, stream>>>(igb_, fgb_, e_g, M_g, md_g);
    k_attn_mfma<<<dim3(8, BB * NHH), 256, 0, stream>>>(qkb, vbt, e_g, M_g, md_g,
                                                       conv_bf, up_bf,
                                                       gn_w + l * II, sk_w + l * II, hs_bf);
    // down: hs @ down_w, accumulate into h
    k_gemm_bf16<<<dim3(DD / 128, BS / 128), 256, 0, stream>>>(hs_bf, II, wt_dn, II, DD, II,
                                                              h, 1, nullptr, 0, nullptr);
  }
  k_head<<<BB, 256, 0, stream>>>(h, po_w, po_b, h1_w, h1_b, h2_w, h2_b, (float*)d_out);
}

// Round 6
// 414.618 us; speedup vs baseline: 4.0732x; 1.0917x over previous
//
#include <hip/hip_runtime.h>
#include <math.h>

#define BB 8
#define SS 512
#define FF 64
#define DD 512
#define II 1024
#define NHH 8
#define KK 4
#define DHH 128
#define H1H 32
#define OUTO 24
#define BS (BB*SS)   // 4096

typedef unsigned short ushort;
typedef __attribute__((ext_vector_type(8))) short short8;
typedef __attribute__((ext_vector_type(8))) unsigned short ushort8;
typedef __attribute__((ext_vector_type(4))) unsigned short ushort4v;
typedef __attribute__((ext_vector_type(4))) float f32x4;

__device__ __forceinline__ float bf2f(ushort u) {
  return __uint_as_float(((unsigned int)u) << 16);
}
__device__ __forceinline__ ushort f2bf(float f) {
  unsigned int u = __float_as_uint(f);
  unsigned int r = u + 0x7fffu + ((u >> 16) & 1u);
  return (ushort)(r >> 16);
}

typedef __attribute__((address_space(1))) const void gvoid;
typedef __attribute__((address_space(3))) void lvoid;
__device__ __forceinline__ void async16(const void* g, void* l) {
  __builtin_amdgcn_global_load_lds((gvoid*)g, (lvoid*)l, 16, 0, 0);
}

// ---------------- input projection: h = x @ in_w + in_b ----------------
__global__ __launch_bounds__(256) void k_in_proj(const float* __restrict__ x,
                                                 const float* __restrict__ w,
                                                 const float* __restrict__ b,
                                                 float* __restrict__ h) {
  int r0 = blockIdx.x * 16;
  int tid = threadIdx.x;
  __shared__ float xs[16][FF];
  for (int i = tid; i < 16 * FF; i += 256)
    xs[i >> 6][i & 63] = x[(size_t)(r0 + (i >> 6)) * FF + (i & 63)];
  __syncthreads();
  float acc0[16], acc1[16];
  float b0 = b[tid], b1 = b[tid + 256];
#pragma unroll
  for (int r = 0; r < 16; ++r) { acc0[r] = b0; acc1[r] = b1; }
  for (int f = 0; f < FF; ++f) {
    float w0 = w[(size_t)f * DD + tid];
    float w1 = w[(size_t)f * DD + tid + 256];
#pragma unroll
    for (int r = 0; r < 16; ++r) {
      float xv = xs[r][f];
      acc0[r] += xv * w0;
      acc1[r] += xv * w1;
    }
  }
#pragma unroll
  for (int r = 0; r < 16; ++r) {
    h[(size_t)(r0 + r) * DD + tid] = acc0[r];
    h[(size_t)(r0 + r) * DD + tid + 256] = acc1[r];
  }
}

// ---------------- row layernorm over D=512 -> bf16 out ----------------
__global__ __launch_bounds__(256) void k_layernorm(const float* __restrict__ in,
                                                   const float* __restrict__ w,
                                                   const float* __restrict__ b,
                                                   ushort* __restrict__ out) {
  int row = blockIdx.x;
  int tid = threadIdx.x;
  float v0 = in[(size_t)row * DD + tid];
  float v1 = in[(size_t)row * DD + tid + 256];
  float s = v0 + v1, sq = v0 * v0 + v1 * v1;
  for (int off = 32; off; off >>= 1) {
    s += __shfl_down(s, off);
    sq += __shfl_down(sq, off);
  }
  __shared__ float ss[4], sqs[4];
  int wid = tid >> 6, lane = tid & 63;
  if (lane == 0) { ss[wid] = s; sqs[wid] = sq; }
  __syncthreads();
  if (tid == 0) {
    ss[0] = ss[0] + ss[1] + ss[2] + ss[3];
    sqs[0] = sqs[0] + sqs[1] + sqs[2] + sqs[3];
  }
  __syncthreads();
  float mean = ss[0] * (1.0f / DD);
  float var = sqs[0] * (1.0f / DD) - mean * mean;
  float r = rsqrtf(var + 1e-5f);
  out[(size_t)row * DD + tid] = f2bf((v0 - mean) * r * w[tid] + b[tid]);
  out[(size_t)row * DD + tid + 256] = f2bf((v1 - mean) * r * w[tid + 256] + b[tid + 256]);
}

// ---------------- fused weight convert+transpose for one layer ----------------
__global__ __launch_bounds__(256) void k_wt_all(const float* __restrict__ up_w,
                                                const float* __restrict__ q_w,
                                                const float* __restrict__ k_w,
                                                const float* __restrict__ v_w,
                                                const float* __restrict__ dn_w,
                                                const float* __restrict__ igw,
                                                const float* __restrict__ fgw,
                                                ushort* __restrict__ wt_up,
                                                ushort* __restrict__ wt_qk,
                                                ushort* __restrict__ wt_v,
                                                ushort* __restrict__ wt_dn,
                                                ushort* __restrict__ Wg) {
  int blk = blockIdx.x;
  int tid = threadIdx.x;
  if (blk >= 4608) {
    int k = (blk - 4608) * 256 + tid;
    if (k < 3 * II) {
#pragma unroll
      for (int o = 0; o < NHH; ++o) {
        Wg[(size_t)o * (3 * II) + k] = f2bf(igw[(size_t)k * NHH + o]);
        Wg[(size_t)(NHH + o) * (3 * II) + k] = f2bf(fgw[(size_t)k * NHH + o]);
      }
    }
    return;
  }
  const float* src; ushort* dst; int N, Kd, t;
  if (blk < 1024)      { src = up_w; dst = wt_up; N = 2048; Kd = 512;  t = blk; }
  else if (blk < 2048) { src = q_w;  dst = wt_qk; N = 1024; Kd = 1024; t = blk - 1024; }
  else if (blk < 3072) { src = k_w;  dst = wt_qk + 1024 * 1024; N = 1024; Kd = 1024; t = blk - 2048; }
  else if (blk < 4096) { src = v_w;  dst = wt_v;  N = 1024; Kd = 1024; t = blk - 3072; }
  else                 { src = dn_w; dst = wt_dn; N = 512;  Kd = 1024; t = blk - 4096; }
  int ntn = N >> 5;
  int n0 = (t % ntn) * 32, k0 = (t / ntn) * 32;
  __shared__ float tb[32][33];
  int c = tid & 31, r8 = tid >> 5;
  for (int rr = r8; rr < 32; rr += 8)
    tb[rr][c] = src[(size_t)(k0 + rr) * N + n0 + c];
  __syncthreads();
  for (int rr = r8; rr < 32; rr += 8)
    dst[(size_t)(n0 + rr) * Kd + k0 + c] = f2bf(tb[c][rr]);
}

// ---------------- bf16 MFMA GEMM, depth-2 prefetch ring, optional split-K atomic ----------------
// C[M,N] (=|+=|atomic+=) A[M,K](lda) @ Wt[N,K]^T.  blockIdx.z = K-slice.
__global__ __launch_bounds__(256) void k_gemm_bf16(const ushort* __restrict__ A, int lda,
                                                   const ushort* __restrict__ Bt, int ldb,
                                                   int N, int Kd,
                                                   float* __restrict__ Cf, int accumulate,
                                                   int atomic,
                                                   ushort* __restrict__ Cb, int ldc,
                                                   ushort* __restrict__ Ct) {
  __shared__ ushort As[3][128 * 32];
  __shared__ ushort Bs[3][128 * 32];
  int tid = threadIdx.x;
  int wave = tid >> 6, lane = tid & 63;
  int m0 = blockIdx.y * 128, n0 = blockIdx.x * 128;
  int ksl = Kd / gridDim.z;
  int k0 = blockIdx.z * ksl;
  int wm = wave >> 1, wn = wave & 1;
  f32x4 acc[4][4] = {};

  int srow = wave * 32 + (lane >> 2);
  int scol = (lane & 3) * 8;
  const ushort* Ag = A + (size_t)(m0 + srow) * lda + k0 + scol;
  const ushort* Bg = Bt + (size_t)(n0 + srow) * ldb + k0 + scol;
  int woff = wave * 1024;

  int frow = lane & 15, fk = (lane >> 4) * 8;
  int apo = (wm * 64 + frow) * 32 + fk;
  int bpo = (wn * 64 + frow) * 32 + fk;

  int nkt = ksl >> 5;
  // prologue: stage tiles 0,1
#pragma unroll
  for (int p = 0; p < 2; ++p) {
    if (p < nkt) {
      async16(Ag + p * 32, &As[p][woff]);
      async16(Ag + p * 32 + (size_t)16 * lda, &As[p][woff + 512]);
      async16(Bg + p * 32, &Bs[p][woff]);
      async16(Bg + p * 32 + (size_t)16 * ldb, &Bs[p][woff + 512]);
    }
  }
  int buf = 0;
  for (int it = 0; it < nkt; ++it) {
    if (it + 2 < nkt) {
      int nb = (buf + 2) % 3;
      int kt = (it + 2) * 32;
      async16(Ag + kt, &As[nb][woff]);
      async16(Ag + kt + (size_t)16 * lda, &As[nb][woff + 512]);
      async16(Bg + kt, &Bs[nb][woff]);
      async16(Bg + kt + (size_t)16 * ldb, &Bs[nb][woff + 512]);
    }
    int ahead = nkt - 1 - it;
    if (ahead >= 2)      asm volatile("s_waitcnt vmcnt(8)" ::: "memory");
    else if (ahead == 1) asm volatile("s_waitcnt vmcnt(4)" ::: "memory");
    else                 asm volatile("s_waitcnt vmcnt(0)" ::: "memory");
    __builtin_amdgcn_s_barrier();
    const ushort* ap = &As[buf][apo];
    const ushort* bp = &Bs[buf][bpo];
    short8 a[4], b[4];
#pragma unroll
    for (int i = 0; i < 4; ++i) {
      a[i] = *(const short8*)(ap + i * 16 * 32);
      b[i] = *(const short8*)(bp + i * 16 * 32);
    }
#pragma unroll
    for (int i = 0; i < 4; ++i)
#pragma unroll
      for (int j = 0; j < 4; ++j)
        acc[i][j] = __builtin_amdgcn_mfma_f32_16x16x32_bf16(a[i], b[j], acc[i][j], 0, 0, 0);
    __builtin_amdgcn_s_barrier();
    buf = (buf + 1) % 3;
  }

  int ccol = lane & 15, crow = (lane >> 4) * 4;
#pragma unroll
  for (int i = 0; i < 4; ++i) {
#pragma unroll
    for (int j = 0; j < 4; ++j) {
      int grow = m0 + wm * 64 + i * 16 + crow;
      int gcol = n0 + wn * 64 + j * 16 + ccol;
#pragma unroll
      for (int r = 0; r < 4; ++r) {
        float v = acc[i][j][r];
        if (Cf) {
          size_t idx = (size_t)(grow + r) * N + gcol;
          if (atomic) atomicAdd(&Cf[idx], v);
          else Cf[idx] = accumulate ? (Cf[idx] + v) : v;
        }
        if (Cb) Cb[(size_t)(grow + r) * ldc + gcol] = f2bf(v);
      }
      if (Ct) {
        int b8 = grow >> 9, sloc = grow & 511;
        int nh = gcol >> 7, d = gcol & 127;
        ushort4v o;
#pragma unroll
        for (int r = 0; r < 4; ++r) o[r] = f2bf(acc[i][j][r]);
        *(ushort4v*)&Ct[((size_t)(b8 * NHH + nh) * DHH + d) * SS + sloc] = o;
      }
    }
  }
}

// ---------------- causal conv (K=4) + SiLU, 8 channels/thread ----------------
__global__ __launch_bounds__(256) void k_conv_silu(const ushort* __restrict__ up,
                                                   const float* __restrict__ cw,
                                                   const float* __restrict__ cb,
                                                   ushort* __restrict__ out) {
  int g = blockIdx.x * 256 + threadIdx.x;
  int c8 = (g & 127) * 8;
  int row = g >> 7;
  int s = row & (SS - 1);
  float acc[8];
  float4 wv[8];
#pragma unroll
  for (int t = 0; t < 8; ++t) {
    acc[t] = cb[c8 + t];
    wv[t] = *(const float4*)(cw + (size_t)(c8 + t) * 4);
  }
#pragma unroll
  for (int j = 0; j < 4; ++j) {
    int so = s + j - 3;
    if (so >= 0) {
      ushort8 u = *(const ushort8*)&up[(size_t)(row + j - 3) * 2048 + c8];
#pragma unroll
      for (int t = 0; t < 8; ++t) {
        float wc = (j == 0) ? wv[t].x : (j == 1) ? wv[t].y : (j == 2) ? wv[t].z : wv[t].w;
        acc[t] += bf2f(u[t]) * wc;
      }
    }
  }
  ushort8 o;
#pragma unroll
  for (int t = 0; t < 8; ++t) {
    float sig = 1.0f / (1.0f + __expf(-acc[t]));
    o[t] = f2bf(acc[t] * sig);
  }
  *(ushort8*)&out[(size_t)row * II + c8] = o;
}

// ---------------- gate projections via MFMA ----------------
__global__ __launch_bounds__(64) void k_gates_mfma(const ushort* __restrict__ qkb,
                                                   const ushort* __restrict__ vb,
                                                   const ushort* __restrict__ Wg,
                                                   const float* __restrict__ igb,
                                                   const float* __restrict__ fgb,
                                                   float* __restrict__ ig,
                                                   float* __restrict__ fg) {
  int lane = threadIdx.x;
  int row0 = blockIdx.x * 16;
  int l15 = lane & 15, lg = lane >> 4;
  int arow = row0 + l15;
  const ushort* qrow = qkb + (size_t)arow * 2048 + lg * 8;
  const ushort* vrow = vb + (size_t)arow * II + lg * 8;
  const ushort* wrow = Wg + (size_t)l15 * (3 * II) + lg * 8;
  f32x4 acc0 = {}, acc1 = {};
#pragma unroll 4
  for (int k = 0; k < 2048; k += 64) {
    short8 a0 = *(const short8*)(qrow + k);
    short8 b0 = *(const short8*)(wrow + k);
    short8 a1 = *(const short8*)(qrow + k + 32);
    short8 b1 = *(const short8*)(wrow + k + 32);
    acc0 = __builtin_amdgcn_mfma_f32_16x16x32_bf16(a0, b0, acc0, 0, 0, 0);
    acc1 = __builtin_amdgcn_mfma_f32_16x16x32_bf16(a1, b1, acc1, 0, 0, 0);
  }
#pragma unroll 4
  for (int k = 0; k < 1024; k += 64) {
    short8 a0 = *(const short8*)(vrow + k);
    short8 b0 = *(const short8*)(wrow + 2048 + k);
    short8 a1 = *(const short8*)(vrow + k + 32);
    short8 b1 = *(const short8*)(wrow + 2048 + k + 32);
    acc0 = __builtin_amdgcn_mfma_f32_16x16x32_bf16(a0, b0, acc0, 0, 0, 0);
    acc1 = __builtin_amdgcn_mfma_f32_16x16x32_bf16(a1, b1, acc1, 0, 0, 0);
  }
  int o = l15;
#pragma unroll
  for (int r = 0; r < 4; ++r) {
    int row = row0 + lg * 4 + r;
    int bb = row >> 9, s = row & (SS - 1);
    float val = acc0[r] + acc1[r];
    if (o < NHH)
      ig[((size_t)bb * NHH + o) * SS + s] = val + igb[o];
    else
      fg[((size_t)bb * NHH + (o - NHH)) * SS + s] = val + fgb[o - NHH];
  }
}

// ---------------- per-(b,n) scan: one wave per bn, shfl prefix ----------------
__global__ __launch_bounds__(64) void k_scan(const float* __restrict__ ig,
                                             const float* __restrict__ fg,
                                             float* __restrict__ e_g, float* __restrict__ M_g,
                                             float* __restrict__ maxd_g) {
  int bn = blockIdx.x;
  int lane = threadIdx.x;
  size_t base = (size_t)bn * SS + lane * 8;
  float4 f0 = *(const float4*)&fg[base];
  float4 f1 = *(const float4*)&fg[base + 4];
  float fv[8] = {f0.x, f0.y, f0.z, f0.w, f1.x, f1.y, f1.z, f1.w};
  float lf[8];
#pragma unroll
  for (int j = 0; j < 8; ++j) {
    float f = fv[j];
    lf[j] = (f >= 0.f) ? -log1pf(expf(-f)) : (f - log1pf(expf(f)));
  }
  float cum[8];
  float run = 0.f;
#pragma unroll
  for (int j = 0; j < 8; ++j) { run += lf[j]; cum[j] = run; }
  float inc = run;
#pragma unroll
  for (int off = 1; off < 64; off <<= 1) {
    float t = __shfl_up(inc, off);
    if (lane >= off) inc += t;
  }
  float exs = inc - run;
  float4 i0 = *(const float4*)&ig[base];
  float4 i1 = *(const float4*)&ig[base + 4];
  float igv[8] = {i0.x, i0.y, i0.z, i0.w, i1.x, i1.y, i1.z, i1.w};
  float cs[8], e[8];
#pragma unroll
  for (int j = 0; j < 8; ++j) {
    cs[j] = exs + cum[j];
    e[j] = igv[j] - cs[j];
  }
  float mcum[8];
  float mrun = -3.0e38f;
#pragma unroll
  for (int j = 0; j < 8; ++j) { mrun = fmaxf(mrun, e[j]); mcum[j] = mrun; }
  float minc = mrun;
#pragma unroll
  for (int off = 1; off < 64; off <<= 1) {
    float t = __shfl_up(minc, off);
    if (lane >= off) minc = fmaxf(minc, t);
  }
  float mex = __shfl_up(minc, 1);
  if (lane == 0) mex = -3.0e38f;
  float M[8], mdv[8];
#pragma unroll
  for (int j = 0; j < 8; ++j) {
    M[j] = fmaxf(mex, mcum[j]);
    mdv[j] = cs[j] + M[j];
  }
  *(float4*)&e_g[base] = make_float4(e[0], e[1], e[2], e[3]);
  *(float4*)&e_g[base + 4] = make_float4(e[4], e[5], e[6], e[7]);
  *(float4*)&M_g[base] = make_float4(M[0], M[1], M[2], M[3]);
  *(float4*)&M_g[base + 4] = make_float4(M[4], M[5], M[6], M[7]);
  *(float4*)&maxd_g[base] = make_float4(mdv[0], mdv[1], mdv[2], mdv[3]);
  *(float4*)&maxd_g[base + 4] = make_float4(mdv[4], mdv[5], mdv[6], mdv[7]);
}

// ---------------- mLSTM attention, MFMA bf16, async dbuf staging, fused GN epilogue --------
__global__ __launch_bounds__(256) void k_attn_mfma(const ushort* __restrict__ qkb,
                                                   const ushort* __restrict__ vbt,
                                                   const float* __restrict__ e_g,
                                                   const float* __restrict__ M_g,
                                                   const float* __restrict__ maxd_g,
                                                   const ushort* __restrict__ convact,
                                                   const ushort* __restrict__ up,
                                                   const float* __restrict__ gnw,
                                                   const float* __restrict__ skw,
                                                   ushort* __restrict__ hs) {
  __shared__ __align__(16) ushort K2[2][64 * 128];
  __shared__ __align__(16) ushort V2[2][128 * 64];
  __shared__ __align__(16) ushort w_s[4][16 * 72];
  __shared__ float e_s[SS];

  int tid = threadIdx.x;
  int wave = tid >> 6, lane = tid & 63;
  int xb = blockIdx.x;
  int stile = (xb & 1) ? (7 - (xb >> 1)) : (xb >> 1);
  int bn = blockIdx.y;
  int b = bn >> 3, n = bn & 7;
  int s0 = stile * 64;

  const size_t qbase = (size_t)(b * SS) * 2048 + (size_t)n * DHH;
  const size_t kbase = qbase + II;
  const size_t vtbase = (size_t)bn * DHH * SS;

  int l15 = lane & 15, lg = lane >> 4;
  int kg8 = lg * 8;
  int crow = lg * 4;
  int srow_base = s0 + wave * 16 + crow;

  e_s[tid] = e_g[(size_t)bn * SS + tid];
  e_s[tid + 256] = e_g[(size_t)bn * SS + tid + 256];

  short8 qf[4];
  {
    int qrow = s0 + wave * 16 + l15;
#pragma unroll
    for (int ks = 0; ks < 4; ++ks)
      qf[ks] = *(const short8*)&qkb[qbase + (size_t)qrow * 2048 + ks * 32 + kg8];
  }
  float Ms[4], md[4];
#pragma unroll
  for (int r = 0; r < 4; ++r) {
    Ms[r] = M_g[(size_t)bn * SS + srow_base + r];
    md[r] = maxd_g[(size_t)bn * SS + srow_base + r];
  }

  f32x4 acc[8] = {};
  float rsum[4] = {};
  const float rsq = 0.08838834764831845f;
  ushort* w_w = &w_s[wave][0];
  int ntt = stile + 1;

#pragma unroll
  for (int i = 0; i < 4; ++i) {
    int r = wave * 16 + i * 4 + (lane >> 4);
    int sp = (lane & 15) ^ (r & 7);
    async16(&qkb[kbase + (size_t)r * 2048 + sp * 8], &K2[0][(wave * 16 + i * 4) * 128]);
  }
#pragma unroll
  for (int i = 0; i < 4; ++i) {
    int d = wave * 32 + i * 8 + (lane >> 3);
    int sp = (lane & 7) ^ (d & 7);
    async16(&vbt[vtbase + (size_t)d * SS + sp * 8], &V2[0][(wave * 32 + i * 8) * 64]);
  }

  for (int tt = 0; tt < ntt; ++tt) {
    int cur = tt & 1;
    if (tt + 1 < ntt) {
      int t1 = (tt + 1) * 64;
      int nxt = cur ^ 1;
#pragma unroll
      for (int i = 0; i < 4; ++i) {
        int r = wave * 16 + i * 4 + (lane >> 4);
        int sp = (lane & 15) ^ (r & 7);
        async16(&qkb[kbase + (size_t)(t1 + r) * 2048 + sp * 8], &K2[nxt][(wave * 16 + i * 4) * 128]);
      }
#pragma unroll
      for (int i = 0; i < 4; ++i) {
        int d = wave * 32 + i * 8 + (lane >> 3);
        int sp = (lane & 7) ^ (d & 7);
        async16(&vbt[vtbase + (size_t)d * SS + t1 + sp * 8], &V2[nxt][(wave * 32 + i * 8) * 64]);
      }
      asm volatile("s_waitcnt vmcnt(8) lgkmcnt(0)" ::: "memory");
    } else {
      asm volatile("s_waitcnt vmcnt(0) lgkmcnt(0)" ::: "memory");
    }
    __builtin_amdgcn_s_barrier();

    int t0 = tt * 64;
    const ushort* Kc = &K2[cur][0];
    const ushort* Vc = &V2[cur][0];

    f32x4 s4[4];
#pragma unroll
    for (int ct = 0; ct < 4; ++ct) {
      f32x4 c = {};
      int ro = l15 + 16 * ct;
#pragma unroll
      for (int ks = 0; ks < 4; ++ks) {
        int sp = (ks * 4 + lg) ^ (ro & 7);
        short8 kf = *(const short8*)&Kc[ro * 128 + sp * 8];
        c = __builtin_amdgcn_mfma_f32_16x16x32_bf16(qf[ks], kf, c, 0, 0, 0);
      }
      s4[ct] = c;
    }
#pragma unroll
    for (int ct = 0; ct < 4; ++ct) {
      int t = t0 + l15 + 16 * ct;
      float e = e_s[t];
#pragma unroll
      for (int r = 0; r < 4; ++r) {
        int s = srow_base + r;
        float val = (t <= s) ? s4[ct][r] * rsq * __expf(e - Ms[r]) : 0.f;
        s4[ct][r] = val;
        w_w[(crow + r) * 72 + l15 + 16 * ct] = f2bf(val);
      }
    }
#pragma unroll
    for (int r = 0; r < 4; ++r) {
      float tmp = s4[0][r] + s4[1][r] + s4[2][r] + s4[3][r];
      tmp += __shfl_xor(tmp, 1);
      tmp += __shfl_xor(tmp, 2);
      tmp += __shfl_xor(tmp, 4);
      tmp += __shfl_xor(tmp, 8);
      rsum[r] += tmp;
    }
    short8 wf0 = *(const short8*)&w_w[l15 * 72 + kg8];
    short8 wf1 = *(const short8*)&w_w[l15 * 72 + 32 + kg8];
#pragma unroll
    for (int dt = 0; dt < 8; ++dt) {
      int d = dt * 16 + l15;
      int sp0 = lg ^ (d & 7);
      int sp1 = (lg + 4) ^ (d & 7);
      short8 vf0 = *(const short8*)&Vc[d * 64 + sp0 * 8];
      short8 vf1 = *(const short8*)&Vc[d * 64 + sp1 * 8];
      acc[dt] = __builtin_amdgcn_mfma_f32_16x16x32_bf16(wf0, vf0, acc[dt], 0, 0, 0);
      acc[dt] = __builtin_amdgcn_mfma_f32_16x16x32_bf16(wf1, vf1, acc[dt], 0, 0, 0);
    }
    __builtin_amdgcn_s_barrier();
  }

  float scl[4], sum[4] = {}, sq[4] = {};
#pragma unroll
  for (int r = 0; r < 4; ++r) {
    float nrm = fmaxf(fabsf(rsum[r]), __expf(-md[r]));
    scl[r] = 1.0f / (nrm + 1e-6f);
  }
#pragma unroll
  for (int dt = 0; dt < 8; ++dt)
#pragma unroll
    for (int r = 0; r < 4; ++r) {
      float v = acc[dt][r] * scl[r];
      sum[r] += v;
      sq[r] += v * v;
    }
#pragma unroll
  for (int r = 0; r < 4; ++r) {
#pragma unroll
    for (int off = 1; off <= 8; off <<= 1) {
      sum[r] += __shfl_xor(sum[r], off);
      sq[r] += __shfl_xor(sq[r], off);
    }
  }
  float mu[4], rstd[4];
#pragma unroll
  for (int r = 0; r < 4; ++r) {
    mu[r] = sum[r] * (1.0f / DHH);
    float var = sq[r] * (1.0f / DHH) - mu[r] * mu[r];
    rstd[r] = rsqrtf(var + 1e-5f);
  }
#pragma unroll
  for (int dt = 0; dt < 8; ++dt) {
    int c = dt * 16 + l15;
    float gw = gnw[n * DHH + c];
    float sw = skw[n * DHH + c];
#pragma unroll
    for (int r = 0; r < 4; ++r) {
      size_t ridx = (size_t)(b * SS + srow_base + r);
      float v = acc[dt][r] * scl[r];
      float hn = (v - mu[r]) * rstd[r] * gw;
      float ca = bf2f(convact[ridx * II + n * DHH + c]);
      float z = bf2f(up[ridx * 2048 + II + n * DHH + c]);
      float sz = z / (1.0f + __expf(-z));
      hs[ridx * II + n * DHH + c] = f2bf((hn + sw * ca) * sz);
    }
  }
}

// ---------------- final LN(last row) + 2-layer head ----------------
__global__ __launch_bounds__(256) void k_head(const float* __restrict__ h,
                                              const float* __restrict__ pw,
                                              const float* __restrict__ pb,
                                              const float* __restrict__ w1,
                                              const float* __restrict__ b1,
                                              const float* __restrict__ w2,
                                              const float* __restrict__ b2,
                                              float* __restrict__ out) {
  int b = blockIdx.x;
  int tid = threadIdx.x;
  __shared__ float last[DD];
  __shared__ float hid[H1H];
  __shared__ float ss[4], sqs[4];
  const float* row = h + ((size_t)b * SS + SS - 1) * DD;
  float v0 = row[tid], v1 = row[tid + 256];
  float s = v0 + v1, sq = v0 * v0 + v1 * v1;
  for (int off = 32; off; off >>= 1) {
    s += __shfl_down(s, off);
    sq += __shfl_down(sq, off);
  }
  int wid = tid >> 6, lane = tid & 63;
  if (lane == 0) { ss[wid] = s; sqs[wid] = sq; }
  __syncthreads();
  if (tid == 0) {
    ss[0] = ss[0] + ss[1] + ss[2] + ss[3];
    sqs[0] = sqs[0] + sqs[1] + sqs[2] + sqs[3];
  }
  __syncthreads();
  float mean = ss[0] * (1.0f / DD);
  float var = sqs[0] * (1.0f / DD) - mean * mean;
  float r = rsqrtf(var + 1e-5f);
  last[tid] = (v0 - mean) * r * pw[tid] + pb[tid];
  last[tid + 256] = (v1 - mean) * r * pw[tid + 256] + pb[tid + 256];
  __syncthreads();
  if (tid < H1H) {
    float a = b1[tid];
    for (int d2 = 0; d2 < DD; ++d2) a += last[d2] * w1[(size_t)d2 * H1H + tid];
    hid[tid] = fmaxf(a, 0.f);
  }
  __syncthreads();
  if (tid < OUTO) {
    float a = b2[tid];
#pragma unroll
    for (int j2 = 0; j2 < H1H; ++j2) a += hid[j2] * w2[(size_t)j2 * OUTO + tid];
    out[(size_t)b * OUTO + tid] = a;
  }
}

extern "C" void kernel_launch(void* const* d_in, const int* in_sizes, int n_in,
                              void* d_out, int out_size, void* d_ws, size_t ws_size,
                              hipStream_t stream) {
  (void)in_sizes; (void)n_in; (void)out_size; (void)ws_size;
  const float* x    = (const float*)d_in[0];
  const float* in_w = (const float*)d_in[1];
  const float* in_b = (const float*)d_in[2];
  const float* ln_w = (const float*)d_in[3];
  const float* ln_b = (const float*)d_in[4];
  const float* up_w = (const float*)d_in[5];
  const float* conv_w = (const float*)d_in[6];
  const float* conv_b = (const float*)d_in[7];
  const float* q_w  = (const float*)d_in[8];
  const float* k_w  = (const float*)d_in[9];
  const float* v_w  = (const float*)d_in[10];
  const float* ig_w = (const float*)d_in[11];
  const float* ig_b = (const float*)d_in[12];
  const float* fg_w = (const float*)d_in[13];
  const float* fg_b = (const float*)d_in[14];
  const float* gn_w = (const float*)d_in[15];
  const float* sk_w = (const float*)d_in[16];
  const float* dn_w = (const float*)d_in[17];
  const float* po_w = (const float*)d_in[18];
  const float* po_b = (const float*)d_in[19];
  const float* h1_w = (const float*)d_in[20];
  const float* h1_b = (const float*)d_in[21];
  const float* h2_w = (const float*)d_in[22];
  const float* h2_b = (const float*)d_in[23];

  float* h = (float*)d_ws;                              // 2M f32
  ushort* xn_bf = (ushort*)(h + 2097152);               // 2M bf16
  ushort* up_bf = xn_bf + 2097152;                      // 8M bf16
  ushort* conv_bf = up_bf + 8388608;                    // 4M bf16
  ushort* qkb = conv_bf + 4194304;                      // 8M bf16 (q | k fused)
  ushort* vb = qkb + 8388608;                           // 4M bf16
  ushort* vbt = vb + 4194304;                           // 4M bf16 (per-head V^T)
  ushort* hs_bf = vbt + 4194304;                        // 4M bf16
  ushort* wt_up = hs_bf + 4194304;                      // 1M bf16
  ushort* wt_qk = wt_up + 1048576;                      // 2M bf16
  ushort* wt_v  = wt_qk + 2097152;                      // 1M bf16
  ushort* wt_dn = wt_v + 1048576;                       // 0.5M bf16
  ushort* Wg = wt_dn + 524288;                          // 49152 bf16
  float* igb_ = (float*)(Wg + 49152);
  float* fgb_ = igb_ + 32768;
  float* e_g  = fgb_ + 32768;
  float* M_g  = e_g + 32768;
  float* md_g = M_g + 32768;

  k_in_proj<<<BS / 16, 256, 0, stream>>>(x, in_w, in_b, h);
  for (int l = 0; l < 2; ++l) {
    k_layernorm<<<BS, 256, 0, stream>>>(h, ln_w + l * DD, ln_b + l * DD, xn_bf);
    k_wt_all<<<4620, 256, 0, stream>>>(up_w + (size_t)l * DD * 2 * II,
                                       q_w + (size_t)l * II * II,
                                       k_w + (size_t)l * II * II,
                                       v_w + (size_t)l * II * II,
                                       dn_w + (size_t)l * II * DD,
                                       ig_w + (size_t)l * 3 * II * NHH,
                                       fg_w + (size_t)l * 3 * II * NHH,
                                       wt_up, wt_qk, wt_v, wt_dn, Wg);
    // up: [4096,512] @ [512,2048]
    k_gemm_bf16<<<dim3(2 * II / 128, BS / 128, 1), 256, 0, stream>>>(
        xn_bf, DD, wt_up, DD, 2 * II, DD, nullptr, 0, 0, up_bf, 2 * II, nullptr);
    k_conv_silu<<<BS * II / 8 / 256, 256, 0, stream>>>(up_bf, conv_w + l * II * KK, conv_b + l * II, conv_bf);
    // q|k fused: conv_act @ [q_w k_w] -> qkb [4096][2048]
    k_gemm_bf16<<<dim3(2 * II / 128, BS / 128, 1), 256, 0, stream>>>(
        conv_bf, II, wt_qk, II, 2 * II, II, nullptr, 0, 0, qkb, 2 * II, nullptr);
    // v: x_m @ v_w (x_m = up_bf[..., :I], lda = 2I)
    k_gemm_bf16<<<dim3(II / 128, BS / 128, 1), 256, 0, stream>>>(
        up_bf, 2 * II, wt_v, II, II, II, nullptr, 0, 0, vb, II, vbt);
    k_gates_mfma<<<256, 64, 0, stream>>>(qkb, vb, Wg, ig_b + l * NHH, fg_b + l * NHH, igb_, fgb_);
    k_scan<<<BB * NHH, 64, 0, stream>>>(igb_, fgb_, e_g, M_g, md_g);
    k_attn_mfma<<<dim3(8, BB * NHH), 256, 0, stream>>>(qkb, vbt, e_g, M_g, md_g,
                                                       conv_bf, up_bf,
                                                       gn_w + l * II, sk_w + l * II, hs_bf);
    // down: hs @ down_w, split-K=4, atomic accumulate into h
    k_gemm_bf16<<<dim3(DD / 128, BS / 128, 4), 256, 0, stream>>>(
        hs_bf, II, wt_dn, II, DD, II, h, 1, 1, nullptr, 0, nullptr);
  }
  k_head<<<BB, 256, 0, stream>>>(h, po_w, po_b, h1_w, h1_b, h2_w, h2_b, (float*)d_out);
}

// Round 7
// 409.342 us; speedup vs baseline: 4.1257x; 1.0129x over previous
//
#include <hip/hip_runtime.h>
#include <math.h>

#define BB 8
#define SS 512
#define FF 64
#define DD 512
#define II 1024
#define NHH 8
#define KK 4
#define DHH 128
#define H1H 32
#define OUTO 24
#define BS (BB*SS)   // 4096

typedef unsigned short ushort;
typedef __attribute__((ext_vector_type(8))) short short8;
typedef __attribute__((ext_vector_type(8))) unsigned short ushort8;
typedef __attribute__((ext_vector_type(4))) unsigned short ushort4v;
typedef __attribute__((ext_vector_type(4))) float f32x4;

__device__ __forceinline__ float bf2f(ushort u) {
  return __uint_as_float(((unsigned int)u) << 16);
}
__device__ __forceinline__ ushort f2bf(float f) {
  unsigned int u = __float_as_uint(f);
  unsigned int r = u + 0x7fffu + ((u >> 16) & 1u);
  return (ushort)(r >> 16);
}

typedef __attribute__((address_space(1))) const void gvoid;
typedef __attribute__((address_space(3))) void lvoid;
__device__ __forceinline__ void async16(const void* g, void* l) {
  __builtin_amdgcn_global_load_lds((gvoid*)g, (lvoid*)l, 16, 0, 0);
}

// ---------------- input projection: h = x @ in_w + in_b ----------------
__global__ __launch_bounds__(256) void k_in_proj(const float* __restrict__ x,
                                                 const float* __restrict__ w,
                                                 const float* __restrict__ b,
                                                 float* __restrict__ h) {
  int r0 = blockIdx.x * 16;
  int tid = threadIdx.x;
  __shared__ float xs[16][FF];
  for (int i = tid; i < 16 * FF; i += 256)
    xs[i >> 6][i & 63] = x[(size_t)(r0 + (i >> 6)) * FF + (i & 63)];
  __syncthreads();
  float acc0[16], acc1[16];
  float b0 = b[tid], b1 = b[tid + 256];
#pragma unroll
  for (int r = 0; r < 16; ++r) { acc0[r] = b0; acc1[r] = b1; }
  for (int f = 0; f < FF; ++f) {
    float w0 = w[(size_t)f * DD + tid];
    float w1 = w[(size_t)f * DD + tid + 256];
#pragma unroll
    for (int r = 0; r < 16; ++r) {
      float xv = xs[r][f];
      acc0[r] += xv * w0;
      acc1[r] += xv * w1;
    }
  }
#pragma unroll
  for (int r = 0; r < 16; ++r) {
    h[(size_t)(r0 + r) * DD + tid] = acc0[r];
    h[(size_t)(r0 + r) * DD + tid + 256] = acc1[r];
  }
}

// ---------------- row layernorm over D=512 -> bf16 out ----------------
__global__ __launch_bounds__(256) void k_layernorm(const float* __restrict__ in,
                                                   const float* __restrict__ w,
                                                   const float* __restrict__ b,
                                                   ushort* __restrict__ out) {
  int row = blockIdx.x;
  int tid = threadIdx.x;
  float v0 = in[(size_t)row * DD + tid];
  float v1 = in[(size_t)row * DD + tid + 256];
  float s = v0 + v1, sq = v0 * v0 + v1 * v1;
  for (int off = 32; off; off >>= 1) {
    s += __shfl_down(s, off);
    sq += __shfl_down(sq, off);
  }
  __shared__ float ss[4], sqs[4];
  int wid = tid >> 6, lane = tid & 63;
  if (lane == 0) { ss[wid] = s; sqs[wid] = sq; }
  __syncthreads();
  if (tid == 0) {
    ss[0] = ss[0] + ss[1] + ss[2] + ss[3];
    sqs[0] = sqs[0] + sqs[1] + sqs[2] + sqs[3];
  }
  __syncthreads();
  float mean = ss[0] * (1.0f / DD);
  float var = sqs[0] * (1.0f / DD) - mean * mean;
  float r = rsqrtf(var + 1e-5f);
  out[(size_t)row * DD + tid] = f2bf((v0 - mean) * r * w[tid] + b[tid]);
  out[(size_t)row * DD + tid + 256] = f2bf((v1 - mean) * r * w[tid + 256] + b[tid + 256]);
}

// ---------------- fused weight convert+transpose for one layer ----------------
__global__ __launch_bounds__(256) void k_wt_all(const float* __restrict__ up_w,
                                                const float* __restrict__ q_w,
                                                const float* __restrict__ k_w,
                                                const float* __restrict__ v_w,
                                                const float* __restrict__ dn_w,
                                                const float* __restrict__ igw,
                                                const float* __restrict__ fgw,
                                                ushort* __restrict__ wt_up,
                                                ushort* __restrict__ wt_qk,
                                                ushort* __restrict__ wt_v,
                                                ushort* __restrict__ wt_dn,
                                                ushort* __restrict__ Wg) {
  int blk = blockIdx.x;
  int tid = threadIdx.x;
  if (blk >= 4608) {
    int k = (blk - 4608) * 256 + tid;
    if (k < 3 * II) {
#pragma unroll
      for (int o = 0; o < NHH; ++o) {
        Wg[(size_t)o * (3 * II) + k] = f2bf(igw[(size_t)k * NHH + o]);
        Wg[(size_t)(NHH + o) * (3 * II) + k] = f2bf(fgw[(size_t)k * NHH + o]);
      }
    }
    return;
  }
  const float* src; ushort* dst; int N, Kd, t;
  if (blk < 1024)      { src = up_w; dst = wt_up; N = 2048; Kd = 512;  t = blk; }
  else if (blk < 2048) { src = q_w;  dst = wt_qk; N = 1024; Kd = 1024; t = blk - 1024; }
  else if (blk < 3072) { src = k_w;  dst = wt_qk + 1024 * 1024; N = 1024; Kd = 1024; t = blk - 2048; }
  else if (blk < 4096) { src = v_w;  dst = wt_v;  N = 1024; Kd = 1024; t = blk - 3072; }
  else                 { src = dn_w; dst = wt_dn; N = 512;  Kd = 1024; t = blk - 4096; }
  int ntn = N >> 5;
  int n0 = (t % ntn) * 32, k0 = (t / ntn) * 32;
  __shared__ float tb[32][33];
  int c = tid & 31, r8 = tid >> 5;
  for (int rr = r8; rr < 32; rr += 8)
    tb[rr][c] = src[(size_t)(k0 + rr) * N + n0 + c];
  __syncthreads();
  for (int rr = r8; rr < 32; rr += 8)
    dst[(size_t)(n0 + rr) * Kd + k0 + c] = f2bf(tb[c][rr]);
}

// ---------------- bf16 MFMA GEMM, ring-4 prefetch distance-3, ONE barrier/iter ----------------
// C[M,N] (=|+=|atomic+=) A[M,K](lda) @ Wt[N,K]^T.  blockIdx.z = K-slice.
__global__ __launch_bounds__(256) void k_gemm_bf16(const ushort* __restrict__ A, int lda,
                                                   const ushort* __restrict__ Bt, int ldb,
                                                   int N, int Kd,
                                                   float* __restrict__ Cf, int accumulate,
                                                   int atomic,
                                                   ushort* __restrict__ Cb, int ldc,
                                                   ushort* __restrict__ Ct) {
  __shared__ ushort As[4][128 * 32];
  __shared__ ushort Bs[4][128 * 32];
  int tid = threadIdx.x;
  int wave = tid >> 6, lane = tid & 63;
  int m0 = blockIdx.y * 128, n0 = blockIdx.x * 128;
  int ksl = Kd / gridDim.z;
  int k0 = blockIdx.z * ksl;
  int wm = wave >> 1, wn = wave & 1;
  f32x4 acc[4][4] = {};

  int srow = wave * 32 + (lane >> 2);
  int scol = (lane & 3) * 8;
  const ushort* Ag = A + (size_t)(m0 + srow) * lda + k0 + scol;
  const ushort* Bg = Bt + (size_t)(n0 + srow) * ldb + k0 + scol;
  int woff = wave * 1024;

  int frow = lane & 15, fk = (lane >> 4) * 8;
  int apo = (wm * 64 + frow) * 32 + fk;
  int bpo = (wn * 64 + frow) * 32 + fk;

  int nkt = ksl >> 5;
  auto STAGE = [&](int p) {
    int kt = p * 32;
    int bi = p & 3;
    async16(Ag + kt, &As[bi][woff]);
    async16(Ag + kt + (size_t)16 * lda, &As[bi][woff + 512]);
    async16(Bg + kt, &Bs[bi][woff]);
    async16(Bg + kt + (size_t)16 * ldb, &Bs[bi][woff + 512]);
  };
  // prologue: stage tiles 0..2
#pragma unroll
  for (int p = 0; p < 3; ++p)
    if (p < nkt) STAGE(p);

  for (int it = 0; it < nkt; ++it) {
    int bey = nkt - 1 - it;
    if (bey >= 2)      asm volatile("s_waitcnt vmcnt(8)" ::: "memory");
    else if (bey == 1) asm volatile("s_waitcnt vmcnt(4)" ::: "memory");
    else               asm volatile("s_waitcnt vmcnt(0)" ::: "memory");
    __builtin_amdgcn_s_barrier();
    int buf = it & 3;
    const ushort* ap = &As[buf][apo];
    const ushort* bp = &Bs[buf][bpo];
    short8 a[4], b[4];
#pragma unroll
    for (int i = 0; i < 4; ++i) {
      a[i] = *(const short8*)(ap + i * 16 * 32);
      b[i] = *(const short8*)(bp + i * 16 * 32);
    }
#pragma unroll
    for (int i = 0; i < 4; ++i)
#pragma unroll
      for (int j = 0; j < 4; ++j)
        acc[i][j] = __builtin_amdgcn_mfma_f32_16x16x32_bf16(a[i], b[j], acc[i][j], 0, 0, 0);
    // stage tile it+3 over buffer (it-1)&3 — safe: all waves passed this iter's
    // barrier, i.e. finished reading buffer (it-1)&3 in the previous iteration.
    if (it + 3 < nkt) STAGE(it + 3);
  }

  int ccol = lane & 15, crow = (lane >> 4) * 4;
#pragma unroll
  for (int i = 0; i < 4; ++i) {
#pragma unroll
    for (int j = 0; j < 4; ++j) {
      int grow = m0 + wm * 64 + i * 16 + crow;
      int gcol = n0 + wn * 64 + j * 16 + ccol;
#pragma unroll
      for (int r = 0; r < 4; ++r) {
        float v = acc[i][j][r];
        if (Cf) {
          size_t idx = (size_t)(grow + r) * N + gcol;
          if (atomic) atomicAdd(&Cf[idx], v);
          else Cf[idx] = accumulate ? (Cf[idx] + v) : v;
        }
        if (Cb) Cb[(size_t)(grow + r) * ldc + gcol] = f2bf(v);
      }
      if (Ct) {
        int b8 = grow >> 9, sloc = grow & 511;
        int nh = gcol >> 7, d = gcol & 127;
        ushort4v o;
#pragma unroll
        for (int r = 0; r < 4; ++r) o[r] = f2bf(acc[i][j][r]);
        *(ushort4v*)&Ct[((size_t)(b8 * NHH + nh) * DHH + d) * SS + sloc] = o;
      }
    }
  }
}

// ---------------- causal conv (K=4) + SiLU, 8 channels/thread ----------------
__global__ __launch_bounds__(256) void k_conv_silu(const ushort* __restrict__ up,
                                                   const float* __restrict__ cw,
                                                   const float* __restrict__ cb,
                                                   ushort* __restrict__ out) {
  int g = blockIdx.x * 256 + threadIdx.x;
  int c8 = (g & 127) * 8;
  int row = g >> 7;
  int s = row & (SS - 1);
  float acc[8];
  float4 wv[8];
#pragma unroll
  for (int t = 0; t < 8; ++t) {
    acc[t] = cb[c8 + t];
    wv[t] = *(const float4*)(cw + (size_t)(c8 + t) * 4);
  }
#pragma unroll
  for (int j = 0; j < 4; ++j) {
    int so = s + j - 3;
    if (so >= 0) {
      ushort8 u = *(const ushort8*)&up[(size_t)(row + j - 3) * 2048 + c8];
#pragma unroll
      for (int t = 0; t < 8; ++t) {
        float wc = (j == 0) ? wv[t].x : (j == 1) ? wv[t].y : (j == 2) ? wv[t].z : wv[t].w;
        acc[t] += bf2f(u[t]) * wc;
      }
    }
  }
  ushort8 o;
#pragma unroll
  for (int t = 0; t < 8; ++t) {
    float sig = 1.0f / (1.0f + __expf(-acc[t]));
    o[t] = f2bf(acc[t] * sig);
  }
  *(ushort8*)&out[(size_t)row * II + c8] = o;
}

// ---------------- gate projections via MFMA ----------------
__global__ __launch_bounds__(64) void k_gates_mfma(const ushort* __restrict__ qkb,
                                                   const ushort* __restrict__ vb,
                                                   const ushort* __restrict__ Wg,
                                                   const float* __restrict__ igb,
                                                   const float* __restrict__ fgb,
                                                   float* __restrict__ ig,
                                                   float* __restrict__ fg) {
  int lane = threadIdx.x;
  int row0 = blockIdx.x * 16;
  int l15 = lane & 15, lg = lane >> 4;
  int arow = row0 + l15;
  const ushort* qrow = qkb + (size_t)arow * 2048 + lg * 8;
  const ushort* vrow = vb + (size_t)arow * II + lg * 8;
  const ushort* wrow = Wg + (size_t)l15 * (3 * II) + lg * 8;
  f32x4 acc0 = {}, acc1 = {};
#pragma unroll 4
  for (int k = 0; k < 2048; k += 64) {
    short8 a0 = *(const short8*)(qrow + k);
    short8 b0 = *(const short8*)(wrow + k);
    short8 a1 = *(const short8*)(qrow + k + 32);
    short8 b1 = *(const short8*)(wrow + k + 32);
    acc0 = __builtin_amdgcn_mfma_f32_16x16x32_bf16(a0, b0, acc0, 0, 0, 0);
    acc1 = __builtin_amdgcn_mfma_f32_16x16x32_bf16(a1, b1, acc1, 0, 0, 0);
  }
#pragma unroll 4
  for (int k = 0; k < 1024; k += 64) {
    short8 a0 = *(const short8*)(vrow + k);
    short8 b0 = *(const short8*)(wrow + 2048 + k);
    short8 a1 = *(const short8*)(vrow + k + 32);
    short8 b1 = *(const short8*)(wrow + 2048 + k + 32);
    acc0 = __builtin_amdgcn_mfma_f32_16x16x32_bf16(a0, b0, acc0, 0, 0, 0);
    acc1 = __builtin_amdgcn_mfma_f32_16x16x32_bf16(a1, b1, acc1, 0, 0, 0);
  }
  int o = l15;
#pragma unroll
  for (int r = 0; r < 4; ++r) {
    int row = row0 + lg * 4 + r;
    int bb = row >> 9, s = row & (SS - 1);
    float val = acc0[r] + acc1[r];
    if (o < NHH)
      ig[((size_t)bb * NHH + o) * SS + s] = val + igb[o];
    else
      fg[((size_t)bb * NHH + (o - NHH)) * SS + s] = val + fgb[o - NHH];
  }
}

// ---------------- per-(b,n) scan: one wave per bn, shfl prefix ----------------
__global__ __launch_bounds__(64) void k_scan(const float* __restrict__ ig,
                                             const float* __restrict__ fg,
                                             float* __restrict__ e_g, float* __restrict__ M_g,
                                             float* __restrict__ maxd_g) {
  int bn = blockIdx.x;
  int lane = threadIdx.x;
  size_t base = (size_t)bn * SS + lane * 8;
  float4 f0 = *(const float4*)&fg[base];
  float4 f1 = *(const float4*)&fg[base + 4];
  float fv[8] = {f0.x, f0.y, f0.z, f0.w, f1.x, f1.y, f1.z, f1.w};
  float lf[8];
#pragma unroll
  for (int j = 0; j < 8; ++j) {
    float f = fv[j];
    lf[j] = (f >= 0.f) ? -log1pf(expf(-f)) : (f - log1pf(expf(f)));
  }
  float cum[8];
  float run = 0.f;
#pragma unroll
  for (int j = 0; j < 8; ++j) { run += lf[j]; cum[j] = run; }
  float inc = run;
#pragma unroll
  for (int off = 1; off < 64; off <<= 1) {
    float t = __shfl_up(inc, off);
    if (lane >= off) inc += t;
  }
  float exs = inc - run;
  float4 i0 = *(const float4*)&ig[base];
  float4 i1 = *(const float4*)&ig[base + 4];
  float igv[8] = {i0.x, i0.y, i0.z, i0.w, i1.x, i1.y, i1.z, i1.w};
  float cs[8], e[8];
#pragma unroll
  for (int j = 0; j < 8; ++j) {
    cs[j] = exs + cum[j];
    e[j] = igv[j] - cs[j];
  }
  float mcum[8];
  float mrun = -3.0e38f;
#pragma unroll
  for (int j = 0; j < 8; ++j) { mrun = fmaxf(mrun, e[j]); mcum[j] = mrun; }
  float minc = mrun;
#pragma unroll
  for (int off = 1; off < 64; off <<= 1) {
    float t = __shfl_up(minc, off);
    if (lane >= off) minc = fmaxf(minc, t);
  }
  float mex = __shfl_up(minc, 1);
  if (lane == 0) mex = -3.0e38f;
  float M[8], mdv[8];
#pragma unroll
  for (int j = 0; j < 8; ++j) {
    M[j] = fmaxf(mex, mcum[j]);
    mdv[j] = cs[j] + M[j];
  }
  *(float4*)&e_g[base] = make_float4(e[0], e[1], e[2], e[3]);
  *(float4*)&e_g[base + 4] = make_float4(e[4], e[5], e[6], e[7]);
  *(float4*)&M_g[base] = make_float4(M[0], M[1], M[2], M[3]);
  *(float4*)&M_g[base + 4] = make_float4(M[4], M[5], M[6], M[7]);
  *(float4*)&maxd_g[base] = make_float4(mdv[0], mdv[1], mdv[2], mdv[3]);
  *(float4*)&maxd_g[base + 4] = make_float4(mdv[4], mdv[5], mdv[6], mdv[7]);
}

// ---------------- mLSTM attention, MFMA bf16, async dbuf staging, fused GN epilogue --------
__global__ __launch_bounds__(256) void k_attn_mfma(const ushort* __restrict__ qkb,
                                                   const ushort* __restrict__ vbt,
                                                   const float* __restrict__ e_g,
                                                   const float* __restrict__ M_g,
                                                   const float* __restrict__ maxd_g,
                                                   const ushort* __restrict__ convact,
                                                   const ushort* __restrict__ up,
                                                   const float* __restrict__ gnw,
                                                   const float* __restrict__ skw,
                                                   ushort* __restrict__ hs) {
  __shared__ __align__(16) ushort K2[2][64 * 128];
  __shared__ __align__(16) ushort V2[2][128 * 64];
  __shared__ __align__(16) ushort w_s[4][16 * 72];
  __shared__ float e_s[SS];

  int tid = threadIdx.x;
  int wave = tid >> 6, lane = tid & 63;
  int xb = blockIdx.x;
  int stile = (xb & 1) ? (7 - (xb >> 1)) : (xb >> 1);
  int bn = blockIdx.y;
  int b = bn >> 3, n = bn & 7;
  int s0 = stile * 64;

  const size_t qbase = (size_t)(b * SS) * 2048 + (size_t)n * DHH;
  const size_t kbase = qbase + II;
  const size_t vtbase = (size_t)bn * DHH * SS;

  int l15 = lane & 15, lg = lane >> 4;
  int kg8 = lg * 8;
  int crow = lg * 4;
  int srow_base = s0 + wave * 16 + crow;

  e_s[tid] = e_g[(size_t)bn * SS + tid];
  e_s[tid + 256] = e_g[(size_t)bn * SS + tid + 256];

  short8 qf[4];
  {
    int qrow = s0 + wave * 16 + l15;
#pragma unroll
    for (int ks = 0; ks < 4; ++ks)
      qf[ks] = *(const short8*)&qkb[qbase + (size_t)qrow * 2048 + ks * 32 + kg8];
  }
  float Ms[4], md[4];
#pragma unroll
  for (int r = 0; r < 4; ++r) {
    Ms[r] = M_g[(size_t)bn * SS + srow_base + r];
    md[r] = maxd_g[(size_t)bn * SS + srow_base + r];
  }

  f32x4 acc[8] = {};
  float rsum[4] = {};
  const float rsq = 0.08838834764831845f;
  ushort* w_w = &w_s[wave][0];
  int ntt = stile + 1;

#pragma unroll
  for (int i = 0; i < 4; ++i) {
    int r = wave * 16 + i * 4 + (lane >> 4);
    int sp = (lane & 15) ^ (r & 7);
    async16(&qkb[kbase + (size_t)r * 2048 + sp * 8], &K2[0][(wave * 16 + i * 4) * 128]);
  }
#pragma unroll
  for (int i = 0; i < 4; ++i) {
    int d = wave * 32 + i * 8 + (lane >> 3);
    int sp = (lane & 7) ^ (d & 7);
    async16(&vbt[vtbase + (size_t)d * SS + sp * 8], &V2[0][(wave * 32 + i * 8) * 64]);
  }

  for (int tt = 0; tt < ntt; ++tt) {
    int cur = tt & 1;
    if (tt + 1 < ntt) {
      int t1 = (tt + 1) * 64;
      int nxt = cur ^ 1;
#pragma unroll
      for (int i = 0; i < 4; ++i) {
        int r = wave * 16 + i * 4 + (lane >> 4);
        int sp = (lane & 15) ^ (r & 7);
        async16(&qkb[kbase + (size_t)(t1 + r) * 2048 + sp * 8], &K2[nxt][(wave * 16 + i * 4) * 128]);
      }
#pragma unroll
      for (int i = 0; i < 4; ++i) {
        int d = wave * 32 + i * 8 + (lane >> 3);
        int sp = (lane & 7) ^ (d & 7);
        async16(&vbt[vtbase + (size_t)d * SS + t1 + sp * 8], &V2[nxt][(wave * 32 + i * 8) * 64]);
      }
      asm volatile("s_waitcnt vmcnt(8) lgkmcnt(0)" ::: "memory");
    } else {
      asm volatile("s_waitcnt vmcnt(0) lgkmcnt(0)" ::: "memory");
    }
    __builtin_amdgcn_s_barrier();

    int t0 = tt * 64;
    const ushort* Kc = &K2[cur][0];
    const ushort* Vc = &V2[cur][0];

    f32x4 s4[4];
#pragma unroll
    for (int ct = 0; ct < 4; ++ct) {
      f32x4 c = {};
      int ro = l15 + 16 * ct;
#pragma unroll
      for (int ks = 0; ks < 4; ++ks) {
        int sp = (ks * 4 + lg) ^ (ro & 7);
        short8 kf = *(const short8*)&Kc[ro * 128 + sp * 8];
        c = __builtin_amdgcn_mfma_f32_16x16x32_bf16(qf[ks], kf, c, 0, 0, 0);
      }
      s4[ct] = c;
    }
#pragma unroll
    for (int ct = 0; ct < 4; ++ct) {
      int t = t0 + l15 + 16 * ct;
      float e = e_s[t];
#pragma unroll
      for (int r = 0; r < 4; ++r) {
        int s = srow_base + r;
        float val = (t <= s) ? s4[ct][r] * rsq * __expf(e - Ms[r]) : 0.f;
        s4[ct][r] = val;
        w_w[(crow + r) * 72 + l15 + 16 * ct] = f2bf(val);
      }
    }
#pragma unroll
    for (int r = 0; r < 4; ++r) {
      float tmp = s4[0][r] + s4[1][r] + s4[2][r] + s4[3][r];
      tmp += __shfl_xor(tmp, 1);
      tmp += __shfl_xor(tmp, 2);
      tmp += __shfl_xor(tmp, 4);
      tmp += __shfl_xor(tmp, 8);
      rsum[r] += tmp;
    }
    short8 wf0 = *(const short8*)&w_w[l15 * 72 + kg8];
    short8 wf1 = *(const short8*)&w_w[l15 * 72 + 32 + kg8];
#pragma unroll
    for (int dt = 0; dt < 8; ++dt) {
      int d = dt * 16 + l15;
      int sp0 = lg ^ (d & 7);
      int sp1 = (lg + 4) ^ (d & 7);
      short8 vf0 = *(const short8*)&Vc[d * 64 + sp0 * 8];
      short8 vf1 = *(const short8*)&Vc[d * 64 + sp1 * 8];
      acc[dt] = __builtin_amdgcn_mfma_f32_16x16x32_bf16(wf0, vf0, acc[dt], 0, 0, 0);
      acc[dt] = __builtin_amdgcn_mfma_f32_16x16x32_bf16(wf1, vf1, acc[dt], 0, 0, 0);
    }
    __builtin_amdgcn_s_barrier();
  }

  float scl[4], sum[4] = {}, sq[4] = {};
#pragma unroll
  for (int r = 0; r < 4; ++r) {
    float nrm = fmaxf(fabsf(rsum[r]), __expf(-md[r]));
    scl[r] = 1.0f / (nrm + 1e-6f);
  }
#pragma unroll
  for (int dt = 0; dt < 8; ++dt)
#pragma unroll
    for (int r = 0; r < 4; ++r) {
      float v = acc[dt][r] * scl[r];
      sum[r] += v;
      sq[r] += v * v;
    }
#pragma unroll
  for (int r = 0; r < 4; ++r) {
#pragma unroll
    for (int off = 1; off <= 8; off <<= 1) {
      sum[r] += __shfl_xor(sum[r], off);
      sq[r] += __shfl_xor(sq[r], off);
    }
  }
  float mu[4], rstd[4];
#pragma unroll
  for (int r = 0; r < 4; ++r) {
    mu[r] = sum[r] * (1.0f / DHH);
    float var = sq[r] * (1.0f / DHH) - mu[r] * mu[r];
    rstd[r] = rsqrtf(var + 1e-5f);
  }
#pragma unroll
  for (int dt = 0; dt < 8; ++dt) {
    int c = dt * 16 + l15;
    float gw = gnw[n * DHH + c];
    float sw = skw[n * DHH + c];
#pragma unroll
    for (int r = 0; r < 4; ++r) {
      size_t ridx = (size_t)(b * SS + srow_base + r);
      float v = acc[dt][r] * scl[r];
      float hn = (v - mu[r]) * rstd[r] * gw;
      float ca = bf2f(convact[ridx * II + n * DHH + c]);
      float z = bf2f(up[ridx * 2048 + II + n * DHH + c]);
      float sz = z / (1.0f + __expf(-z));
      hs[ridx * II + n * DHH + c] = f2bf((hn + sw * ca) * sz);
    }
  }
}

// ---------------- final LN(last row) + 2-layer head ----------------
__global__ __launch_bounds__(256) void k_head(const float* __restrict__ h,
                                              const float* __restrict__ pw,
                                              const float* __restrict__ pb,
                                              const float* __restrict__ w1,
                                              const float* __restrict__ b1,
                                              const float* __restrict__ w2,
                                              const float* __restrict__ b2,
                                              float* __restrict__ out) {
  int b = blockIdx.x;
  int tid = threadIdx.x;
  __shared__ float last[DD];
  __shared__ float hid[H1H];
  __shared__ float ss[4], sqs[4];
  const float* row = h + ((size_t)b * SS + SS - 1) * DD;
  float v0 = row[tid], v1 = row[tid + 256];
  float s = v0 + v1, sq = v0 * v0 + v1 * v1;
  for (int off = 32; off; off >>= 1) {
    s += __shfl_down(s, off);
    sq += __shfl_down(sq, off);
  }
  int wid = tid >> 6, lane = tid & 63;
  if (lane == 0) { ss[wid] = s; sqs[wid] = sq; }
  __syncthreads();
  if (tid == 0) {
    ss[0] = ss[0] + ss[1] + ss[2] + ss[3];
    sqs[0] = sqs[0] + sqs[1] + sqs[2] + sqs[3];
  }
  __syncthreads();
  float mean = ss[0] * (1.0f / DD);
  float var = sqs[0] * (1.0f / DD) - mean * mean;
  float r = rsqrtf(var + 1e-5f);
  last[tid] = (v0 - mean) * r * pw[tid] + pb[tid];
  last[tid + 256] = (v1 - mean) * r * pw[tid + 256] + pb[tid + 256];
  __syncthreads();
  if (tid < H1H) {
    float a = b1[tid];
    for (int d2 = 0; d2 < DD; ++d2) a += last[d2] * w1[(size_t)d2 * H1H + tid];
    hid[tid] = fmaxf(a, 0.f);
  }
  __syncthreads();
  if (tid < OUTO) {
    float a = b2[tid];
#pragma unroll
    for (int j2 = 0; j2 < H1H; ++j2) a += hid[j2] * w2[(size_t)j2 * OUTO + tid];
    out[(size_t)b * OUTO + tid] = a;
  }
}

extern "C" void kernel_launch(void* const* d_in, const int* in_sizes, int n_in,
                              void* d_out, int out_size, void* d_ws, size_t ws_size,
                              hipStream_t stream) {
  (void)in_sizes; (void)n_in; (void)out_size; (void)ws_size;
  const float* x    = (const float*)d_in[0];
  const float* in_w = (const float*)d_in[1];
  const float* in_b = (const float*)d_in[2];
  const float* ln_w = (const float*)d_in[3];
  const float* ln_b = (const float*)d_in[4];
  const float* up_w = (const float*)d_in[5];
  const float* conv_w = (const float*)d_in[6];
  const float* conv_b = (const float*)d_in[7];
  const float* q_w  = (const float*)d_in[8];
  const float* k_w  = (const float*)d_in[9];
  const float* v_w  = (const float*)d_in[10];
  const float* ig_w = (const float*)d_in[11];
  const float* ig_b = (const float*)d_in[12];
  const float* fg_w = (const float*)d_in[13];
  const float* fg_b = (const float*)d_in[14];
  const float* gn_w = (const float*)d_in[15];
  const float* sk_w = (const float*)d_in[16];
  const float* dn_w = (const float*)d_in[17];
  const float* po_w = (const float*)d_in[18];
  const float* po_b = (const float*)d_in[19];
  const float* h1_w = (const float*)d_in[20];
  const float* h1_b = (const float*)d_in[21];
  const float* h2_w = (const float*)d_in[22];
  const float* h2_b = (const float*)d_in[23];

  float* h = (float*)d_ws;                              // 2M f32
  ushort* xn_bf = (ushort*)(h + 2097152);               // 2M bf16
  ushort* up_bf = xn_bf + 2097152;                      // 8M bf16
  ushort* conv_bf = up_bf + 8388608;                    // 4M bf16
  ushort* qkb = conv_bf + 4194304;                      // 8M bf16 (q | k fused)
  ushort* vb = qkb + 8388608;                           // 4M bf16
  ushort* vbt = vb + 4194304;                           // 4M bf16 (per-head V^T)
  ushort* hs_bf = vbt + 4194304;                        // 4M bf16
  ushort* wt_up = hs_bf + 4194304;                      // 1M bf16
  ushort* wt_qk = wt_up + 1048576;                      // 2M bf16
  ushort* wt_v  = wt_qk + 2097152;                      // 1M bf16
  ushort* wt_dn = wt_v + 1048576;                       // 0.5M bf16
  ushort* Wg = wt_dn + 524288;                          // 49152 bf16
  float* igb_ = (float*)(Wg + 49152);
  float* fgb_ = igb_ + 32768;
  float* e_g  = fgb_ + 32768;
  float* M_g  = e_g + 32768;
  float* md_g = M_g + 32768;

  k_in_proj<<<BS / 16, 256, 0, stream>>>(x, in_w, in_b, h);
  for (int l = 0; l < 2; ++l) {
    k_layernorm<<<BS, 256, 0, stream>>>(h, ln_w + l * DD, ln_b + l * DD, xn_bf);
    k_wt_all<<<4620, 256, 0, stream>>>(up_w + (size_t)l * DD * 2 * II,
                                       q_w + (size_t)l * II * II,
                                       k_w + (size_t)l * II * II,
                                       v_w + (size_t)l * II * II,
                                       dn_w + (size_t)l * II * DD,
                                       ig_w + (size_t)l * 3 * II * NHH,
                                       fg_w + (size_t)l * 3 * II * NHH,
                                       wt_up, wt_qk, wt_v, wt_dn, Wg);
    // up: [4096,512] @ [512,2048]
    k_gemm_bf16<<<dim3(2 * II / 128, BS / 128, 1), 256, 0, stream>>>(
        xn_bf, DD, wt_up, DD, 2 * II, DD, nullptr, 0, 0, up_bf, 2 * II, nullptr);
    k_conv_silu<<<BS * II / 8 / 256, 256, 0, stream>>>(up_bf, conv_w + l * II * KK, conv_b + l * II, conv_bf);
    // q|k fused: conv_act @ [q_w k_w] -> qkb [4096][2048]
    k_gemm_bf16<<<dim3(2 * II / 128, BS / 128, 1), 256, 0, stream>>>(
        conv_bf, II, wt_qk, II, 2 * II, II, nullptr, 0, 0, qkb, 2 * II, nullptr);
    // v: x_m @ v_w (x_m = up_bf[..., :I], lda = 2I)
    k_gemm_bf16<<<dim3(II / 128, BS / 128, 1), 256, 0, stream>>>(
        up_bf, 2 * II, wt_v, II, II, II, nullptr, 0, 0, vb, II, vbt);
    k_gates_mfma<<<256, 64, 0, stream>>>(qkb, vb, Wg, ig_b + l * NHH, fg_b + l * NHH, igb_, fgb_);
    k_scan<<<BB * NHH, 64, 0, stream>>>(igb_, fgb_, e_g, M_g, md_g);
    k_attn_mfma<<<dim3(8, BB * NHH), 256, 0, stream>>>(qkb, vbt, e_g, M_g, md_g,
                                                       conv_bf, up_bf,
                                                       gn_w + l * II, sk_w + l * II, hs_bf);
    // down: hs @ down_w, split-K=4, atomic accumulate into h
    k_gemm_bf16<<<dim3(DD / 128, BS / 128, 4), 256, 0, stream>>>(
        hs_bf, II, wt_dn, II, DD, II, h, 1, 1, nullptr, 0, nullptr);
  }
  k_head<<<BB, 256, 0, stream>>>(h, po_w, po_b, h1_w, h1_b, h2_w, h2_b, (float*)d_out);
}

// Round 8
// 385.546 us; speedup vs baseline: 4.3803x; 1.0617x over previous
//
#include <hip/hip_runtime.h>
#include <math.h>

#define BB 8
#define SS 512
#define FF 64
#define DD 512
#define II 1024
#define NHH 8
#define KK 4
#define DHH 128
#define H1H 32
#define OUTO 24
#define BS (BB*SS)   // 4096

typedef unsigned short ushort;
typedef __attribute__((ext_vector_type(8))) short short8;
typedef __attribute__((ext_vector_type(8))) unsigned short ushort8;
typedef __attribute__((ext_vector_type(4))) unsigned short ushort4v;
typedef __attribute__((ext_vector_type(4))) float f32x4;

__device__ __forceinline__ float bf2f(ushort u) {
  return __uint_as_float(((unsigned int)u) << 16);
}
__device__ __forceinline__ ushort f2bf(float f) {
  unsigned int u = __float_as_uint(f);
  unsigned int r = u + 0x7fffu + ((u >> 16) & 1u);
  return (ushort)(r >> 16);
}

typedef __attribute__((address_space(1))) const void gvoid;
typedef __attribute__((address_space(3))) void lvoid;
__device__ __forceinline__ void async16(const void* g, void* l) {
  __builtin_amdgcn_global_load_lds((gvoid*)g, (lvoid*)l, 16, 0, 0);
}

// ---------------- input projection: h = x @ in_w + in_b ----------------
__global__ __launch_bounds__(256) void k_in_proj(const float* __restrict__ x,
                                                 const float* __restrict__ w,
                                                 const float* __restrict__ b,
                                                 float* __restrict__ h) {
  int r0 = blockIdx.x * 16;
  int tid = threadIdx.x;
  __shared__ float xs[16][FF];
  for (int i = tid; i < 16 * FF; i += 256)
    xs[i >> 6][i & 63] = x[(size_t)(r0 + (i >> 6)) * FF + (i & 63)];
  __syncthreads();
  float acc0[16], acc1[16];
  float b0 = b[tid], b1 = b[tid + 256];
#pragma unroll
  for (int r = 0; r < 16; ++r) { acc0[r] = b0; acc1[r] = b1; }
  for (int f = 0; f < FF; ++f) {
    float w0 = w[(size_t)f * DD + tid];
    float w1 = w[(size_t)f * DD + tid + 256];
#pragma unroll
    for (int r = 0; r < 16; ++r) {
      float xv = xs[r][f];
      acc0[r] += xv * w0;
      acc1[r] += xv * w1;
    }
  }
#pragma unroll
  for (int r = 0; r < 16; ++r) {
    h[(size_t)(r0 + r) * DD + tid] = acc0[r];
    h[(size_t)(r0 + r) * DD + tid + 256] = acc1[r];
  }
}

// ---------------- row layernorm over D=512 -> bf16 out ----------------
__global__ __launch_bounds__(256) void k_layernorm(const float* __restrict__ in,
                                                   const float* __restrict__ w,
                                                   const float* __restrict__ b,
                                                   ushort* __restrict__ out) {
  int row = blockIdx.x;
  int tid = threadIdx.x;
  float v0 = in[(size_t)row * DD + tid];
  float v1 = in[(size_t)row * DD + tid + 256];
  float s = v0 + v1, sq = v0 * v0 + v1 * v1;
  for (int off = 32; off; off >>= 1) {
    s += __shfl_down(s, off);
    sq += __shfl_down(sq, off);
  }
  __shared__ float ss[4], sqs[4];
  int wid = tid >> 6, lane = tid & 63;
  if (lane == 0) { ss[wid] = s; sqs[wid] = sq; }
  __syncthreads();
  if (tid == 0) {
    ss[0] = ss[0] + ss[1] + ss[2] + ss[3];
    sqs[0] = sqs[0] + sqs[1] + sqs[2] + sqs[3];
  }
  __syncthreads();
  float mean = ss[0] * (1.0f / DD);
  float var = sqs[0] * (1.0f / DD) - mean * mean;
  float r = rsqrtf(var + 1e-5f);
  out[(size_t)row * DD + tid] = f2bf((v0 - mean) * r * w[tid] + b[tid]);
  out[(size_t)row * DD + tid + 256] = f2bf((v1 - mean) * r * w[tid + 256] + b[tid + 256]);
}

// ---------------- fused weight convert+transpose, BOTH layers in one launch ----------------
// per layer 4620 blocks: 0..1023 up_w, 1024..2047 q_w, 2048..3071 k_w,
// 3072..4095 v_w, 4096..4607 dn_w, 4608..4619 gate pack.
__global__ __launch_bounds__(256) void k_wt_all(const float* __restrict__ up_w,
                                                const float* __restrict__ q_w,
                                                const float* __restrict__ k_w,
                                                const float* __restrict__ v_w,
                                                const float* __restrict__ dn_w,
                                                const float* __restrict__ igw,
                                                const float* __restrict__ fgw,
                                                ushort* __restrict__ wt_up,
                                                ushort* __restrict__ wt_qk,
                                                ushort* __restrict__ wt_v,
                                                ushort* __restrict__ wt_dn,
                                                ushort* __restrict__ Wg) {
  int blk = blockIdx.x;
  int l = blk / 4620;
  blk -= l * 4620;
  int tid = threadIdx.x;
  if (blk >= 4608) {
    const float* igwl = igw + (size_t)l * 3 * II * NHH;
    const float* fgwl = fgw + (size_t)l * 3 * II * NHH;
    ushort* Wgl = Wg + (size_t)l * 16 * 3 * II;
    int k = (blk - 4608) * 256 + tid;
    if (k < 3 * II) {
#pragma unroll
      for (int o = 0; o < NHH; ++o) {
        Wgl[(size_t)o * (3 * II) + k] = f2bf(igwl[(size_t)k * NHH + o]);
        Wgl[(size_t)(NHH + o) * (3 * II) + k] = f2bf(fgwl[(size_t)k * NHH + o]);
      }
    }
    return;
  }
  const float* src; ushort* dst; int N, Kd, t;
  if (blk < 1024)      { src = up_w + (size_t)l * DD * 2 * II; dst = wt_up + (size_t)l * 1048576; N = 2048; Kd = 512;  t = blk; }
  else if (blk < 2048) { src = q_w + (size_t)l * II * II;  dst = wt_qk + (size_t)l * 2097152; N = 1024; Kd = 1024; t = blk - 1024; }
  else if (blk < 3072) { src = k_w + (size_t)l * II * II;  dst = wt_qk + (size_t)l * 2097152 + 1024 * 1024; N = 1024; Kd = 1024; t = blk - 2048; }
  else if (blk < 4096) { src = v_w + (size_t)l * II * II;  dst = wt_v + (size_t)l * 1048576;  N = 1024; Kd = 1024; t = blk - 3072; }
  else                 { src = dn_w + (size_t)l * II * DD; dst = wt_dn + (size_t)l * 524288;  N = 512;  Kd = 1024; t = blk - 4096; }
  int ntn = N >> 5;
  int n0 = (t % ntn) * 32, k0 = (t / ntn) * 32;
  __shared__ float tb[32][33];
  int c = tid & 31, r8 = tid >> 5;
  for (int rr = r8; rr < 32; rr += 8)
    tb[rr][c] = src[(size_t)(k0 + rr) * N + n0 + c];
  __syncthreads();
  for (int rr = r8; rr < 32; rr += 8)
    dst[(size_t)(n0 + rr) * Kd + k0 + c] = f2bf(tb[c][rr]);
}

// ---------------- 8-wave GEMM core: 128x128 tile, wave=32x64, ring-4, counted vmcnt -------
// Each wave stages 16 rows of A and of B (1 async16 each per K-step).
__device__ __forceinline__ void gemm_core8(const ushort* __restrict__ Ag,
                                           const ushort* __restrict__ Bg,
                                           int nkt, ushort* AsB, ushort* BsB,
                                           int woff, int apo, int bpo,
                                           f32x4 (&acc)[2][4]) {
#define STAGE8(p) { int kt_ = (p) * 32; int bi_ = (p) & 3; \
    async16(Ag + kt_, AsB + bi_ * 4096 + woff); \
    async16(Bg + kt_, BsB + bi_ * 4096 + woff); }
  if (0 < nkt) STAGE8(0);
  if (1 < nkt) STAGE8(1);
  if (2 < nkt) STAGE8(2);
  for (int it = 0; it < nkt; ++it) {
    int bey = nkt - 1 - it;
    if (bey >= 2)      asm volatile("s_waitcnt vmcnt(4)" ::: "memory");
    else if (bey == 1) asm volatile("s_waitcnt vmcnt(2)" ::: "memory");
    else               asm volatile("s_waitcnt vmcnt(0)" ::: "memory");
    __builtin_amdgcn_s_barrier();
    int bi = it & 3;
    const ushort* ap = AsB + bi * 4096 + apo;
    const ushort* bp = BsB + bi * 4096 + bpo;
    short8 a[2], b[4];
#pragma unroll
    for (int i = 0; i < 2; ++i) a[i] = *(const short8*)(ap + i * 16 * 32);
#pragma unroll
    for (int j = 0; j < 4; ++j) b[j] = *(const short8*)(bp + j * 16 * 32);
#pragma unroll
    for (int i = 0; i < 2; ++i)
#pragma unroll
      for (int j = 0; j < 4; ++j)
        acc[i][j] = __builtin_amdgcn_mfma_f32_16x16x32_bf16(a[i], b[j], acc[i][j], 0, 0, 0);
    // stage tile it+3 over buffer (it-1)&3: all waves passed this iter's barrier,
    // so everyone finished reading that buffer last iteration.
    if (it + 3 < nkt) STAGE8(it + 3);
  }
#undef STAGE8
}

// ---------------- up GEMM: up = xn @ wt_up^T  (K=512, N=2048, bf16 out) ----------------
__global__ __launch_bounds__(512) void k_gemm_up(const ushort* __restrict__ A,
                                                 const ushort* __restrict__ Bt,
                                                 ushort* __restrict__ Cb) {
  __shared__ ushort As[4][4096];
  __shared__ ushort Bs[4][4096];
  int tid = threadIdx.x;
  int wave = tid >> 6, lane = tid & 63;
  int wm = wave >> 1, wn = wave & 1;
  int m0 = blockIdx.y * 128, n0 = blockIdx.x * 128;
  int srow = wave * 16 + (lane >> 2), scol = (lane & 3) * 8;
  const ushort* Ag = A + (size_t)(m0 + srow) * DD + scol;
  const ushort* Bg = Bt + (size_t)(n0 + srow) * DD + scol;
  int woff = wave * 512;
  int frow = lane & 15, fk = (lane >> 4) * 8;
  int apo = (wm * 32 + frow) * 32 + fk;
  int bpo = (wn * 64 + frow) * 32 + fk;
  f32x4 acc[2][4] = {};
  gemm_core8(Ag, Bg, DD / 32, &As[0][0], &Bs[0][0], woff, apo, bpo, acc);
  int ccol = lane & 15, crow = (lane >> 4) * 4;
#pragma unroll
  for (int i = 0; i < 2; ++i)
#pragma unroll
    for (int j = 0; j < 4; ++j) {
      int grow = m0 + wm * 32 + i * 16 + crow;
      int gcol = n0 + wn * 64 + j * 16 + ccol;
#pragma unroll
      for (int r = 0; r < 4; ++r)
        Cb[(size_t)(grow + r) * 2048 + gcol] = f2bf(acc[i][j][r]);
    }
}

// ---------------- fused qk|v GEMM: bx<16 -> qk (A=conv), else v (A=up, +V^T out) --------
__global__ __launch_bounds__(512) void k_gemm_qkv(const ushort* __restrict__ convb,
                                                  const ushort* __restrict__ upb,
                                                  const ushort* __restrict__ wt_qk,
                                                  const ushort* __restrict__ wt_v,
                                                  ushort* __restrict__ qkb,
                                                  ushort* __restrict__ vb,
                                                  ushort* __restrict__ vbt) {
  __shared__ ushort As[4][4096];
  __shared__ ushort Bs[4][4096];
  int tid = threadIdx.x;
  int wave = tid >> 6, lane = tid & 63;
  int wm = wave >> 1, wn = wave & 1;
  int bx = blockIdx.x;
  int isv = bx >= 16;
  int m0 = blockIdx.y * 128;
  int n0 = (isv ? bx - 16 : bx) * 128;
  const ushort* A = isv ? upb : convb;
  int lda = isv ? 2048 : 1024;
  const ushort* Bt = isv ? wt_v : wt_qk;
  int srow = wave * 16 + (lane >> 2), scol = (lane & 3) * 8;
  const ushort* Ag = A + (size_t)(m0 + srow) * lda + scol;
  const ushort* Bg = Bt + (size_t)(n0 + srow) * II + scol;
  int woff = wave * 512;
  int frow = lane & 15, fk = (lane >> 4) * 8;
  int apo = (wm * 32 + frow) * 32 + fk;
  int bpo = (wn * 64 + frow) * 32 + fk;
  f32x4 acc[2][4] = {};
  gemm_core8(Ag, Bg, II / 32, &As[0][0], &Bs[0][0], woff, apo, bpo, acc);
  int ccol = lane & 15, crow = (lane >> 4) * 4;
#pragma unroll
  for (int i = 0; i < 2; ++i)
#pragma unroll
    for (int j = 0; j < 4; ++j) {
      int grow = m0 + wm * 32 + i * 16 + crow;
      int gcol = n0 + wn * 64 + j * 16 + ccol;
      if (!isv) {
#pragma unroll
        for (int r = 0; r < 4; ++r)
          qkb[(size_t)(grow + r) * 2048 + gcol] = f2bf(acc[i][j][r]);
      } else {
#pragma unroll
        for (int r = 0; r < 4; ++r)
          vb[(size_t)(grow + r) * II + gcol] = f2bf(acc[i][j][r]);
        int b8 = grow >> 9, sloc = grow & 511;
        int nh = gcol >> 7, d = gcol & 127;
        ushort4v o;
#pragma unroll
        for (int r = 0; r < 4; ++r) o[r] = f2bf(acc[i][j][r]);
        *(ushort4v*)&vbt[((size_t)(b8 * NHH + nh) * DHH + d) * SS + sloc] = o;
      }
    }
}

// ---------------- down GEMM: split-K=4, atomic f32 accumulate into h ----------------
__global__ __launch_bounds__(512) void k_gemm_down(const ushort* __restrict__ A,
                                                   const ushort* __restrict__ Bt,
                                                   float* __restrict__ Cf) {
  __shared__ ushort As[4][4096];
  __shared__ ushort Bs[4][4096];
  int tid = threadIdx.x;
  int wave = tid >> 6, lane = tid & 63;
  int wm = wave >> 1, wn = wave & 1;
  int m0 = blockIdx.y * 128, n0 = blockIdx.x * 128;
  int k0 = blockIdx.z * 256;
  int srow = wave * 16 + (lane >> 2), scol = (lane & 3) * 8;
  const ushort* Ag = A + (size_t)(m0 + srow) * II + k0 + scol;
  const ushort* Bg = Bt + (size_t)(n0 + srow) * II + k0 + scol;
  int woff = wave * 512;
  int frow = lane & 15, fk = (lane >> 4) * 8;
  int apo = (wm * 32 + frow) * 32 + fk;
  int bpo = (wn * 64 + frow) * 32 + fk;
  f32x4 acc[2][4] = {};
  gemm_core8(Ag, Bg, 256 / 32, &As[0][0], &Bs[0][0], woff, apo, bpo, acc);
  int ccol = lane & 15, crow = (lane >> 4) * 4;
#pragma unroll
  for (int i = 0; i < 2; ++i)
#pragma unroll
    for (int j = 0; j < 4; ++j) {
      int grow = m0 + wm * 32 + i * 16 + crow;
      int gcol = n0 + wn * 64 + j * 16 + ccol;
#pragma unroll
      for (int r = 0; r < 4; ++r)
        atomicAdd(&Cf[(size_t)(grow + r) * DD + gcol], acc[i][j][r]);
    }
}

// ---------------- causal conv (K=4) + SiLU, 8 channels/thread ----------------
__global__ __launch_bounds__(256) void k_conv_silu(const ushort* __restrict__ up,
                                                   const float* __restrict__ cw,
                                                   const float* __restrict__ cb,
                                                   ushort* __restrict__ out) {
  int g = blockIdx.x * 256 + threadIdx.x;
  int c8 = (g & 127) * 8;
  int row = g >> 7;
  int s = row & (SS - 1);
  float acc[8];
  float4 wv[8];
#pragma unroll
  for (int t = 0; t < 8; ++t) {
    acc[t] = cb[c8 + t];
    wv[t] = *(const float4*)(cw + (size_t)(c8 + t) * 4);
  }
#pragma unroll
  for (int j = 0; j < 4; ++j) {
    int so = s + j - 3;
    if (so >= 0) {
      ushort8 u = *(const ushort8*)&up[(size_t)(row + j - 3) * 2048 + c8];
#pragma unroll
      for (int t = 0; t < 8; ++t) {
        float wc = (j == 0) ? wv[t].x : (j == 1) ? wv[t].y : (j == 2) ? wv[t].z : wv[t].w;
        acc[t] += bf2f(u[t]) * wc;
      }
    }
  }
  ushort8 o;
#pragma unroll
  for (int t = 0; t < 8; ++t) {
    float sig = 1.0f / (1.0f + __expf(-acc[t]));
    o[t] = f2bf(acc[t] * sig);
  }
  *(ushort8*)&out[(size_t)row * II + c8] = o;
}

// ---------------- gate projections via MFMA ----------------
__global__ __launch_bounds__(64) void k_gates_mfma(const ushort* __restrict__ qkb,
                                                   const ushort* __restrict__ vb,
                                                   const ushort* __restrict__ Wg,
                                                   const float* __restrict__ igb,
                                                   const float* __restrict__ fgb,
                                                   float* __restrict__ ig,
                                                   float* __restrict__ fg) {
  int lane = threadIdx.x;
  int row0 = blockIdx.x * 16;
  int l15 = lane & 15, lg = lane >> 4;
  int arow = row0 + l15;
  const ushort* qrow = qkb + (size_t)arow * 2048 + lg * 8;
  const ushort* vrow = vb + (size_t)arow * II + lg * 8;
  const ushort* wrow = Wg + (size_t)l15 * (3 * II) + lg * 8;
  f32x4 acc0 = {}, acc1 = {};
#pragma unroll 4
  for (int k = 0; k < 2048; k += 64) {
    short8 a0 = *(const short8*)(qrow + k);
    short8 b0 = *(const short8*)(wrow + k);
    short8 a1 = *(const short8*)(qrow + k + 32);
    short8 b1 = *(const short8*)(wrow + k + 32);
    acc0 = __builtin_amdgcn_mfma_f32_16x16x32_bf16(a0, b0, acc0, 0, 0, 0);
    acc1 = __builtin_amdgcn_mfma_f32_16x16x32_bf16(a1, b1, acc1, 0, 0, 0);
  }
#pragma unroll 4
  for (int k = 0; k < 1024; k += 64) {
    short8 a0 = *(const short8*)(vrow + k);
    short8 b0 = *(const short8*)(wrow + 2048 + k);
    short8 a1 = *(const short8*)(vrow + k + 32);
    short8 b1 = *(const short8*)(wrow + 2048 + k + 32);
    acc0 = __builtin_amdgcn_mfma_f32_16x16x32_bf16(a0, b0, acc0, 0, 0, 0);
    acc1 = __builtin_amdgcn_mfma_f32_16x16x32_bf16(a1, b1, acc1, 0, 0, 0);
  }
  int o = l15;
#pragma unroll
  for (int r = 0; r < 4; ++r) {
    int row = row0 + lg * 4 + r;
    int bb = row >> 9, s = row & (SS - 1);
    float val = acc0[r] + acc1[r];
    if (o < NHH)
      ig[((size_t)bb * NHH + o) * SS + s] = val + igb[o];
    else
      fg[((size_t)bb * NHH + (o - NHH)) * SS + s] = val + fgb[o - NHH];
  }
}

// ---------------- per-(b,n) scan: one wave per bn, shfl prefix ----------------
__global__ __launch_bounds__(64) void k_scan(const float* __restrict__ ig,
                                             const float* __restrict__ fg,
                                             float* __restrict__ e_g, float* __restrict__ M_g,
                                             float* __restrict__ maxd_g) {
  int bn = blockIdx.x;
  int lane = threadIdx.x;
  size_t base = (size_t)bn * SS + lane * 8;
  float4 f0 = *(const float4*)&fg[base];
  float4 f1 = *(const float4*)&fg[base + 4];
  float fv[8] = {f0.x, f0.y, f0.z, f0.w, f1.x, f1.y, f1.z, f1.w};
  float lf[8];
#pragma unroll
  for (int j = 0; j < 8; ++j) {
    float f = fv[j];
    lf[j] = (f >= 0.f) ? -log1pf(expf(-f)) : (f - log1pf(expf(f)));
  }
  float cum[8];
  float run = 0.f;
#pragma unroll
  for (int j = 0; j < 8; ++j) { run += lf[j]; cum[j] = run; }
  float inc = run;
#pragma unroll
  for (int off = 1; off < 64; off <<= 1) {
    float t = __shfl_up(inc, off);
    if (lane >= off) inc += t;
  }
  float exs = inc - run;
  float4 i0 = *(const float4*)&ig[base];
  float4 i1 = *(const float4*)&ig[base + 4];
  float igv[8] = {i0.x, i0.y, i0.z, i0.w, i1.x, i1.y, i1.z, i1.w};
  float cs[8], e[8];
#pragma unroll
  for (int j = 0; j < 8; ++j) {
    cs[j] = exs + cum[j];
    e[j] = igv[j] - cs[j];
  }
  float mcum[8];
  float mrun = -3.0e38f;
#pragma unroll
  for (int j = 0; j < 8; ++j) { mrun = fmaxf(mrun, e[j]); mcum[j] = mrun; }
  float minc = mrun;
#pragma unroll
  for (int off = 1; off < 64; off <<= 1) {
    float t = __shfl_up(minc, off);
    if (lane >= off) minc = fmaxf(minc, t);
  }
  float mex = __shfl_up(minc, 1);
  if (lane == 0) mex = -3.0e38f;
  float M[8], mdv[8];
#pragma unroll
  for (int j = 0; j < 8; ++j) {
    M[j] = fmaxf(mex, mcum[j]);
    mdv[j] = cs[j] + M[j];
  }
  *(float4*)&e_g[base] = make_float4(e[0], e[1], e[2], e[3]);
  *(float4*)&e_g[base + 4] = make_float4(e[4], e[5], e[6], e[7]);
  *(float4*)&M_g[base] = make_float4(M[0], M[1], M[2], M[3]);
  *(float4*)&M_g[base + 4] = make_float4(M[4], M[5], M[6], M[7]);
  *(float4*)&maxd_g[base] = make_float4(mdv[0], mdv[1], mdv[2], mdv[3]);
  *(float4*)&maxd_g[base + 4] = make_float4(mdv[4], mdv[5], mdv[6], mdv[7]);
}

// ---------------- mLSTM attention, MFMA bf16, async dbuf staging, fused GN epilogue --------
__global__ __launch_bounds__(256) void k_attn_mfma(const ushort* __restrict__ qkb,
                                                   const ushort* __restrict__ vbt,
                                                   const float* __restrict__ e_g,
                                                   const float* __restrict__ M_g,
                                                   const float* __restrict__ maxd_g,
                                                   const ushort* __restrict__ convact,
                                                   const ushort* __restrict__ up,
                                                   const float* __restrict__ gnw,
                                                   const float* __restrict__ skw,
                                                   ushort* __restrict__ hs) {
  __shared__ __align__(16) ushort K2[2][64 * 128];
  __shared__ __align__(16) ushort V2[2][128 * 64];
  __shared__ __align__(16) ushort w_s[4][16 * 72];
  __shared__ float e_s[SS];

  int tid = threadIdx.x;
  int wave = tid >> 6, lane = tid & 63;
  int xb = blockIdx.x;
  int stile = (xb & 1) ? (7 - (xb >> 1)) : (xb >> 1);
  int bn = blockIdx.y;
  int b = bn >> 3, n = bn & 7;
  int s0 = stile * 64;

  const size_t qbase = (size_t)(b * SS) * 2048 + (size_t)n * DHH;
  const size_t kbase = qbase + II;
  const size_t vtbase = (size_t)bn * DHH * SS;

  int l15 = lane & 15, lg = lane >> 4;
  int kg8 = lg * 8;
  int crow = lg * 4;
  int srow_base = s0 + wave * 16 + crow;

  e_s[tid] = e_g[(size_t)bn * SS + tid];
  e_s[tid + 256] = e_g[(size_t)bn * SS + tid + 256];

  short8 qf[4];
  {
    int qrow = s0 + wave * 16 + l15;
#pragma unroll
    for (int ks = 0; ks < 4; ++ks)
      qf[ks] = *(const short8*)&qkb[qbase + (size_t)qrow * 2048 + ks * 32 + kg8];
  }
  float Ms[4], md[4];
#pragma unroll
  for (int r = 0; r < 4; ++r) {
    Ms[r] = M_g[(size_t)bn * SS + srow_base + r];
    md[r] = maxd_g[(size_t)bn * SS + srow_base + r];
  }

  f32x4 acc[8] = {};
  float rsum[4] = {};
  const float rsq = 0.08838834764831845f;
  ushort* w_w = &w_s[wave][0];
  int ntt = stile + 1;

#pragma unroll
  for (int i = 0; i < 4; ++i) {
    int r = wave * 16 + i * 4 + (lane >> 4);
    int sp = (lane & 15) ^ (r & 7);
    async16(&qkb[kbase + (size_t)r * 2048 + sp * 8], &K2[0][(wave * 16 + i * 4) * 128]);
  }
#pragma unroll
  for (int i = 0; i < 4; ++i) {
    int d = wave * 32 + i * 8 + (lane >> 3);
    int sp = (lane & 7) ^ (d & 7);
    async16(&vbt[vtbase + (size_t)d * SS + sp * 8], &V2[0][(wave * 32 + i * 8) * 64]);
  }

  for (int tt = 0; tt < ntt; ++tt) {
    int cur = tt & 1;
    if (tt + 1 < ntt) {
      int t1 = (tt + 1) * 64;
      int nxt = cur ^ 1;
#pragma unroll
      for (int i = 0; i < 4; ++i) {
        int r = wave * 16 + i * 4 + (lane >> 4);
        int sp = (lane & 15) ^ (r & 7);
        async16(&qkb[kbase + (size_t)(t1 + r) * 2048 + sp * 8], &K2[nxt][(wave * 16 + i * 4) * 128]);
      }
#pragma unroll
      for (int i = 0; i < 4; ++i) {
        int d = wave * 32 + i * 8 + (lane >> 3);
        int sp = (lane & 7) ^ (d & 7);
        async16(&vbt[vtbase + (size_t)d * SS + t1 + sp * 8], &V2[nxt][(wave * 32 + i * 8) * 64]);
      }
      asm volatile("s_waitcnt vmcnt(8) lgkmcnt(0)" ::: "memory");
    } else {
      asm volatile("s_waitcnt vmcnt(0) lgkmcnt(0)" ::: "memory");
    }
    __builtin_amdgcn_s_barrier();

    int t0 = tt * 64;
    const ushort* Kc = &K2[cur][0];
    const ushort* Vc = &V2[cur][0];

    f32x4 s4[4];
#pragma unroll
    for (int ct = 0; ct < 4; ++ct) {
      f32x4 c = {};
      int ro = l15 + 16 * ct;
#pragma unroll
      for (int ks = 0; ks < 4; ++ks) {
        int sp = (ks * 4 + lg) ^ (ro & 7);
        short8 kf = *(const short8*)&Kc[ro * 128 + sp * 8];
        c = __builtin_amdgcn_mfma_f32_16x16x32_bf16(qf[ks], kf, c, 0, 0, 0);
      }
      s4[ct] = c;
    }
#pragma unroll
    for (int ct = 0; ct < 4; ++ct) {
      int t = t0 + l15 + 16 * ct;
      float e = e_s[t];
#pragma unroll
      for (int r = 0; r < 4; ++r) {
        int s = srow_base + r;
        float val = (t <= s) ? s4[ct][r] * rsq * __expf(e - Ms[r]) : 0.f;
        s4[ct][r] = val;
        w_w[(crow + r) * 72 + l15 + 16 * ct] = f2bf(val);
      }
    }
#pragma unroll
    for (int r = 0; r < 4; ++r) {
      float tmp = s4[0][r] + s4[1][r] + s4[2][r] + s4[3][r];
      tmp += __shfl_xor(tmp, 1);
      tmp += __shfl_xor(tmp, 2);
      tmp += __shfl_xor(tmp, 4);
      tmp += __shfl_xor(tmp, 8);
      rsum[r] += tmp;
    }
    short8 wf0 = *(const short8*)&w_w[l15 * 72 + kg8];
    short8 wf1 = *(const short8*)&w_w[l15 * 72 + 32 + kg8];
#pragma unroll
    for (int dt = 0; dt < 8; ++dt) {
      int d = dt * 16 + l15;
      int sp0 = lg ^ (d & 7);
      int sp1 = (lg + 4) ^ (d & 7);
      short8 vf0 = *(const short8*)&Vc[d * 64 + sp0 * 8];
      short8 vf1 = *(const short8*)&Vc[d * 64 + sp1 * 8];
      acc[dt] = __builtin_amdgcn_mfma_f32_16x16x32_bf16(wf0, vf0, acc[dt], 0, 0, 0);
      acc[dt] = __builtin_amdgcn_mfma_f32_16x16x32_bf16(wf1, vf1, acc[dt], 0, 0, 0);
    }
    __builtin_amdgcn_s_barrier();
  }

  float scl[4], sum[4] = {}, sq[4] = {};
#pragma unroll
  for (int r = 0; r < 4; ++r) {
    float nrm = fmaxf(fabsf(rsum[r]), __expf(-md[r]));
    scl[r] = 1.0f / (nrm + 1e-6f);
  }
#pragma unroll
  for (int dt = 0; dt < 8; ++dt)
#pragma unroll
    for (int r = 0; r < 4; ++r) {
      float v = acc[dt][r] * scl[r];
      sum[r] += v;
      sq[r] += v * v;
    }
#pragma unroll
  for (int r = 0; r < 4; ++r) {
#pragma unroll
    for (int off = 1; off <= 8; off <<= 1) {
      sum[r] += __shfl_xor(sum[r], off);
      sq[r] += __shfl_xor(sq[r], off);
    }
  }
  float mu[4], rstd[4];
#pragma unroll
  for (int r = 0; r < 4; ++r) {
    mu[r] = sum[r] * (1.0f / DHH);
    float var = sq[r] * (1.0f / DHH) - mu[r] * mu[r];
    rstd[r] = rsqrtf(var + 1e-5f);
  }
#pragma unroll
  for (int dt = 0; dt < 8; ++dt) {
    int c = dt * 16 + l15;
    float gw = gnw[n * DHH + c];
    float sw = skw[n * DHH + c];
#pragma unroll
    for (int r = 0; r < 4; ++r) {
      size_t ridx = (size_t)(b * SS + srow_base + r);
      float v = acc[dt][r] * scl[r];
      float hn = (v - mu[r]) * rstd[r] * gw;
      float ca = bf2f(convact[ridx * II + n * DHH + c]);
      float z = bf2f(up[ridx * 2048 + II + n * DHH + c]);
      float sz = z / (1.0f + __expf(-z));
      hs[ridx * II + n * DHH + c] = f2bf((hn + sw * ca) * sz);
    }
  }
}

// ---------------- final LN(last row) + 2-layer head ----------------
__global__ __launch_bounds__(256) void k_head(const float* __restrict__ h,
                                              const float* __restrict__ pw,
                                              const float* __restrict__ pb,
                                              const float* __restrict__ w1,
                                              const float* __restrict__ b1,
                                              const float* __restrict__ w2,
                                              const float* __restrict__ b2,
                                              float* __restrict__ out) {
  int b = blockIdx.x;
  int tid = threadIdx.x;
  __shared__ float last[DD];
  __shared__ float hid[H1H];
  __shared__ float ss[4], sqs[4];
  const float* row = h + ((size_t)b * SS + SS - 1) * DD;
  float v0 = row[tid], v1 = row[tid + 256];
  float s = v0 + v1, sq = v0 * v0 + v1 * v1;
  for (int off = 32; off; off >>= 1) {
    s += __shfl_down(s, off);
    sq += __shfl_down(sq, off);
  }
  int wid = tid >> 6, lane = tid & 63;
  if (lane == 0) { ss[wid] = s; sqs[wid] = sq; }
  __syncthreads();
  if (tid == 0) {
    ss[0] = ss[0] + ss[1] + ss[2] + ss[3];
    sqs[0] = sqs[0] + sqs[1] + sqs[2] + sqs[3];
  }
  __syncthreads();
  float mean = ss[0] * (1.0f / DD);
  float var = sqs[0] * (1.0f / DD) - mean * mean;
  float r = rsqrtf(var + 1e-5f);
  last[tid] = (v0 - mean) * r * pw[tid] + pb[tid];
  last[tid + 256] = (v1 - mean) * r * pw[tid + 256] + pb[tid + 256];
  __syncthreads();
  if (tid < H1H) {
    float a = b1[tid];
    for (int d2 = 0; d2 < DD; ++d2) a += last[d2] * w1[(size_t)d2 * H1H + tid];
    hid[tid] = fmaxf(a, 0.f);
  }
  __syncthreads();
  if (tid < OUTO) {
    float a = b2[tid];
#pragma unroll
    for (int j2 = 0; j2 < H1H; ++j2) a += hid[j2] * w2[(size_t)j2 * OUTO + tid];
    out[(size_t)b * OUTO + tid] = a;
  }
}

extern "C" void kernel_launch(void* const* d_in, const int* in_sizes, int n_in,
                              void* d_out, int out_size, void* d_ws, size_t ws_size,
                              hipStream_t stream) {
  (void)in_sizes; (void)n_in; (void)out_size; (void)ws_size;
  const float* x    = (const float*)d_in[0];
  const float* in_w = (const float*)d_in[1];
  const float* in_b = (const float*)d_in[2];
  const float* ln_w = (const float*)d_in[3];
  const float* ln_b = (const float*)d_in[4];
  const float* up_w = (const float*)d_in[5];
  const float* conv_w = (const float*)d_in[6];
  const float* conv_b = (const float*)d_in[7];
  const float* q_w  = (const float*)d_in[8];
  const float* k_w  = (const float*)d_in[9];
  const float* v_w  = (const float*)d_in[10];
  const float* ig_w = (const float*)d_in[11];
  const float* ig_b = (const float*)d_in[12];
  const float* fg_w = (const float*)d_in[13];
  const float* fg_b = (const float*)d_in[14];
  const float* gn_w = (const float*)d_in[15];
  const float* sk_w = (const float*)d_in[16];
  const float* dn_w = (const float*)d_in[17];
  const float* po_w = (const float*)d_in[18];
  const float* po_b = (const float*)d_in[19];
  const float* h1_w = (const float*)d_in[20];
  const float* h1_b = (const float*)d_in[21];
  const float* h2_w = (const float*)d_in[22];
  const float* h2_b = (const float*)d_in[23];

  float* h = (float*)d_ws;                              // 2M f32
  ushort* xn_bf = (ushort*)(h + 2097152);               // 2M bf16
  ushort* up_bf = xn_bf + 2097152;                      // 8M
  ushort* conv_bf = up_bf + 8388608;                    // 4M
  ushort* qkb = conv_bf + 4194304;                      // 8M (q | k fused)
  ushort* vb = qkb + 8388608;                           // 4M
  ushort* vbt = vb + 4194304;                           // 4M (per-head V^T)
  ushort* hs_bf = vbt + 4194304;                        // 4M
  ushort* wt_up = hs_bf + 4194304;                      // 2 x 1M
  ushort* wt_qk = wt_up + 2097152;                      // 2 x 2M
  ushort* wt_v  = wt_qk + 4194304;                      // 2 x 1M
  ushort* wt_dn = wt_v + 2097152;                       // 2 x 0.5M
  ushort* Wg = wt_dn + 1048576;                         // 2 x 49152
  float* igb_ = (float*)(Wg + 98304);
  float* fgb_ = igb_ + 32768;
  float* e_g  = fgb_ + 32768;
  float* M_g  = e_g + 32768;
  float* md_g = M_g + 32768;

  k_in_proj<<<BS / 16, 256, 0, stream>>>(x, in_w, in_b, h);
  k_wt_all<<<9240, 256, 0, stream>>>(up_w, q_w, k_w, v_w, dn_w, ig_w, fg_w,
                                     wt_up, wt_qk, wt_v, wt_dn, Wg);
  for (int l = 0; l < 2; ++l) {
    k_layernorm<<<BS, 256, 0, stream>>>(h, ln_w + l * DD, ln_b + l * DD, xn_bf);
    k_gemm_up<<<dim3(16, 32), 512, 0, stream>>>(xn_bf, wt_up + (size_t)l * 1048576, up_bf);
    k_conv_silu<<<BS * II / 8 / 256, 256, 0, stream>>>(up_bf, conv_w + l * II * KK,
                                                       conv_b + l * II, conv_bf);
    k_gemm_qkv<<<dim3(24, 32), 512, 0, stream>>>(conv_bf, up_bf,
                                                 wt_qk + (size_t)l * 2097152,
                                                 wt_v + (size_t)l * 1048576,
                                                 qkb, vb, vbt);
    k_gates_mfma<<<256, 64, 0, stream>>>(qkb, vb, Wg + (size_t)l * 49152,
                                         ig_b + l * NHH, fg_b + l * NHH, igb_, fgb_);
    k_scan<<<BB * NHH, 64, 0, stream>>>(igb_, fgb_, e_g, M_g, md_g);
    k_attn_mfma<<<dim3(8, BB * NHH), 256, 0, stream>>>(qkb, vbt, e_g, M_g, md_g,
                                                       conv_bf, up_bf,
                                                       gn_w + l * II, sk_w + l * II, hs_bf);
    k_gemm_down<<<dim3(4, 32, 4), 512, 0, stream>>>(hs_bf, wt_dn + (size_t)l * 524288, h);
  }
  k_head<<<BB, 256, 0, stream>>>(h, po_w, po_b, h1_w, h1_b, h2_w, h2_b, (float*)d_out);
}

// Round 9
// 378.181 us; speedup vs baseline: 4.4656x; 1.0195x over previous
//
#include <hip/hip_runtime.h>
#include <math.h>

#define BB 8
#define SS 512
#define FF 64
#define DD 512
#define II 1024
#define NHH 8
#define KK 4
#define DHH 128
#define H1H 32
#define OUTO 24
#define BS (BB*SS)   // 4096

typedef unsigned short ushort;
typedef __attribute__((ext_vector_type(8))) short short8;
typedef __attribute__((ext_vector_type(8))) unsigned short ushort8;
typedef __attribute__((ext_vector_type(4))) unsigned short ushort4v;
typedef __attribute__((ext_vector_type(4))) float f32x4;

__device__ __forceinline__ float bf2f(ushort u) {
  return __uint_as_float(((unsigned int)u) << 16);
}
__device__ __forceinline__ ushort f2bf(float f) {
  unsigned int u = __float_as_uint(f);
  unsigned int r = u + 0x7fffu + ((u >> 16) & 1u);
  return (ushort)(r >> 16);
}

typedef __attribute__((address_space(1))) const void gvoid;
typedef __attribute__((address_space(3))) void lvoid;
__device__ __forceinline__ void async16(const void* g, void* l) {
  __builtin_amdgcn_global_load_lds((gvoid*)g, (lvoid*)l, 16, 0, 0);
}

// ---------------- input projection: h = x @ in_w + in_b ----------------
__global__ __launch_bounds__(256) void k_in_proj(const float* __restrict__ x,
                                                 const float* __restrict__ w,
                                                 const float* __restrict__ b,
                                                 float* __restrict__ h) {
  int r0 = blockIdx.x * 16;
  int tid = threadIdx.x;
  __shared__ float xs[16][FF];
  for (int i = tid; i < 16 * FF; i += 256)
    xs[i >> 6][i & 63] = x[(size_t)(r0 + (i >> 6)) * FF + (i & 63)];
  __syncthreads();
  float acc0[16], acc1[16];
  float b0 = b[tid], b1 = b[tid + 256];
#pragma unroll
  for (int r = 0; r < 16; ++r) { acc0[r] = b0; acc1[r] = b1; }
  for (int f = 0; f < FF; ++f) {
    float w0 = w[(size_t)f * DD + tid];
    float w1 = w[(size_t)f * DD + tid + 256];
#pragma unroll
    for (int r = 0; r < 16; ++r) {
      float xv = xs[r][f];
      acc0[r] += xv * w0;
      acc1[r] += xv * w1;
    }
  }
#pragma unroll
  for (int r = 0; r < 16; ++r) {
    h[(size_t)(r0 + r) * DD + tid] = acc0[r];
    h[(size_t)(r0 + r) * DD + tid + 256] = acc1[r];
  }
}

// ---------------- row layernorm over D=512 -> bf16 out ----------------
__global__ __launch_bounds__(256) void k_layernorm(const float* __restrict__ in,
                                                   const float* __restrict__ w,
                                                   const float* __restrict__ b,
                                                   ushort* __restrict__ out) {
  int row = blockIdx.x;
  int tid = threadIdx.x;
  float v0 = in[(size_t)row * DD + tid];
  float v1 = in[(size_t)row * DD + tid + 256];
  float s = v0 + v1, sq = v0 * v0 + v1 * v1;
  for (int off = 32; off; off >>= 1) {
    s += __shfl_down(s, off);
    sq += __shfl_down(sq, off);
  }
  __shared__ float ss[4], sqs[4];
  int wid = tid >> 6, lane = tid & 63;
  if (lane == 0) { ss[wid] = s; sqs[wid] = sq; }
  __syncthreads();
  if (tid == 0) {
    ss[0] = ss[0] + ss[1] + ss[2] + ss[3];
    sqs[0] = sqs[0] + sqs[1] + sqs[2] + sqs[3];
  }
  __syncthreads();
  float mean = ss[0] * (1.0f / DD);
  float var = sqs[0] * (1.0f / DD) - mean * mean;
  float r = rsqrtf(var + 1e-5f);
  out[(size_t)row * DD + tid] = f2bf((v0 - mean) * r * w[tid] + b[tid]);
  out[(size_t)row * DD + tid + 256] = f2bf((v1 - mean) * r * w[tid + 256] + b[tid + 256]);
}

// ---------------- fused weight convert+transpose, BOTH layers in one launch ----------------
__global__ __launch_bounds__(256) void k_wt_all(const float* __restrict__ up_w,
                                                const float* __restrict__ q_w,
                                                const float* __restrict__ k_w,
                                                const float* __restrict__ v_w,
                                                const float* __restrict__ dn_w,
                                                const float* __restrict__ igw,
                                                const float* __restrict__ fgw,
                                                ushort* __restrict__ wt_up,
                                                ushort* __restrict__ wt_qk,
                                                ushort* __restrict__ wt_v,
                                                ushort* __restrict__ wt_dn,
                                                ushort* __restrict__ Wg) {
  int blk = blockIdx.x;
  int l = blk / 4620;
  blk -= l * 4620;
  int tid = threadIdx.x;
  if (blk >= 4608) {
    const float* igwl = igw + (size_t)l * 3 * II * NHH;
    const float* fgwl = fgw + (size_t)l * 3 * II * NHH;
    ushort* Wgl = Wg + (size_t)l * 16 * 3 * II;
    int k = (blk - 4608) * 256 + tid;
    if (k < 3 * II) {
#pragma unroll
      for (int o = 0; o < NHH; ++o) {
        Wgl[(size_t)o * (3 * II) + k] = f2bf(igwl[(size_t)k * NHH + o]);
        Wgl[(size_t)(NHH + o) * (3 * II) + k] = f2bf(fgwl[(size_t)k * NHH + o]);
      }
    }
    return;
  }
  const float* src; ushort* dst; int N, Kd, t;
  if (blk < 1024)      { src = up_w + (size_t)l * DD * 2 * II; dst = wt_up + (size_t)l * 1048576; N = 2048; Kd = 512;  t = blk; }
  else if (blk < 2048) { src = q_w + (size_t)l * II * II;  dst = wt_qk + (size_t)l * 2097152; N = 1024; Kd = 1024; t = blk - 1024; }
  else if (blk < 3072) { src = k_w + (size_t)l * II * II;  dst = wt_qk + (size_t)l * 2097152 + 1024 * 1024; N = 1024; Kd = 1024; t = blk - 2048; }
  else if (blk < 4096) { src = v_w + (size_t)l * II * II;  dst = wt_v + (size_t)l * 1048576;  N = 1024; Kd = 1024; t = blk - 3072; }
  else                 { src = dn_w + (size_t)l * II * DD; dst = wt_dn + (size_t)l * 524288;  N = 512;  Kd = 1024; t = blk - 4096; }
  int ntn = N >> 5;
  int n0 = (t % ntn) * 32, k0 = (t / ntn) * 32;
  __shared__ float tb[32][33];
  int c = tid & 31, r8 = tid >> 5;
  for (int rr = r8; rr < 32; rr += 8)
    tb[rr][c] = src[(size_t)(k0 + rr) * N + n0 + c];
  __syncthreads();
  for (int rr = r8; rr < 32; rr += 8)
    dst[(size_t)(n0 + rr) * Kd + k0 + c] = f2bf(tb[c][rr]);
}

// ---------------- 8-wave GEMM core: 128x128 tile, wave=32x64, ring-4, counted vmcnt -------
// LDS rows are 64B; the 16B-chunk index is XOR-swizzled with (row>>1)&3 on BOTH the
// staging source (pre-swizzled global col) and the fragment read — conflict-free b128.
__device__ __forceinline__ void gemm_core8(const ushort* __restrict__ Ag,
                                           const ushort* __restrict__ Bg,
                                           int nkt, ushort* AsB, ushort* BsB,
                                           int woff, int apo, int bpo,
                                           f32x4 (&acc)[2][4]) {
#define STAGE8(p) { int kt_ = (p) * 32; int bi_ = (p) & 3; \
    async16(Ag + kt_, AsB + bi_ * 4096 + woff); \
    async16(Bg + kt_, BsB + bi_ * 4096 + woff); }
  if (0 < nkt) STAGE8(0);
  if (1 < nkt) STAGE8(1);
  if (2 < nkt) STAGE8(2);
  for (int it = 0; it < nkt; ++it) {
    int bey = nkt - 1 - it;
    if (bey >= 2)      asm volatile("s_waitcnt vmcnt(4)" ::: "memory");
    else if (bey == 1) asm volatile("s_waitcnt vmcnt(2)" ::: "memory");
    else               asm volatile("s_waitcnt vmcnt(0)" ::: "memory");
    __builtin_amdgcn_s_barrier();
    int bi = it & 3;
    const ushort* ap = AsB + bi * 4096 + apo;
    const ushort* bp = BsB + bi * 4096 + bpo;
    short8 a[2], b[4];
#pragma unroll
    for (int i = 0; i < 2; ++i) a[i] = *(const short8*)(ap + i * 16 * 32);
#pragma unroll
    for (int j = 0; j < 4; ++j) b[j] = *(const short8*)(bp + j * 16 * 32);
#pragma unroll
    for (int i = 0; i < 2; ++i)
#pragma unroll
      for (int j = 0; j < 4; ++j)
        acc[i][j] = __builtin_amdgcn_mfma_f32_16x16x32_bf16(a[i], b[j], acc[i][j], 0, 0, 0);
    if (it + 3 < nkt) STAGE8(it + 3);
  }
#undef STAGE8
}

// swizzle helpers (per-thread constants)
__device__ __forceinline__ int swz_scol(int lane) {            // staging global col offset
  return (((lane & 3) ^ ((lane >> 3) & 3)) * 8);
}
__device__ __forceinline__ int swz_fk(int lane) {              // fragment read col offset
  return ((((lane >> 4) ^ (lane >> 1)) & 3) * 8);
}
__device__ __forceinline__ void xcd_swz(int* bx, int* by) {    // bijective (grid%8==0)
  int gx = gridDim.x;
  int nwg = gx * gridDim.y;
  int orig = blockIdx.y * gx + blockIdx.x;
  int q = nwg >> 3;
  int wgid = (orig & 7) * q + (orig >> 3);
  *bx = wgid % gx;
  *by = wgid / gx;
}

// ---------------- up GEMM: up = xn @ wt_up^T  (K=512, N=2048, bf16 out) ----------------
__global__ __launch_bounds__(512) void k_gemm_up(const ushort* __restrict__ A,
                                                 const ushort* __restrict__ Bt,
                                                 ushort* __restrict__ Cb) {
  __shared__ ushort As[4][4096];
  __shared__ ushort Bs[4][4096];
  int tid = threadIdx.x;
  int wave = tid >> 6, lane = tid & 63;
  int wm = wave >> 1, wn = wave & 1;
  int bx, by; xcd_swz(&bx, &by);
  int m0 = by * 128, n0 = bx * 128;
  int srow = wave * 16 + (lane >> 2), scol = swz_scol(lane);
  const ushort* Ag = A + (size_t)(m0 + srow) * DD + scol;
  const ushort* Bg = Bt + (size_t)(n0 + srow) * DD + scol;
  int woff = wave * 512;
  int frow = lane & 15, fk = swz_fk(lane);
  int apo = (wm * 32 + frow) * 32 + fk;
  int bpo = (wn * 64 + frow) * 32 + fk;
  f32x4 acc[2][4] = {};
  gemm_core8(Ag, Bg, DD / 32, &As[0][0], &Bs[0][0], woff, apo, bpo, acc);
  int ccol = lane & 15, crow = (lane >> 4) * 4;
#pragma unroll
  for (int i = 0; i < 2; ++i)
#pragma unroll
    for (int j = 0; j < 4; ++j) {
      int grow = m0 + wm * 32 + i * 16 + crow;
      int gcol = n0 + wn * 64 + j * 16 + ccol;
#pragma unroll
      for (int r = 0; r < 4; ++r)
        Cb[(size_t)(grow + r) * 2048 + gcol] = f2bf(acc[i][j][r]);
    }
}

// ---------------- fused qk|v GEMM: bx<16 -> qk (A=conv), else v (A=up, +V^T out) --------
__global__ __launch_bounds__(512) void k_gemm_qkv(const ushort* __restrict__ convb,
                                                  const ushort* __restrict__ upb,
                                                  const ushort* __restrict__ wt_qk,
                                                  const ushort* __restrict__ wt_v,
                                                  ushort* __restrict__ qkb,
                                                  ushort* __restrict__ vb,
                                                  ushort* __restrict__ vbt) {
  __shared__ ushort As[4][4096];
  __shared__ ushort Bs[4][4096];
  int tid = threadIdx.x;
  int wave = tid >> 6, lane = tid & 63;
  int wm = wave >> 1, wn = wave & 1;
  int bx, by; xcd_swz(&bx, &by);
  int isv = bx >= 16;
  int m0 = by * 128;
  int n0 = (isv ? bx - 16 : bx) * 128;
  const ushort* A = isv ? upb : convb;
  int lda = isv ? 2048 : 1024;
  const ushort* Bt = isv ? wt_v : wt_qk;
  int srow = wave * 16 + (lane >> 2), scol = swz_scol(lane);
  const ushort* Ag = A + (size_t)(m0 + srow) * lda + scol;
  const ushort* Bg = Bt + (size_t)(n0 + srow) * II + scol;
  int woff = wave * 512;
  int frow = lane & 15, fk = swz_fk(lane);
  int apo = (wm * 32 + frow) * 32 + fk;
  int bpo = (wn * 64 + frow) * 32 + fk;
  f32x4 acc[2][4] = {};
  gemm_core8(Ag, Bg, II / 32, &As[0][0], &Bs[0][0], woff, apo, bpo, acc);
  int ccol = lane & 15, crow = (lane >> 4) * 4;
#pragma unroll
  for (int i = 0; i < 2; ++i)
#pragma unroll
    for (int j = 0; j < 4; ++j) {
      int grow = m0 + wm * 32 + i * 16 + crow;
      int gcol = n0 + wn * 64 + j * 16 + ccol;
      if (!isv) {
#pragma unroll
        for (int r = 0; r < 4; ++r)
          qkb[(size_t)(grow + r) * 2048 + gcol] = f2bf(acc[i][j][r]);
      } else {
#pragma unroll
        for (int r = 0; r < 4; ++r)
          vb[(size_t)(grow + r) * II + gcol] = f2bf(acc[i][j][r]);
        int b8 = grow >> 9, sloc = grow & 511;
        int nh = gcol >> 7, d = gcol & 127;
        ushort4v o;
#pragma unroll
        for (int r = 0; r < 4; ++r) o[r] = f2bf(acc[i][j][r]);
        *(ushort4v*)&vbt[((size_t)(b8 * NHH + nh) * DHH + d) * SS + sloc] = o;
      }
    }
}

// ---------------- down GEMM: split-K=4, atomic f32 accumulate into h ----------------
__global__ __launch_bounds__(512) void k_gemm_down(const ushort* __restrict__ A,
                                                   const ushort* __restrict__ Bt,
                                                   float* __restrict__ Cf) {
  __shared__ ushort As[4][4096];
  __shared__ ushort Bs[4][4096];
  int tid = threadIdx.x;
  int wave = tid >> 6, lane = tid & 63;
  int wm = wave >> 1, wn = wave & 1;
  int bx, by; xcd_swz(&bx, &by);
  int m0 = by * 128, n0 = bx * 128;
  int k0 = blockIdx.z * 256;
  int srow = wave * 16 + (lane >> 2), scol = swz_scol(lane);
  const ushort* Ag = A + (size_t)(m0 + srow) * II + k0 + scol;
  const ushort* Bg = Bt + (size_t)(n0 + srow) * II + k0 + scol;
  int woff = wave * 512;
  int frow = lane & 15, fk = swz_fk(lane);
  int apo = (wm * 32 + frow) * 32 + fk;
  int bpo = (wn * 64 + frow) * 32 + fk;
  f32x4 acc[2][4] = {};
  gemm_core8(Ag, Bg, 256 / 32, &As[0][0], &Bs[0][0], woff, apo, bpo, acc);
  int ccol = lane & 15, crow = (lane >> 4) * 4;
#pragma unroll
  for (int i = 0; i < 2; ++i)
#pragma unroll
    for (int j = 0; j < 4; ++j) {
      int grow = m0 + wm * 32 + i * 16 + crow;
      int gcol = n0 + wn * 64 + j * 16 + ccol;
#pragma unroll
      for (int r = 0; r < 4; ++r)
        atomicAdd(&Cf[(size_t)(grow + r) * DD + gcol], acc[i][j][r]);
    }
}

// ---------------- causal conv (K=4) + SiLU, 8 channels/thread ----------------
__global__ __launch_bounds__(256) void k_conv_silu(const ushort* __restrict__ up,
                                                   const float* __restrict__ cw,
                                                   const float* __restrict__ cb,
                                                   ushort* __restrict__ out) {
  int g = blockIdx.x * 256 + threadIdx.x;
  int c8 = (g & 127) * 8;
  int row = g >> 7;
  int s = row & (SS - 1);
  float acc[8];
  float4 wv[8];
#pragma unroll
  for (int t = 0; t < 8; ++t) {
    acc[t] = cb[c8 + t];
    wv[t] = *(const float4*)(cw + (size_t)(c8 + t) * 4);
  }
#pragma unroll
  for (int j = 0; j < 4; ++j) {
    int so = s + j - 3;
    if (so >= 0) {
      ushort8 u = *(const ushort8*)&up[(size_t)(row + j - 3) * 2048 + c8];
#pragma unroll
      for (int t = 0; t < 8; ++t) {
        float wc = (j == 0) ? wv[t].x : (j == 1) ? wv[t].y : (j == 2) ? wv[t].z : wv[t].w;
        acc[t] += bf2f(u[t]) * wc;
      }
    }
  }
  ushort8 o;
#pragma unroll
  for (int t = 0; t < 8; ++t) {
    float sig = 1.0f / (1.0f + __expf(-acc[t]));
    o[t] = f2bf(acc[t] * sig);
  }
  *(ushort8*)&out[(size_t)row * II + c8] = o;
}

// ---------------- gate projections via MFMA ----------------
__global__ __launch_bounds__(64) void k_gates_mfma(const ushort* __restrict__ qkb,
                                                   const ushort* __restrict__ vb,
                                                   const ushort* __restrict__ Wg,
                                                   const float* __restrict__ igb,
                                                   const float* __restrict__ fgb,
                                                   float* __restrict__ ig,
                                                   float* __restrict__ fg) {
  int lane = threadIdx.x;
  int row0 = blockIdx.x * 16;
  int l15 = lane & 15, lg = lane >> 4;
  int arow = row0 + l15;
  const ushort* qrow = qkb + (size_t)arow * 2048 + lg * 8;
  const ushort* vrow = vb + (size_t)arow * II + lg * 8;
  const ushort* wrow = Wg + (size_t)l15 * (3 * II) + lg * 8;
  f32x4 acc0 = {}, acc1 = {};
#pragma unroll 4
  for (int k = 0; k < 2048; k += 64) {
    short8 a0 = *(const short8*)(qrow + k);
    short8 b0 = *(const short8*)(wrow + k);
    short8 a1 = *(const short8*)(qrow + k + 32);
    short8 b1 = *(const short8*)(wrow + k + 32);
    acc0 = __builtin_amdgcn_mfma_f32_16x16x32_bf16(a0, b0, acc0, 0, 0, 0);
    acc1 = __builtin_amdgcn_mfma_f32_16x16x32_bf16(a1, b1, acc1, 0, 0, 0);
  }
#pragma unroll 4
  for (int k = 0; k < 1024; k += 64) {
    short8 a0 = *(const short8*)(vrow + k);
    short8 b0 = *(const short8*)(wrow + 2048 + k);
    short8 a1 = *(const short8*)(vrow + k + 32);
    short8 b1 = *(const short8*)(wrow + 2048 + k + 32);
    acc0 = __builtin_amdgcn_mfma_f32_16x16x32_bf16(a0, b0, acc0, 0, 0, 0);
    acc1 = __builtin_amdgcn_mfma_f32_16x16x32_bf16(a1, b1, acc1, 0, 0, 0);
  }
  int o = l15;
#pragma unroll
  for (int r = 0; r < 4; ++r) {
    int row = row0 + lg * 4 + r;
    int bb = row >> 9, s = row & (SS - 1);
    float val = acc0[r] + acc1[r];
    if (o < NHH)
      ig[((size_t)bb * NHH + o) * SS + s] = val + igb[o];
    else
      fg[((size_t)bb * NHH + (o - NHH)) * SS + s] = val + fgb[o - NHH];
  }
}

// ---------------- per-(b,n) scan: one wave per bn, shfl prefix ----------------
__global__ __launch_bounds__(64) void k_scan(const float* __restrict__ ig,
                                             const float* __restrict__ fg,
                                             float* __restrict__ e_g, float* __restrict__ M_g,
                                             float* __restrict__ maxd_g) {
  int bn = blockIdx.x;
  int lane = threadIdx.x;
  size_t base = (size_t)bn * SS + lane * 8;
  float4 f0 = *(const float4*)&fg[base];
  float4 f1 = *(const float4*)&fg[base + 4];
  float fv[8] = {f0.x, f0.y, f0.z, f0.w, f1.x, f1.y, f1.z, f1.w};
  float lf[8];
#pragma unroll
  for (int j = 0; j < 8; ++j) {
    float f = fv[j];
    lf[j] = (f >= 0.f) ? -log1pf(expf(-f)) : (f - log1pf(expf(f)));
  }
  float cum[8];
  float run = 0.f;
#pragma unroll
  for (int j = 0; j < 8; ++j) { run += lf[j]; cum[j] = run; }
  float inc = run;
#pragma unroll
  for (int off = 1; off < 64; off <<= 1) {
    float t = __shfl_up(inc, off);
    if (lane >= off) inc += t;
  }
  float exs = inc - run;
  float4 i0 = *(const float4*)&ig[base];
  float4 i1 = *(const float4*)&ig[base + 4];
  float igv[8] = {i0.x, i0.y, i0.z, i0.w, i1.x, i1.y, i1.z, i1.w};
  float cs[8], e[8];
#pragma unroll
  for (int j = 0; j < 8; ++j) {
    cs[j] = exs + cum[j];
    e[j] = igv[j] - cs[j];
  }
  float mcum[8];
  float mrun = -3.0e38f;
#pragma unroll
  for (int j = 0; j < 8; ++j) { mrun = fmaxf(mrun, e[j]); mcum[j] = mrun; }
  float minc = mrun;
#pragma unroll
  for (int off = 1; off < 64; off <<= 1) {
    float t = __shfl_up(minc, off);
    if (lane >= off) minc = fmaxf(minc, t);
  }
  float mex = __shfl_up(minc, 1);
  if (lane == 0) mex = -3.0e38f;
  float M[8], mdv[8];
#pragma unroll
  for (int j = 0; j < 8; ++j) {
    M[j] = fmaxf(mex, mcum[j]);
    mdv[j] = cs[j] + M[j];
  }
  *(float4*)&e_g[base] = make_float4(e[0], e[1], e[2], e[3]);
  *(float4*)&e_g[base + 4] = make_float4(e[4], e[5], e[6], e[7]);
  *(float4*)&M_g[base] = make_float4(M[0], M[1], M[2], M[3]);
  *(float4*)&M_g[base + 4] = make_float4(M[4], M[5], M[6], M[7]);
  *(float4*)&maxd_g[base] = make_float4(mdv[0], mdv[1], mdv[2], mdv[3]);
  *(float4*)&maxd_g[base + 4] = make_float4(mdv[4], mdv[5], mdv[6], mdv[7]);
}

// ---------------- mLSTM attention, MFMA bf16, async dbuf staging, fused GN epilogue --------
__global__ __launch_bounds__(256) void k_attn_mfma(const ushort* __restrict__ qkb,
                                                   const ushort* __restrict__ vbt,
                                                   const float* __restrict__ e_g,
                                                   const float* __restrict__ M_g,
                                                   const float* __restrict__ maxd_g,
                                                   const ushort* __restrict__ convact,
                                                   const ushort* __restrict__ up,
                                                   const float* __restrict__ gnw,
                                                   const float* __restrict__ skw,
                                                   ushort* __restrict__ hs) {
  __shared__ __align__(16) ushort K2[2][64 * 128];
  __shared__ __align__(16) ushort V2[2][128 * 64];
  __shared__ __align__(16) ushort w_s[4][16 * 72];
  __shared__ float e_s[SS];

  int tid = threadIdx.x;
  int wave = tid >> 6, lane = tid & 63;
  int xb = blockIdx.x;
  int stile = (xb & 1) ? (7 - (xb >> 1)) : (xb >> 1);
  int bn = blockIdx.y;
  int b = bn >> 3, n = bn & 7;
  int s0 = stile * 64;

  const size_t qbase = (size_t)(b * SS) * 2048 + (size_t)n * DHH;
  const size_t kbase = qbase + II;
  const size_t vtbase = (size_t)bn * DHH * SS;

  int l15 = lane & 15, lg = lane >> 4;
  int kg8 = lg * 8;
  int crow = lg * 4;
  int srow_base = s0 + wave * 16 + crow;

  e_s[tid] = e_g[(size_t)bn * SS + tid];
  e_s[tid + 256] = e_g[(size_t)bn * SS + tid + 256];

  short8 qf[4];
  {
    int qrow = s0 + wave * 16 + l15;
#pragma unroll
    for (int ks = 0; ks < 4; ++ks)
      qf[ks] = *(const short8*)&qkb[qbase + (size_t)qrow * 2048 + ks * 32 + kg8];
  }
  float Ms[4], md[4];
#pragma unroll
  for (int r = 0; r < 4; ++r) {
    Ms[r] = M_g[(size_t)bn * SS + srow_base + r];
    md[r] = maxd_g[(size_t)bn * SS + srow_base + r];
  }

  f32x4 acc[8] = {};
  float rsum[4] = {};
  const float rsq = 0.08838834764831845f;
  ushort* w_w = &w_s[wave][0];
  int ntt = stile + 1;

#pragma unroll
  for (int i = 0; i < 4; ++i) {
    int r = wave * 16 + i * 4 + (lane >> 4);
    int sp = (lane & 15) ^ (r & 7);
    async16(&qkb[kbase + (size_t)r * 2048 + sp * 8], &K2[0][(wave * 16 + i * 4) * 128]);
  }
#pragma unroll
  for (int i = 0; i < 4; ++i) {
    int d = wave * 32 + i * 8 + (lane >> 3);
    int sp = (lane & 7) ^ (d & 7);
    async16(&vbt[vtbase + (size_t)d * SS + sp * 8], &V2[0][(wave * 32 + i * 8) * 64]);
  }

  for (int tt = 0; tt < ntt; ++tt) {
    int cur = tt & 1;
    if (tt + 1 < ntt) {
      int t1 = (tt + 1) * 64;
      int nxt = cur ^ 1;
#pragma unroll
      for (int i = 0; i < 4; ++i) {
        int r = wave * 16 + i * 4 + (lane >> 4);
        int sp = (lane & 15) ^ (r & 7);
        async16(&qkb[kbase + (size_t)(t1 + r) * 2048 + sp * 8], &K2[nxt][(wave * 16 + i * 4) * 128]);
      }
#pragma unroll
      for (int i = 0; i < 4; ++i) {
        int d = wave * 32 + i * 8 + (lane >> 3);
        int sp = (lane & 7) ^ (d & 7);
        async16(&vbt[vtbase + (size_t)d * SS + t1 + sp * 8], &V2[nxt][(wave * 32 + i * 8) * 64]);
      }
      asm volatile("s_waitcnt vmcnt(8) lgkmcnt(0)" ::: "memory");
    } else {
      asm volatile("s_waitcnt vmcnt(0) lgkmcnt(0)" ::: "memory");
    }
    __builtin_amdgcn_s_barrier();

    int t0 = tt * 64;
    const ushort* Kc = &K2[cur][0];
    const ushort* Vc = &V2[cur][0];

    f32x4 s4[4];
#pragma unroll
    for (int ct = 0; ct < 4; ++ct) {
      f32x4 c = {};
      int ro = l15 + 16 * ct;
#pragma unroll
      for (int ks = 0; ks < 4; ++ks) {
        int sp = (ks * 4 + lg) ^ (ro & 7);
        short8 kf = *(const short8*)&Kc[ro * 128 + sp * 8];
        c = __builtin_amdgcn_mfma_f32_16x16x32_bf16(qf[ks], kf, c, 0, 0, 0);
      }
      s4[ct] = c;
    }
#pragma unroll
    for (int ct = 0; ct < 4; ++ct) {
      int t = t0 + l15 + 16 * ct;
      float e = e_s[t];
#pragma unroll
      for (int r = 0; r < 4; ++r) {
        int s = srow_base + r;
        float val = (t <= s) ? s4[ct][r] * rsq * __expf(e - Ms[r]) : 0.f;
        s4[ct][r] = val;
        w_w[(crow + r) * 72 + l15 + 16 * ct] = f2bf(val);
      }
    }
#pragma unroll
    for (int r = 0; r < 4; ++r) {
      float tmp = s4[0][r] + s4[1][r] + s4[2][r] + s4[3][r];
      tmp += __shfl_xor(tmp, 1);
      tmp += __shfl_xor(tmp, 2);
      tmp += __shfl_xor(tmp, 4);
      tmp += __shfl_xor(tmp, 8);
      rsum[r] += tmp;
    }
    short8 wf0 = *(const short8*)&w_w[l15 * 72 + kg8];
    short8 wf1 = *(const short8*)&w_w[l15 * 72 + 32 + kg8];
#pragma unroll
    for (int dt = 0; dt < 8; ++dt) {
      int d = dt * 16 + l15;
      int sp0 = lg ^ (d & 7);
      int sp1 = (lg + 4) ^ (d & 7);
      short8 vf0 = *(const short8*)&Vc[d * 64 + sp0 * 8];
      short8 vf1 = *(const short8*)&Vc[d * 64 + sp1 * 8];
      acc[dt] = __builtin_amdgcn_mfma_f32_16x16x32_bf16(wf0, vf0, acc[dt], 0, 0, 0);
      acc[dt] = __builtin_amdgcn_mfma_f32_16x16x32_bf16(wf1, vf1, acc[dt], 0, 0, 0);
    }
    __builtin_amdgcn_s_barrier();
  }

  float scl[4], sum[4] = {}, sq[4] = {};
#pragma unroll
  for (int r = 0; r < 4; ++r) {
    float nrm = fmaxf(fabsf(rsum[r]), __expf(-md[r]));
    scl[r] = 1.0f / (nrm + 1e-6f);
  }
#pragma unroll
  for (int dt = 0; dt < 8; ++dt)
#pragma unroll
    for (int r = 0; r < 4; ++r) {
      float v = acc[dt][r] * scl[r];
      sum[r] += v;
      sq[r] += v * v;
    }
#pragma unroll
  for (int r = 0; r < 4; ++r) {
#pragma unroll
    for (int off = 1; off <= 8; off <<= 1) {
      sum[r] += __shfl_xor(sum[r], off);
      sq[r] += __shfl_xor(sq[r], off);
    }
  }
  float mu[4], rstd[4];
#pragma unroll
  for (int r = 0; r < 4; ++r) {
    mu[r] = sum[r] * (1.0f / DHH);
    float var = sq[r] * (1.0f / DHH) - mu[r] * mu[r];
    rstd[r] = rsqrtf(var + 1e-5f);
  }
#pragma unroll
  for (int dt = 0; dt < 8; ++dt) {
    int c = dt * 16 + l15;
    float gw = gnw[n * DHH + c];
    float sw = skw[n * DHH + c];
#pragma unroll
    for (int r = 0; r < 4; ++r) {
      size_t ridx = (size_t)(b * SS + srow_base + r);
      float v = acc[dt][r] * scl[r];
      float hn = (v - mu[r]) * rstd[r] * gw;
      float ca = bf2f(convact[ridx * II + n * DHH + c]);
      float z = bf2f(up[ridx * 2048 + II + n * DHH + c]);
      float sz = z / (1.0f + __expf(-z));
      hs[ridx * II + n * DHH + c] = f2bf((hn + sw * ca) * sz);
    }
  }
}

// ---------------- final LN(last row) + 2-layer head ----------------
__global__ __launch_bounds__(256) void k_head(const float* __restrict__ h,
                                              const float* __restrict__ pw,
                                              const float* __restrict__ pb,
                                              const float* __restrict__ w1,
                                              const float* __restrict__ b1,
                                              const float* __restrict__ w2,
                                              const float* __restrict__ b2,
                                              float* __restrict__ out) {
  int b = blockIdx.x;
  int tid = threadIdx.x;
  __shared__ float last[DD];
  __shared__ float hid[H1H];
  __shared__ float ss[4], sqs[4];
  const float* row = h + ((size_t)b * SS + SS - 1) * DD;
  float v0 = row[tid], v1 = row[tid + 256];
  float s = v0 + v1, sq = v0 * v0 + v1 * v1;
  for (int off = 32; off; off >>= 1) {
    s += __shfl_down(s, off);
    sq += __shfl_down(sq, off);
  }
  int wid = tid >> 6, lane = tid & 63;
  if (lane == 0) { ss[wid] = s; sqs[wid] = sq; }
  __syncthreads();
  if (tid == 0) {
    ss[0] = ss[0] + ss[1] + ss[2] + ss[3];
    sqs[0] = sqs[0] + sqs[1] + sqs[2] + sqs[3];
  }
  __syncthreads();
  float mean = ss[0] * (1.0f / DD);
  float var = sqs[0] * (1.0f / DD) - mean * mean;
  float r = rsqrtf(var + 1e-5f);
  last[tid] = (v0 - mean) * r * pw[tid] + pb[tid];
  last[tid + 256] = (v1 - mean) * r * pw[tid + 256] + pb[tid + 256];
  __syncthreads();
  if (tid < H1H) {
    float a = b1[tid];
    for (int d2 = 0; d2 < DD; ++d2) a += last[d2] * w1[(size_t)d2 * H1H + tid];
    hid[tid] = fmaxf(a, 0.f);
  }
  __syncthreads();
  if (tid < OUTO) {
    float a = b2[tid];
#pragma unroll
    for (int j2 = 0; j2 < H1H; ++j2) a += hid[j2] * w2[(size_t)j2 * OUTO + tid];
    out[(size_t)b * OUTO + tid] = a;
  }
}

extern "C" void kernel_launch(void* const* d_in, const int* in_sizes, int n_in,
                              void* d_out, int out_size, void* d_ws, size_t ws_size,
                              hipStream_t stream) {
  (void)in_sizes; (void)n_in; (void)out_size; (void)ws_size;
  const float* x    = (const float*)d_in[0];
  const float* in_w = (const float*)d_in[1];
  const float* in_b = (const float*)d_in[2];
  const float* ln_w = (const float*)d_in[3];
  const float* ln_b = (const float*)d_in[4];
  const float* up_w = (const float*)d_in[5];
  const float* conv_w = (const float*)d_in[6];
  const float* conv_b = (const float*)d_in[7];
  const float* q_w  = (const float*)d_in[8];
  const float* k_w  = (const float*)d_in[9];
  const float* v_w  = (const float*)d_in[10];
  const float* ig_w = (const float*)d_in[11];
  const float* ig_b = (const float*)d_in[12];
  const float* fg_w = (const float*)d_in[13];
  const float* fg_b = (const float*)d_in[14];
  const float* gn_w = (const float*)d_in[15];
  const float* sk_w = (const float*)d_in[16];
  const float* dn_w = (const float*)d_in[17];
  const float* po_w = (const float*)d_in[18];
  const float* po_b = (const float*)d_in[19];
  const float* h1_w = (const float*)d_in[20];
  const float* h1_b = (const float*)d_in[21];
  const float* h2_w = (const float*)d_in[22];
  const float* h2_b = (const float*)d_in[23];

  float* h = (float*)d_ws;                              // 2M f32
  ushort* xn_bf = (ushort*)(h + 2097152);               // 2M bf16
  ushort* up_bf = xn_bf + 2097152;                      // 8M
  ushort* conv_bf = up_bf + 8388608;                    // 4M
  ushort* qkb = conv_bf + 4194304;                      // 8M (q | k fused)
  ushort* vb = qkb + 8388608;                           // 4M
  ushort* vbt = vb + 4194304;                           // 4M (per-head V^T)
  ushort* hs_bf = vbt + 4194304;                        // 4M
  ushort* wt_up = hs_bf + 4194304;                      // 2 x 1M
  ushort* wt_qk = wt_up + 2097152;                      // 2 x 2M
  ushort* wt_v  = wt_qk + 4194304;                      // 2 x 1M
  ushort* wt_dn = wt_v + 2097152;                       // 2 x 0.5M
  ushort* Wg = wt_dn + 1048576;                         // 2 x 49152
  float* igb_ = (float*)(Wg + 98304);
  float* fgb_ = igb_ + 32768;
  float* e_g  = fgb_ + 32768;
  float* M_g  = e_g + 32768;
  float* md_g = M_g + 32768;

  k_in_proj<<<BS / 16, 256, 0, stream>>>(x, in_w, in_b, h);
  k_wt_all<<<9240, 256, 0, stream>>>(up_w, q_w, k_w, v_w, dn_w, ig_w, fg_w,
                                     wt_up, wt_qk, wt_v, wt_dn, Wg);
  for (int l = 0; l < 2; ++l) {
    k_layernorm<<<BS, 256, 0, stream>>>(h, ln_w + l * DD, ln_b + l * DD, xn_bf);
    k_gemm_up<<<dim3(16, 32), 512, 0, stream>>>(xn_bf, wt_up + (size_t)l * 1048576, up_bf);
    k_conv_silu<<<BS * II / 8 / 256, 256, 0, stream>>>(up_bf, conv_w + l * II * KK,
                                                       conv_b + l * II, conv_bf);
    k_gemm_qkv<<<dim3(24, 32), 512, 0, stream>>>(conv_bf, up_bf,
                                                 wt_qk + (size_t)l * 2097152,
                                                 wt_v + (size_t)l * 1048576,
                                                 qkb, vb, vbt);
    k_gates_mfma<<<256, 64, 0, stream>>>(qkb, vb, Wg + (size_t)l * 49152,
                                         ig_b + l * NHH, fg_b + l * NHH, igb_, fgb_);
    k_scan<<<BB * NHH, 64, 0, stream>>>(igb_, fgb_, e_g, M_g, md_g);
    k_attn_mfma<<<dim3(8, BB * NHH), 256, 0, stream>>>(qkb, vbt, e_g, M_g, md_g,
                                                       conv_bf, up_bf,
                                                       gn_w + l * II, sk_w + l * II, hs_bf);
    k_gemm_down<<<dim3(4, 32, 4), 512, 0, stream>>>(hs_bf, wt_dn + (size_t)l * 524288, h);
  }
  k_head<<<BB, 256, 0, stream>>>(h, po_w, po_b, h1_w, h1_b, h2_w, h2_b, (float*)d_out);
}